// Round 3
// baseline (3545.874 us; speedup 1.0000x reference)
//
#include <hip/hip_runtime.h>

typedef unsigned short u16;
typedef __attribute__((ext_vector_type(4))) float f32x4;
typedef __attribute__((ext_vector_type(8))) short s16x8;

static constexpr int V = 32000;
static constexpr int C = 1024;
static constexpr int T = 1024;
static constexpr int H = 16;
static constexpr int L = 8;
static constexpr int B = 4;
static constexpr int HS = 64;
static constexpr int BT = B * T;   // 4096
static constexpr int C4 = 4 * C;   // 4096
static constexpr int C3 = 3 * C;   // 3072

__device__ __forceinline__ u16 f2bf(float f) {
  union { float f; unsigned u; } v; v.f = f;
  unsigned r = v.u + 0x7fffu + ((v.u >> 16) & 1u);
  return (u16)(r >> 16);
}

__device__ __forceinline__ void gload16(const u16* g, u16* l) {
  __builtin_amdgcn_global_load_lds(
      (const __attribute__((address_space(1))) void*)g,
      (__attribute__((address_space(3))) void*)l, 16, 0, 0);
}

// ---------- block reduction (256 threads) ----------
__device__ __forceinline__ float blockReduceSum(float v) {
  __shared__ float red[4];
  int lane = threadIdx.x & 63, w = threadIdx.x >> 6;
#pragma unroll
  for (int m = 32; m >= 1; m >>= 1) v += __shfl_xor(v, m, 64);
  if (lane == 0) red[w] = v;
  __syncthreads();
  float r = red[0] + red[1] + red[2] + red[3];
  __syncthreads();
  return r;
}

// ---------- embed ----------
__global__ __launch_bounds__(256) void k_embed(
    const int* __restrict__ idx, const float* __restrict__ tok,
    const float* __restrict__ pos, float* __restrict__ x, u16* __restrict__ xb) {
  int bt = blockIdx.x;
  int t = bt & (T - 1);
  int row = idx[bt];
  const float* te = tok + (size_t)row * C;
  const float* pe = pos + (size_t)t * C;
  float* xo = x + (size_t)bt * C;
  u16* xbo = xb + (size_t)bt * C;
  for (int c = threadIdx.x; c < C; c += 256) {
    float v = te[c] + pe[c];
    xo[c] = v;
    xbo[c] = f2bf(v);
  }
}

// ---------- weight convert+transpose: fp32 [K,N] -> bf16 [N,K] ----------
__global__ __launch_bounds__(256) void k_transpose(
    const float* __restrict__ W, u16* __restrict__ Wt, int K, int N,
    size_t sW, size_t sWt) {
  __shared__ float tile[64][65];
  const float* Wz = W + sW * blockIdx.z;
  u16* Wtz = Wt + sWt * blockIdx.z;
  int n0 = blockIdx.x * 64, k0 = blockIdx.y * 64;
  int tc = threadIdx.x & 63, tr = threadIdx.x >> 6;
#pragma unroll
  for (int i = 0; i < 16; ++i) {
    int r = tr + i * 4;
    tile[r][tc] = Wz[(size_t)(k0 + r) * N + (n0 + tc)];
  }
  __syncthreads();
#pragma unroll
  for (int i = 0; i < 16; ++i) {
    int r = tr + i * 4;  // n-offset within tile
    Wtz[(size_t)(n0 + r) * K + (k0 + tc)] = f2bf(tile[tc][r]);
  }
}

// ---------- GEMM 256x256 8-phase (T2+T3+T4+T5): C = A[M,K] @ Bt[N,K]^T ----
// 512 threads = 8 waves (2M x 4N), per-wave 128x64 out, BK=64 (2 kk-halves).
// LDS 128 KiB: As/Bs[2 buf][kk-half 16KB contiguous][16-row subtile 1KB]
// [row16][slot^((row16>>1)&3)][16B]. Staged via global_load_lds(16B) with
// inverse-swizzled global source (linear LDS dest). Counted vmcnt: (2)@P1,
// (4)@P4; drain 0 only at last tile.
template <int OUT_BF16, int RELU, int HAS_BIAS, int HAS_RES>
__global__ __launch_bounds__(512) void k_gemm256(
    const u16* __restrict__ A, const u16* __restrict__ Bt,
    const float* __restrict__ bias, const float* __restrict__ Res,
    float* __restrict__ Cf, u16* __restrict__ Cb, int M, int N, int K) {
  __shared__ u16 As[2][16384];
  __shared__ u16 Bs[2][16384];
  const int tid = threadIdx.x;
  const int lane = tid & 63, wid = tid >> 6;
  const int lm = lane & 15, lg = lane >> 4;
  const int wr = wid >> 2, wc = wid & 3;

  unsigned nbx = gridDim.x;
  unsigned nwg = nbx * gridDim.y;
  unsigned orig = blockIdx.y * nbx + blockIdx.x;
  unsigned f = ((nwg & 7u) == 0u) ? (orig & 7u) * (nwg >> 3) + (orig >> 3) : orig;
  const int mb = (int)(f / nbx) * 256, nb = (int)(f % nbx) * 256;

  // staging addresses: h = kk*2 + p (ordinal order Ak0,Bk0,Ak1,Bk1 via h)
  int aoff[4], boff[4], ldso[4];
#pragma unroll
  for (int h = 0; h < 4; ++h) {
    const int kk = h >> 1, p = h & 1;
    int rem = p * 512 + tid;          // slot within 1024-slot kk-half
    int rblk = rem >> 6;              // 16-row subtile
    int rem2 = rem & 63;
    int row16 = rem2 >> 2, psl = rem2 & 3;
    int sl = psl ^ ((row16 >> 1) & 3);  // inverse swizzle on global source
    int grow = rblk * 16 + row16;
    int gk = kk * 32 + sl * 8;
    aoff[h] = (mb + grow) * K + gk;
    boff[h] = (nb + grow) * K + gk;
    ldso[h] = kk * 8192 + p * 4096 + wid * 512;  // u16 units, wave-uniform
  }
  // ds-read lane offset (u16): row16=lm (64B rows), slot = lg ^ ((lm>>1)&3)
  const int lo = lm * 32 + ((lg ^ ((lm >> 1) & 3)) << 3);

  f32x4 acc[8][4];
#pragma unroll
  for (int i = 0; i < 8; ++i)
#pragma unroll
    for (int j = 0; j < 4; ++j) acc[i][j] = f32x4{0.f, 0.f, 0.f, 0.f};

  const int nK = K >> 6;
  // ---- prologue: stage tile 0 (order Ak0,Bk0,Ak1,Bk1), gate Ak0+Bk0 ----
  gload16(A + aoff[0], &As[0][ldso[0]]);
  gload16(A + aoff[1], &As[0][ldso[1]]);
  gload16(Bt + boff[0], &Bs[0][ldso[0]]);
  gload16(Bt + boff[1], &Bs[0][ldso[1]]);
  gload16(A + aoff[2], &As[0][ldso[2]]);
  gload16(A + aoff[3], &As[0][ldso[3]]);
  gload16(Bt + boff[2], &Bs[0][ldso[2]]);
  gload16(Bt + boff[3], &Bs[0][ldso[3]]);
  asm volatile("s_waitcnt vmcnt(4)" ::: "memory");
  __builtin_amdgcn_s_barrier();

  for (int t = 0; t < nK; ++t) {
    const int buf = t & 1, nbuf = buf ^ 1;
    const bool pre = (t + 1 < nK);
    const int nk64 = (t + 1) * 64;
    s16x8 af[4], bfr[4];
    // ======== P1: kk0 frags (A m0-3 + B n0-3); stage Ak0(t+1) ========
#pragma unroll
    for (int m = 0; m < 4; ++m)
      af[m] = *(const s16x8*)&As[buf][(wr * 8 + m) * 512 + lo];
#pragma unroll
    for (int n = 0; n < 4; ++n)
      bfr[n] = *(const s16x8*)&Bs[buf][(wc * 4 + n) * 512 + lo];
    if (pre) {
      gload16(A + aoff[0] + nk64, &As[nbuf][ldso[0]]);
      gload16(A + aoff[1] + nk64, &As[nbuf][ldso[1]]);
      asm volatile("s_waitcnt vmcnt(2)" ::: "memory");  // Ak1(t),Bk1(t) landed
    } else {
      asm volatile("s_waitcnt vmcnt(0)" ::: "memory");
    }
    __builtin_amdgcn_s_barrier();
    __builtin_amdgcn_s_setprio(1);
#pragma unroll
    for (int m = 0; m < 4; ++m)
#pragma unroll
      for (int n = 0; n < 4; ++n)
        acc[m][n] = __builtin_amdgcn_mfma_f32_16x16x32_bf16(af[m], bfr[n],
                                                            acc[m][n], 0, 0, 0);
    __builtin_amdgcn_s_setprio(0);
    __builtin_amdgcn_s_barrier();
    // ======== P2: A m4-7 kk0 (B reused); stage Bk0(t+1) ========
#pragma unroll
    for (int m = 0; m < 4; ++m)
      af[m] = *(const s16x8*)&As[buf][(wr * 8 + 4 + m) * 512 + lo];
    if (pre) {
      gload16(Bt + boff[0] + nk64, &Bs[nbuf][ldso[0]]);
      gload16(Bt + boff[1] + nk64, &Bs[nbuf][ldso[1]]);
    }
    __builtin_amdgcn_s_barrier();
    __builtin_amdgcn_s_setprio(1);
#pragma unroll
    for (int m = 0; m < 4; ++m)
#pragma unroll
      for (int n = 0; n < 4; ++n)
        acc[m + 4][n] = __builtin_amdgcn_mfma_f32_16x16x32_bf16(
            af[m], bfr[n], acc[m + 4][n], 0, 0, 0);
    __builtin_amdgcn_s_setprio(0);
    __builtin_amdgcn_s_barrier();
    // ======== P3: kk1 frags (A m0-3 + B); stage Ak1(t+1) ========
#pragma unroll
    for (int m = 0; m < 4; ++m)
      af[m] = *(const s16x8*)&As[buf][8192 + (wr * 8 + m) * 512 + lo];
#pragma unroll
    for (int n = 0; n < 4; ++n)
      bfr[n] = *(const s16x8*)&Bs[buf][8192 + (wc * 4 + n) * 512 + lo];
    if (pre) {
      gload16(A + aoff[2] + nk64, &As[nbuf][ldso[2]]);
      gload16(A + aoff[3] + nk64, &As[nbuf][ldso[3]]);
    }
    __builtin_amdgcn_s_barrier();
    __builtin_amdgcn_s_setprio(1);
#pragma unroll
    for (int m = 0; m < 4; ++m)
#pragma unroll
      for (int n = 0; n < 4; ++n)
        acc[m][n] = __builtin_amdgcn_mfma_f32_16x16x32_bf16(af[m], bfr[n],
                                                            acc[m][n], 0, 0, 0);
    __builtin_amdgcn_s_setprio(0);
    __builtin_amdgcn_s_barrier();
    // ======== P4: A m4-7 kk1; stage Bk1(t+1); gate Ak0,Bk0(t+1) ========
#pragma unroll
    for (int m = 0; m < 4; ++m)
      af[m] = *(const s16x8*)&As[buf][8192 + (wr * 8 + 4 + m) * 512 + lo];
    if (pre) {
      gload16(Bt + boff[2] + nk64, &Bs[nbuf][ldso[2]]);
      gload16(Bt + boff[3] + nk64, &Bs[nbuf][ldso[3]]);
    }
    asm volatile("s_waitcnt vmcnt(4)" ::: "memory");
    __builtin_amdgcn_s_barrier();
    __builtin_amdgcn_s_setprio(1);
#pragma unroll
    for (int m = 0; m < 4; ++m)
#pragma unroll
      for (int n = 0; n < 4; ++n)
        acc[m + 4][n] = __builtin_amdgcn_mfma_f32_16x16x32_bf16(
            af[m], bfr[n], acc[m + 4][n], 0, 0, 0);
    __builtin_amdgcn_s_setprio(0);
    __builtin_amdgcn_s_barrier();
  }
  // ---- epilogue ----
#pragma unroll
  for (int n = 0; n < 4; ++n) {
    int col = nb + wc * 64 + n * 16 + lm;
    float bv = HAS_BIAS ? bias[col] : 0.0f;
#pragma unroll
    for (int m = 0; m < 8; ++m) {
#pragma unroll
      for (int r = 0; r < 4; ++r) {
        int row = mb + wr * 128 + m * 16 + lg * 4 + r;
        float v = acc[m][n][r] + bv;
        if (HAS_RES) v += Res[(size_t)row * N + col];
        if (RELU) v = v > 0.f ? v : 0.f;
        if (OUT_BF16)
          Cb[(size_t)row * N + col] = f2bf(v);
        else
          Cf[(size_t)row * N + col] = v;
      }
    }
  }
}

// ---------- flash attention: 64 q-rows/block, 4 waves x 16 rows ----------
__global__ __launch_bounds__(256) void k_attn(
    const u16* __restrict__ qkv, u16* __restrict__ o) {
  constexpr int KP = 72;
  constexpr int VP = 40;
  constexpr int PP = 40;
  __shared__ u16 Ks[32 * KP];
  __shared__ u16 Vt[64 * VP];
  __shared__ u16 Ps[4][16 * PP];
  int bid = blockIdx.x;
  int qt = bid & 15, h = (bid >> 4) & 15, b = bid >> 8;
  int tid = threadIdx.x, lane = tid & 63, wid = tid >> 6;
  int lm = lane & 15, lg = lane >> 4;
  const size_t rowbase = (size_t)b * T * C3 + (size_t)h * HS;
  int qb = qt * 64;
  int qw = qb + wid * 16;
  const float scale = 0.125f;

  s16x8 qf[2];
#pragma unroll
  for (int s = 0; s < 2; ++s)
    qf[s] = *(const s16x8*)&qkv[rowbase + (size_t)(qw + lm) * C3 + s * 32 + lg * 8];

  float m_[4], l_[4];
  f32x4 oacc[4];
#pragma unroll
  for (int r = 0; r < 4; ++r) { m_[r] = -3e38f; l_[r] = 0.f; }
#pragma unroll
  for (int n = 0; n < 4; ++n) oacc[n] = f32x4{0.f, 0.f, 0.f, 0.f};

  int nkt = (qb + 64) >> 5;
  int sr = tid >> 3, sc8 = (tid & 7) * 8;
  for (int kt = 0; kt < nkt; ++kt) {
    __syncthreads();
    {
      s16x8 kv = *(const s16x8*)&qkv[rowbase + C + (size_t)(kt * 32 + sr) * C3 + sc8];
      *(s16x8*)&Ks[sr * KP + sc8] = kv;
      s16x8 vv = *(const s16x8*)&qkv[rowbase + 2 * C + (size_t)(kt * 32 + sr) * C3 + sc8];
#pragma unroll
      for (int j = 0; j < 8; ++j) Vt[(sc8 + j) * VP + sr] = (u16)vv[j];
    }
    __syncthreads();
    f32x4 s0 = f32x4{0.f, 0.f, 0.f, 0.f}, s1 = f32x4{0.f, 0.f, 0.f, 0.f};
#pragma unroll
    for (int s = 0; s < 2; ++s) {
      s16x8 k0 = *(const s16x8*)&Ks[lm * KP + s * 32 + lg * 8];
      s16x8 k1 = *(const s16x8*)&Ks[(16 + lm) * KP + s * 32 + lg * 8];
      s0 = __builtin_amdgcn_mfma_f32_16x16x32_bf16(qf[s], k0, s0, 0, 0, 0);
      s1 = __builtin_amdgcn_mfma_f32_16x16x32_bf16(qf[s], k1, s1, 0, 0, 0);
    }
    int c0 = kt * 32 + lm, c1 = c0 + 16;
    float rmax[4];
#pragma unroll
    for (int r = 0; r < 4; ++r) {
      int row = qw + lg * 4 + r;
      float v0 = (c0 <= row) ? s0[r] * scale : -3e38f;
      float v1 = (c1 <= row) ? s1[r] * scale : -3e38f;
      s0[r] = v0; s1[r] = v1;
      rmax[r] = fmaxf(v0, v1);
    }
#pragma unroll
    for (int mm = 1; mm < 16; mm <<= 1)
#pragma unroll
      for (int r = 0; r < 4; ++r)
        rmax[r] = fmaxf(rmax[r], __shfl_xor(rmax[r], mm, 16));
    float alpha[4], rsum[4];
#pragma unroll
    for (int r = 0; r < 4; ++r) {
      float mn = fmaxf(m_[r], rmax[r]);
      alpha[r] = __expf(m_[r] - mn);
      m_[r] = mn;
      s0[r] = __expf(s0[r] - mn);
      s1[r] = __expf(s1[r] - mn);
      rsum[r] = s0[r] + s1[r];
    }
#pragma unroll
    for (int mm = 1; mm < 16; mm <<= 1)
#pragma unroll
      for (int r = 0; r < 4; ++r) rsum[r] += __shfl_xor(rsum[r], mm, 16);
#pragma unroll
    for (int r = 0; r < 4; ++r) l_[r] = l_[r] * alpha[r] + rsum[r];
#pragma unroll
    for (int n = 0; n < 4; ++n)
#pragma unroll
      for (int r = 0; r < 4; ++r) oacc[n][r] *= alpha[r];
#pragma unroll
    for (int r = 0; r < 4; ++r) {
      int pr = lg * 4 + r;
      Ps[wid][pr * PP + lm] = f2bf(s0[r]);
      Ps[wid][pr * PP + 16 + lm] = f2bf(s1[r]);
    }
    s16x8 pa = *(const s16x8*)&Ps[wid][lm * PP + lg * 8];
#pragma unroll
    for (int n = 0; n < 4; ++n) {
      s16x8 vf = *(const s16x8*)&Vt[(n * 16 + lm) * VP + lg * 8];
      oacc[n] = __builtin_amdgcn_mfma_f32_16x16x32_bf16(pa, vf, oacc[n], 0, 0, 0);
    }
  }
  const size_t obase = (size_t)b * T * C + (size_t)h * HS;
  float inv[4];
#pragma unroll
  for (int r = 0; r < 4; ++r) inv[r] = 1.0f / l_[r];
#pragma unroll
  for (int n = 0; n < 4; ++n)
#pragma unroll
    for (int r = 0; r < 4; ++r)
      o[obase + (size_t)(qw + lg * 4 + r) * C + n * 16 + lm] =
          f2bf(oacc[n][r] * inv[r]);
}

// ---------- LayerNorm ----------
__global__ __launch_bounds__(256) void k_ln(
    const float* __restrict__ in, const float* __restrict__ g,
    const float* __restrict__ bsh, float* __restrict__ xout,
    u16* __restrict__ xbout) {
  int row = blockIdx.x;
  const float* xr = in + (size_t)row * C;
  int tid = threadIdx.x;
  float vals[4];
  float s = 0.f;
#pragma unroll
  for (int i = 0; i < 4; ++i) {
    float vv = xr[tid + i * 256];
    vals[i] = vv;
    s += vv;
  }
  s = blockReduceSum(s);
  float mean = s * (1.0f / C);
  float s2 = 0.f;
#pragma unroll
  for (int i = 0; i < 4; ++i) {
    float d = vals[i] - mean;
    s2 += d * d;
  }
  s2 = blockReduceSum(s2);
  float rstd = rsqrtf(s2 * (1.0f / C) + 1e-5f);
#pragma unroll
  for (int i = 0; i < 4; ++i) {
    int c = tid + i * 256;
    float y = (vals[i] - mean) * rstd * g[c] + bsh[c];
    xout[(size_t)row * C + c] = y;
    xbout[(size_t)row * C + c] = f2bf(y);
  }
}

// ---------- loss: single-pass online logsumexp per row ----------
__global__ __launch_bounds__(256) void k_rowloss(
    const float* __restrict__ logits, const int* __restrict__ tgt,
    float* __restrict__ rowloss) {
  int row = blockIdx.x;
  const float* lr = logits + (size_t)row * V;
  const f32x4* lr4 = (const f32x4*)lr;
  int tid = threadIdx.x;
  float m = -3e38f, s = 0.f;
  for (int i = tid; i < V / 4; i += 256) {
    f32x4 v = lr4[i];
#pragma unroll
    for (int j = 0; j < 4; ++j) {
      float x = v[j];
      if (x > m) {
        s = s * __expf(m - x) + 1.f;
        m = x;
      } else {
        s += __expf(x - m);
      }
    }
  }
#pragma unroll
  for (int d = 1; d < 64; d <<= 1) {
    float mo = __shfl_xor(m, d, 64), so = __shfl_xor(s, d, 64);
    float mn = fmaxf(m, mo);
    s = s * __expf(m - mn) + so * __expf(mo - mn);
    m = mn;
  }
  __shared__ float sm[4], ss[4];
  int w = tid >> 6;
  if ((tid & 63) == 0) { sm[w] = m; ss[w] = s; }
  __syncthreads();
  if (tid == 0) {
    float M = fmaxf(fmaxf(sm[0], sm[1]), fmaxf(sm[2], sm[3]));
    float S = ss[0] * __expf(sm[0] - M) + ss[1] * __expf(sm[1] - M) +
              ss[2] * __expf(sm[2] - M) + ss[3] * __expf(sm[3] - M);
    rowloss[row] = (M + logf(S)) - lr[tgt[row]];
  }
}

__global__ __launch_bounds__(256) void k_lossreduce(
    const float* __restrict__ rowloss, float* __restrict__ out) {
  __shared__ float red[256];
  int tid = threadIdx.x;
  float s = 0.f;
  for (int i = tid; i < BT; i += 256) s += rowloss[i];
  red[tid] = s;
  __syncthreads();
  for (int m = 128; m >= 1; m >>= 1) {
    if (tid < m) red[tid] += red[tid + m];
    __syncthreads();
  }
  if (tid == 0) out[0] = red[0] * (1.0f / BT);
}

// ---------------- host orchestration ----------------
extern "C" void kernel_launch(void* const* d_in, const int* in_sizes, int n_in,
                              void* d_out, int out_size, void* d_ws,
                              size_t ws_size, hipStream_t stream) {
  (void)in_sizes; (void)n_in; (void)out_size; (void)ws_size;
  const int* index = (const int*)d_in[0];
  const int* targets = (const int*)d_in[1];
  const float* tok_emb = (const float*)d_in[2];
  const float* pos_emb = (const float*)d_in[3];
  const float* wq = (const float*)d_in[4];
  const float* wk = (const float*)d_in[5];
  const float* wv = (const float*)d_in[6];
  const float* wo = (const float*)d_in[7];
  const float* bo = (const float*)d_in[8];
  const float* w1 = (const float*)d_in[9];
  const float* b1 = (const float*)d_in[10];
  const float* w2 = (const float*)d_in[11];
  const float* b2 = (const float*)d_in[12];
  const float* ln1_g = (const float*)d_in[13];
  const float* ln1_b = (const float*)d_in[14];
  const float* ln2_g = (const float*)d_in[15];
  const float* ln2_b = (const float*)d_in[16];
  const float* lnf_g = (const float*)d_in[17];
  const float* lnf_b = (const float*)d_in[18];
  const float* lm_w = (const float*)d_in[19];
  const float* lm_b = (const float*)d_in[20];

  float* logits = (float*)d_out;
  float* loss = logits + (size_t)BT * V;

  size_t off = 0;
  auto alloc = [&](size_t bytes) -> void* {
    off = (off + 255) & ~(size_t)255;
    void* p = (void*)((char*)d_ws + off);
    off += bytes;
    return p;
  };
  u16* wqkv_t = (u16*)alloc((size_t)L * C3 * C * 2);  // [L][3C][C]
  u16* wo_t = (u16*)alloc((size_t)L * C * C * 2);
  u16* w1_t = (u16*)alloc((size_t)L * C * C4 * 2);
  u16* w2_t = (u16*)alloc((size_t)L * C4 * C * 2);
  u16* lmw_t = (u16*)alloc((size_t)V * C * 2);
  float* x = (float*)alloc((size_t)BT * C * 4);
  float* tmp = (float*)alloc((size_t)BT * C * 4);
  u16* xb = (u16*)alloc((size_t)BT * C * 2);
  u16* qkvb = (u16*)alloc((size_t)BT * C3 * 2);
  u16* attb = (u16*)alloc((size_t)BT * C * 2);
  u16* hb = (u16*)alloc((size_t)BT * C4 * 2);
  float* rowloss = (float*)alloc((size_t)BT * 4);

  dim3 blk(256);
  dim3 blk5(512);
  k_transpose<<<dim3(C / 64, C / 64, L), blk, 0, stream>>>(
      wq, wqkv_t, C, C, (size_t)C * C, (size_t)C3 * C);
  k_transpose<<<dim3(C / 64, C / 64, L), blk, 0, stream>>>(
      wk, wqkv_t + (size_t)C * C, C, C, (size_t)C * C, (size_t)C3 * C);
  k_transpose<<<dim3(C / 64, C / 64, L), blk, 0, stream>>>(
      wv, wqkv_t + (size_t)2 * C * C, C, C, (size_t)C * C, (size_t)C3 * C);
  k_transpose<<<dim3(C / 64, C / 64, L), blk, 0, stream>>>(
      wo, wo_t, C, C, (size_t)C * C, (size_t)C * C);
  k_transpose<<<dim3(C4 / 64, C / 64, L), blk, 0, stream>>>(
      w1, w1_t, C, C4, (size_t)C * C4, (size_t)C * C4);
  k_transpose<<<dim3(C / 64, C4 / 64, L), blk, 0, stream>>>(
      w2, w2_t, C4, C, (size_t)C4 * C, (size_t)C4 * C);
  k_transpose<<<dim3(V / 64, C / 64, 1), blk, 0, stream>>>(
      lm_w, lmw_t, C, V, 0, 0);

  k_embed<<<BT, blk, 0, stream>>>(index, tok_emb, pos_emb, x, xb);

  dim3 gQKV(C3 / 256, BT / 256);
  dim3 gCC(C / 256, BT / 256);
  dim3 gC4(C4 / 256, BT / 256);
  for (int l = 0; l < L; ++l) {
    const u16* wqkvt = wqkv_t + (size_t)l * C3 * C;
    const u16* wot = wo_t + (size_t)l * C * C;
    const u16* w1t = w1_t + (size_t)l * C * C4;
    const u16* w2t = w2_t + (size_t)l * C4 * C;

    k_gemm256<1, 0, 0, 0><<<gQKV, blk5, 0, stream>>>(
        xb, wqkvt, nullptr, nullptr, nullptr, qkvb, BT, C3, C);
    k_attn<<<B * H * (T / 64), blk, 0, stream>>>(qkvb, attb);
    k_gemm256<0, 0, 1, 1><<<gCC, blk5, 0, stream>>>(
        attb, wot, bo + (size_t)l * C, x, tmp, nullptr, BT, C, C);
    k_ln<<<BT, blk, 0, stream>>>(tmp, ln1_g + (size_t)l * C,
                                 ln1_b + (size_t)l * C, x, xb);
    k_gemm256<1, 1, 1, 0><<<gC4, blk5, 0, stream>>>(
        xb, w1t, b1 + (size_t)l * C4, nullptr, nullptr, hb, BT, C4, C);
    k_gemm256<0, 0, 1, 1><<<gCC, blk5, 0, stream>>>(
        hb, w2t, b2 + (size_t)l * C, x, tmp, nullptr, BT, C, C4);
    k_ln<<<BT, blk, 0, stream>>>(tmp, ln2_g + (size_t)l * C,
                                 ln2_b + (size_t)l * C, x, xb);
  }
  k_ln<<<BT, blk, 0, stream>>>(x, lnf_g, lnf_b, x, xb);
  k_gemm256<0, 0, 1, 0><<<dim3(V / 256, BT / 256), blk5, 0, stream>>>(
      xb, lmw_t, lm_b, nullptr, logits, nullptr, BT, V, C);
  k_rowloss<<<BT, blk, 0, stream>>>(logits, targets, rowloss);
  k_lossreduce<<<1, blk, 0, stream>>>(rowloss, loss);
}

// Round 4
// 3256.783 us; speedup vs baseline: 1.0888x; 1.0888x over previous
//
#include <hip/hip_runtime.h>

typedef unsigned short u16;
typedef __attribute__((ext_vector_type(4))) float f32x4;
typedef __attribute__((ext_vector_type(8))) short s16x8;

static constexpr int V = 32000;
static constexpr int C = 1024;
static constexpr int T = 1024;
static constexpr int H = 16;
static constexpr int L = 8;
static constexpr int B = 4;
static constexpr int HS = 64;
static constexpr int BT = B * T;   // 4096
static constexpr int C4 = 4 * C;   // 4096
static constexpr int C3 = 3 * C;   // 3072

__device__ __forceinline__ u16 f2bf(float f) {
  union { float f; unsigned u; } v; v.f = f;
  unsigned r = v.u + 0x7fffu + ((v.u >> 16) & 1u);
  return (u16)(r >> 16);
}

__device__ __forceinline__ void gload16(const u16* g, u16* l) {
  __builtin_amdgcn_global_load_lds(
      (const __attribute__((address_space(1))) void*)g,
      (__attribute__((address_space(3))) void*)l, 16, 0, 0);
}

// ---------- block reduction (256 threads) ----------
__device__ __forceinline__ float blockReduceSum(float v) {
  __shared__ float red[4];
  int lane = threadIdx.x & 63, w = threadIdx.x >> 6;
#pragma unroll
  for (int m = 32; m >= 1; m >>= 1) v += __shfl_xor(v, m, 64);
  if (lane == 0) red[w] = v;
  __syncthreads();
  float r = red[0] + red[1] + red[2] + red[3];
  __syncthreads();
  return r;
}

// ---------- embed ----------
__global__ __launch_bounds__(256) void k_embed(
    const int* __restrict__ idx, const float* __restrict__ tok,
    const float* __restrict__ pos, float* __restrict__ x, u16* __restrict__ xb) {
  int bt = blockIdx.x;
  int t = bt & (T - 1);
  int row = idx[bt];
  const float* te = tok + (size_t)row * C;
  const float* pe = pos + (size_t)t * C;
  float* xo = x + (size_t)bt * C;
  u16* xbo = xb + (size_t)bt * C;
  for (int c = threadIdx.x; c < C; c += 256) {
    float v = te[c] + pe[c];
    xo[c] = v;
    xbo[c] = f2bf(v);
  }
}

// ---------- weight convert+transpose: fp32 [K,N] -> bf16 [N,K] ----------
__global__ __launch_bounds__(256) void k_transpose(
    const float* __restrict__ W, u16* __restrict__ Wt, int K, int N,
    size_t sW, size_t sWt) {
  __shared__ float tile[64][65];
  const float* Wz = W + sW * blockIdx.z;
  u16* Wtz = Wt + sWt * blockIdx.z;
  int n0 = blockIdx.x * 64, k0 = blockIdx.y * 64;
  int tc = threadIdx.x & 63, tr = threadIdx.x >> 6;
#pragma unroll
  for (int i = 0; i < 16; ++i) {
    int r = tr + i * 4;
    tile[r][tc] = Wz[(size_t)(k0 + r) * N + (n0 + tc)];
  }
  __syncthreads();
#pragma unroll
  for (int i = 0; i < 16; ++i) {
    int r = tr + i * 4;  // n-offset within tile
    Wtz[(size_t)(n0 + r) * K + (k0 + tc)] = f2bf(tile[tc][r]);
  }
}

// ---------- GEMM 128x128 (m97 structure) for small-N shapes ----------
template <int OUT_BF16, int RELU, int HAS_BIAS, int HAS_RES>
__global__ __launch_bounds__(256, 2) void k_gemm(
    const u16* __restrict__ A, const u16* __restrict__ Bt,
    const float* __restrict__ bias, const float* __restrict__ Res,
    float* __restrict__ Cf, u16* __restrict__ Cb, int M, int N, int K) {
  __shared__ u16 As[128 * 32];
  __shared__ u16 Bs[128 * 32];
  int tid = threadIdx.x;
  int lane = tid & 63, wid = tid >> 6;
  int lm = lane & 15, lg = lane >> 4;
  int wm = wid >> 1, wn = wid & 1;

  unsigned nbx = gridDim.x;
  unsigned nwg = nbx * gridDim.y;
  unsigned orig = blockIdx.y * nbx + blockIdx.x;
  unsigned f = ((nwg & 7u) == 0u) ? (orig & 7u) * (nwg >> 3) + (orig >> 3) : orig;
  int mb = (int)(f / nbx) * 128, nb = (int)(f % nbx) * 128;

  f32x4 acc[4][4];
#pragma unroll
  for (int i = 0; i < 4; ++i)
#pragma unroll
    for (int j = 0; j < 4; ++j) acc[i][j] = f32x4{0.f, 0.f, 0.f, 0.f};

  int r0 = tid >> 2, q0 = tid & 3;
  int r1 = (256 + tid) >> 2, q1 = tid & 3;
  const u16* a0 = A + (size_t)(mb + r0) * K + q0 * 8;
  const u16* a1 = A + (size_t)(mb + r1) * K + q1 * 8;
  const u16* b0 = Bt + (size_t)(nb + r0) * K + q0 * 8;
  const u16* b1 = Bt + (size_t)(nb + r1) * K + q1 * 8;
  u16* lA0 = &As[wid * 512];
  u16* lA1 = &As[2048 + wid * 512];
  u16* lB0 = &Bs[wid * 512];
  u16* lB1 = &Bs[2048 + wid * 512];

  int nK = K >> 5;
  for (int kb = 0; kb < nK; ++kb) {
    __syncthreads();
    int ko = kb * 32;
    gload16(a0 + ko, lA0);
    gload16(a1 + ko, lA1);
    gload16(b0 + ko, lB0);
    gload16(b1 + ko, lB1);
    __syncthreads();
    s16x8 af[4], bfr[4];
#pragma unroll
    for (int m = 0; m < 4; ++m)
      af[m] = *(const s16x8*)&As[(wm * 64 + m * 16 + lm) * 32 + lg * 8];
#pragma unroll
    for (int n = 0; n < 4; ++n)
      bfr[n] = *(const s16x8*)&Bs[(wn * 64 + n * 16 + lm) * 32 + lg * 8];
#pragma unroll
    for (int m = 0; m < 4; ++m)
#pragma unroll
      for (int n = 0; n < 4; ++n)
        acc[m][n] = __builtin_amdgcn_mfma_f32_16x16x32_bf16(af[m], bfr[n],
                                                            acc[m][n], 0, 0, 0);
  }
#pragma unroll
  for (int m = 0; m < 4; ++m) {
#pragma unroll
    for (int n = 0; n < 4; ++n) {
      int col = nb + wn * 64 + n * 16 + lm;
      float bv = HAS_BIAS ? bias[col] : 0.0f;
#pragma unroll
      for (int r = 0; r < 4; ++r) {
        int row = mb + wm * 64 + m * 16 + lg * 4 + r;
        float v = acc[m][n][r] + bv;
        if (HAS_RES) v += Res[(size_t)row * N + col];
        if (RELU) v = v > 0.f ? v : 0.f;
        if (OUT_BF16)
          Cb[(size_t)row * N + col] = f2bf(v);
        else
          Cf[(size_t)row * N + col] = v;
      }
    }
  }
}

// ---------- GEMM 256x256 8-phase (T2+T3+T4+T5) for big-N shapes ----------
// 512 threads = 8 waves (2M x 4N), BK=64 (2 kk-halves). Counted vmcnt:
// kk1 gate moved to P3 (vmcnt 6), P4 gates next kk0 (vmcnt 4); drain only
// on last tile.
template <int OUT_BF16, int RELU, int HAS_BIAS, int HAS_RES>
__global__ __launch_bounds__(512) void k_gemm256(
    const u16* __restrict__ A, const u16* __restrict__ Bt,
    const float* __restrict__ bias, const float* __restrict__ Res,
    float* __restrict__ Cf, u16* __restrict__ Cb, int M, int N, int K) {
  __shared__ u16 As[2][16384];
  __shared__ u16 Bs[2][16384];
  const int tid = threadIdx.x;
  const int lane = tid & 63, wid = tid >> 6;
  const int lm = lane & 15, lg = lane >> 4;
  const int wr = wid >> 2, wc = wid & 3;

  unsigned nbx = gridDim.x;
  unsigned nwg = nbx * gridDim.y;
  unsigned orig = blockIdx.y * nbx + blockIdx.x;
  unsigned f = ((nwg & 7u) == 0u) ? (orig & 7u) * (nwg >> 3) + (orig >> 3) : orig;
  const int mb = (int)(f / nbx) * 256, nb = (int)(f % nbx) * 256;

  int aoff[4], boff[4], ldso[4];
#pragma unroll
  for (int h = 0; h < 4; ++h) {
    const int kk = h >> 1, p = h & 1;
    int rem = p * 512 + tid;
    int rblk = rem >> 6;
    int rem2 = rem & 63;
    int row16 = rem2 >> 2, psl = rem2 & 3;
    int sl = psl ^ ((row16 >> 1) & 3);
    int grow = rblk * 16 + row16;
    int gk = kk * 32 + sl * 8;
    aoff[h] = (mb + grow) * K + gk;
    boff[h] = (nb + grow) * K + gk;
    ldso[h] = kk * 8192 + p * 4096 + wid * 512;
  }
  const int lo = lm * 32 + ((lg ^ ((lm >> 1) & 3)) << 3);

  f32x4 acc[8][4];
#pragma unroll
  for (int i = 0; i < 8; ++i)
#pragma unroll
    for (int j = 0; j < 4; ++j) acc[i][j] = f32x4{0.f, 0.f, 0.f, 0.f};

  const int nK = K >> 6;
  // prologue: stage tile 0, gate kk0
  gload16(A + aoff[0], &As[0][ldso[0]]);
  gload16(A + aoff[1], &As[0][ldso[1]]);
  gload16(Bt + boff[0], &Bs[0][ldso[0]]);
  gload16(Bt + boff[1], &Bs[0][ldso[1]]);
  gload16(A + aoff[2], &As[0][ldso[2]]);
  gload16(A + aoff[3], &As[0][ldso[3]]);
  gload16(Bt + boff[2], &Bs[0][ldso[2]]);
  gload16(Bt + boff[3], &Bs[0][ldso[3]]);
  asm volatile("s_waitcnt vmcnt(4)" ::: "memory");
  __builtin_amdgcn_s_barrier();

  for (int t = 0; t < nK; ++t) {
    const int buf = t & 1, nbuf = buf ^ 1;
    const bool pre = (t + 1 < nK);
    const int nk64 = (t + 1) * 64;
    s16x8 af[4], bfr[4];
    // ======== P1: kk0 A m0-3 + B; stage Ak0(t+1); no wait ========
#pragma unroll
    for (int m = 0; m < 4; ++m)
      af[m] = *(const s16x8*)&As[buf][(wr * 8 + m) * 512 + lo];
#pragma unroll
    for (int n = 0; n < 4; ++n)
      bfr[n] = *(const s16x8*)&Bs[buf][(wc * 4 + n) * 512 + lo];
    if (pre) {
      gload16(A + aoff[0] + nk64, &As[nbuf][ldso[0]]);
      gload16(A + aoff[1] + nk64, &As[nbuf][ldso[1]]);
    }
    __builtin_amdgcn_s_barrier();
    __builtin_amdgcn_s_setprio(1);
#pragma unroll
    for (int m = 0; m < 4; ++m)
#pragma unroll
      for (int n = 0; n < 4; ++n)
        acc[m][n] = __builtin_amdgcn_mfma_f32_16x16x32_bf16(af[m], bfr[n],
                                                            acc[m][n], 0, 0, 0);
    __builtin_amdgcn_s_setprio(0);
    __builtin_amdgcn_s_barrier();
    // ======== P2: kk0 A m4-7; stage Bk0(t+1) ========
#pragma unroll
    for (int m = 0; m < 4; ++m)
      af[m] = *(const s16x8*)&As[buf][(wr * 8 + 4 + m) * 512 + lo];
    if (pre) {
      gload16(Bt + boff[0] + nk64, &Bs[nbuf][ldso[0]]);
      gload16(Bt + boff[1] + nk64, &Bs[nbuf][ldso[1]]);
    }
    __builtin_amdgcn_s_barrier();
    __builtin_amdgcn_s_setprio(1);
#pragma unroll
    for (int m = 0; m < 4; ++m)
#pragma unroll
      for (int n = 0; n < 4; ++n)
        acc[m + 4][n] = __builtin_amdgcn_mfma_f32_16x16x32_bf16(
            af[m], bfr[n], acc[m + 4][n], 0, 0, 0);
    __builtin_amdgcn_s_setprio(0);
    __builtin_amdgcn_s_barrier();
    // ======== P3: kk1 A m0-3 + B; stage Ak1(t+1); gate kk1(t) ========
#pragma unroll
    for (int m = 0; m < 4; ++m)
      af[m] = *(const s16x8*)&As[buf][8192 + (wr * 8 + m) * 512 + lo];
#pragma unroll
    for (int n = 0; n < 4; ++n)
      bfr[n] = *(const s16x8*)&Bs[buf][8192 + (wc * 4 + n) * 512 + lo];
    if (pre) {
      gload16(A + aoff[2] + nk64, &As[nbuf][ldso[2]]);
      gload16(A + aoff[3] + nk64, &As[nbuf][ldso[3]]);
      asm volatile("s_waitcnt vmcnt(6)" ::: "memory");
    } else {
      asm volatile("s_waitcnt vmcnt(0)" ::: "memory");
    }
    __builtin_amdgcn_s_barrier();
    __builtin_amdgcn_s_setprio(1);
#pragma unroll
    for (int m = 0; m < 4; ++m)
#pragma unroll
      for (int n = 0; n < 4; ++n)
        acc[m][n] = __builtin_amdgcn_mfma_f32_16x16x32_bf16(af[m], bfr[n],
                                                            acc[m][n], 0, 0, 0);
    __builtin_amdgcn_s_setprio(0);
    __builtin_amdgcn_s_barrier();
    // ======== P4: kk1 A m4-7; stage Bk1(t+1); gate kk0(t+1) ========
#pragma unroll
    for (int m = 0; m < 4; ++m)
      af[m] = *(const s16x8*)&As[buf][8192 + (wr * 8 + 4 + m) * 512 + lo];
    if (pre) {
      gload16(Bt + boff[2] + nk64, &Bs[nbuf][ldso[2]]);
      gload16(Bt + boff[3] + nk64, &Bs[nbuf][ldso[3]]);
      asm volatile("s_waitcnt vmcnt(4)" ::: "memory");
    }
    __builtin_amdgcn_s_barrier();
    __builtin_amdgcn_s_setprio(1);
#pragma unroll
    for (int m = 0; m < 4; ++m)
#pragma unroll
      for (int n = 0; n < 4; ++n)
        acc[m + 4][n] = __builtin_amdgcn_mfma_f32_16x16x32_bf16(
            af[m], bfr[n], acc[m + 4][n], 0, 0, 0);
    __builtin_amdgcn_s_setprio(0);
    __builtin_amdgcn_s_barrier();
  }
  // ---- epilogue: n-inner so each row's 4 stores cover 256 contiguous B ----
  float bv[4];
#pragma unroll
  for (int n = 0; n < 4; ++n)
    bv[n] = HAS_BIAS ? bias[nb + wc * 64 + n * 16 + lm] : 0.0f;
#pragma unroll
  for (int m = 0; m < 8; ++m) {
#pragma unroll
    for (int r = 0; r < 4; ++r) {
      int row = mb + wr * 128 + m * 16 + lg * 4 + r;
#pragma unroll
      for (int n = 0; n < 4; ++n) {
        int col = nb + wc * 64 + n * 16 + lm;
        float v = acc[m][n][r] + bv[n];
        if (HAS_RES) v += Res[(size_t)row * N + col];
        if (RELU) v = v > 0.f ? v : 0.f;
        if (OUT_BF16)
          Cb[(size_t)row * N + col] = f2bf(v);
        else
          Cf[(size_t)row * N + col] = v;
      }
    }
  }
}

// ---------- flash attention: 64 q-rows/block, 4 waves x 16 rows ----------
__global__ __launch_bounds__(256) void k_attn(
    const u16* __restrict__ qkv, u16* __restrict__ o) {
  constexpr int KP = 72;
  constexpr int VP = 40;
  constexpr int PP = 40;
  __shared__ u16 Ks[32 * KP];
  __shared__ u16 Vt[64 * VP];
  __shared__ u16 Ps[4][16 * PP];
  int bid = blockIdx.x;
  int qt = bid & 15, h = (bid >> 4) & 15, b = bid >> 8;
  int tid = threadIdx.x, lane = tid & 63, wid = tid >> 6;
  int lm = lane & 15, lg = lane >> 4;
  const size_t rowbase = (size_t)b * T * C3 + (size_t)h * HS;
  int qb = qt * 64;
  int qw = qb + wid * 16;
  const float scale = 0.125f;

  s16x8 qf[2];
#pragma unroll
  for (int s = 0; s < 2; ++s)
    qf[s] = *(const s16x8*)&qkv[rowbase + (size_t)(qw + lm) * C3 + s * 32 + lg * 8];

  float m_[4], l_[4];
  f32x4 oacc[4];
#pragma unroll
  for (int r = 0; r < 4; ++r) { m_[r] = -3e38f; l_[r] = 0.f; }
#pragma unroll
  for (int n = 0; n < 4; ++n) oacc[n] = f32x4{0.f, 0.f, 0.f, 0.f};

  int nkt = (qb + 64) >> 5;
  int sr = tid >> 3, sc8 = (tid & 7) * 8;
  for (int kt = 0; kt < nkt; ++kt) {
    __syncthreads();
    {
      s16x8 kv = *(const s16x8*)&qkv[rowbase + C + (size_t)(kt * 32 + sr) * C3 + sc8];
      *(s16x8*)&Ks[sr * KP + sc8] = kv;
      s16x8 vv = *(const s16x8*)&qkv[rowbase + 2 * C + (size_t)(kt * 32 + sr) * C3 + sc8];
#pragma unroll
      for (int j = 0; j < 8; ++j) Vt[(sc8 + j) * VP + sr] = (u16)vv[j];
    }
    __syncthreads();
    f32x4 s0 = f32x4{0.f, 0.f, 0.f, 0.f}, s1 = f32x4{0.f, 0.f, 0.f, 0.f};
#pragma unroll
    for (int s = 0; s < 2; ++s) {
      s16x8 k0 = *(const s16x8*)&Ks[lm * KP + s * 32 + lg * 8];
      s16x8 k1 = *(const s16x8*)&Ks[(16 + lm) * KP + s * 32 + lg * 8];
      s0 = __builtin_amdgcn_mfma_f32_16x16x32_bf16(qf[s], k0, s0, 0, 0, 0);
      s1 = __builtin_amdgcn_mfma_f32_16x16x32_bf16(qf[s], k1, s1, 0, 0, 0);
    }
    int c0 = kt * 32 + lm, c1 = c0 + 16;
    float rmax[4];
#pragma unroll
    for (int r = 0; r < 4; ++r) {
      int row = qw + lg * 4 + r;
      float v0 = (c0 <= row) ? s0[r] * scale : -3e38f;
      float v1 = (c1 <= row) ? s1[r] * scale : -3e38f;
      s0[r] = v0; s1[r] = v1;
      rmax[r] = fmaxf(v0, v1);
    }
#pragma unroll
    for (int mm = 1; mm < 16; mm <<= 1)
#pragma unroll
      for (int r = 0; r < 4; ++r)
        rmax[r] = fmaxf(rmax[r], __shfl_xor(rmax[r], mm, 16));
    float alpha[4], rsum[4];
#pragma unroll
    for (int r = 0; r < 4; ++r) {
      float mn = fmaxf(m_[r], rmax[r]);
      alpha[r] = __expf(m_[r] - mn);
      m_[r] = mn;
      s0[r] = __expf(s0[r] - mn);
      s1[r] = __expf(s1[r] - mn);
      rsum[r] = s0[r] + s1[r];
    }
#pragma unroll
    for (int mm = 1; mm < 16; mm <<= 1)
#pragma unroll
      for (int r = 0; r < 4; ++r) rsum[r] += __shfl_xor(rsum[r], mm, 16);
#pragma unroll
    for (int r = 0; r < 4; ++r) l_[r] = l_[r] * alpha[r] + rsum[r];
#pragma unroll
    for (int n = 0; n < 4; ++n)
#pragma unroll
      for (int r = 0; r < 4; ++r) oacc[n][r] *= alpha[r];
#pragma unroll
    for (int r = 0; r < 4; ++r) {
      int pr = lg * 4 + r;
      Ps[wid][pr * PP + lm] = f2bf(s0[r]);
      Ps[wid][pr * PP + 16 + lm] = f2bf(s1[r]);
    }
    s16x8 pa = *(const s16x8*)&Ps[wid][lm * PP + lg * 8];
#pragma unroll
    for (int n = 0; n < 4; ++n) {
      s16x8 vf = *(const s16x8*)&Vt[(n * 16 + lm) * VP + lg * 8];
      oacc[n] = __builtin_amdgcn_mfma_f32_16x16x32_bf16(pa, vf, oacc[n], 0, 0, 0);
    }
  }
  const size_t obase = (size_t)b * T * C + (size_t)h * HS;
  float inv[4];
#pragma unroll
  for (int r = 0; r < 4; ++r) inv[r] = 1.0f / l_[r];
#pragma unroll
  for (int n = 0; n < 4; ++n)
#pragma unroll
    for (int r = 0; r < 4; ++r)
      o[obase + (size_t)(qw + lg * 4 + r) * C + n * 16 + lm] =
          f2bf(oacc[n][r] * inv[r]);
}

// ---------- LayerNorm ----------
__global__ __launch_bounds__(256) void k_ln(
    const float* __restrict__ in, const float* __restrict__ g,
    const float* __restrict__ bsh, float* __restrict__ xout,
    u16* __restrict__ xbout) {
  int row = blockIdx.x;
  const float* xr = in + (size_t)row * C;
  int tid = threadIdx.x;
  float vals[4];
  float s = 0.f;
#pragma unroll
  for (int i = 0; i < 4; ++i) {
    float vv = xr[tid + i * 256];
    vals[i] = vv;
    s += vv;
  }
  s = blockReduceSum(s);
  float mean = s * (1.0f / C);
  float s2 = 0.f;
#pragma unroll
  for (int i = 0; i < 4; ++i) {
    float d = vals[i] - mean;
    s2 += d * d;
  }
  s2 = blockReduceSum(s2);
  float rstd = rsqrtf(s2 * (1.0f / C) + 1e-5f);
#pragma unroll
  for (int i = 0; i < 4; ++i) {
    int c = tid + i * 256;
    float y = (vals[i] - mean) * rstd * g[c] + bsh[c];
    xout[(size_t)row * C + c] = y;
    xbout[(size_t)row * C + c] = f2bf(y);
  }
}

// ---------- loss: single-pass online logsumexp per row ----------
__global__ __launch_bounds__(256) void k_rowloss(
    const float* __restrict__ logits, const int* __restrict__ tgt,
    float* __restrict__ rowloss) {
  int row = blockIdx.x;
  const float* lr = logits + (size_t)row * V;
  const f32x4* lr4 = (const f32x4*)lr;
  int tid = threadIdx.x;
  float m = -3e38f, s = 0.f;
  for (int i = tid; i < V / 4; i += 256) {
    f32x4 v = lr4[i];
#pragma unroll
    for (int j = 0; j < 4; ++j) {
      float x = v[j];
      if (x > m) {
        s = s * __expf(m - x) + 1.f;
        m = x;
      } else {
        s += __expf(x - m);
      }
    }
  }
#pragma unroll
  for (int d = 1; d < 64; d <<= 1) {
    float mo = __shfl_xor(m, d, 64), so = __shfl_xor(s, d, 64);
    float mn = fmaxf(m, mo);
    s = s * __expf(m - mn) + so * __expf(mo - mn);
    m = mn;
  }
  __shared__ float sm[4], ss[4];
  int w = tid >> 6;
  if ((tid & 63) == 0) { sm[w] = m; ss[w] = s; }
  __syncthreads();
  if (tid == 0) {
    float M = fmaxf(fmaxf(sm[0], sm[1]), fmaxf(sm[2], sm[3]));
    float S = ss[0] * __expf(sm[0] - M) + ss[1] * __expf(sm[1] - M) +
              ss[2] * __expf(sm[2] - M) + ss[3] * __expf(sm[3] - M);
    rowloss[row] = (M + logf(S)) - lr[tgt[row]];
  }
}

__global__ __launch_bounds__(256) void k_lossreduce(
    const float* __restrict__ rowloss, float* __restrict__ out) {
  __shared__ float red[256];
  int tid = threadIdx.x;
  float s = 0.f;
  for (int i = tid; i < BT; i += 256) s += rowloss[i];
  red[tid] = s;
  __syncthreads();
  for (int m = 128; m >= 1; m >>= 1) {
    if (tid < m) red[tid] += red[tid + m];
    __syncthreads();
  }
  if (tid == 0) out[0] = red[0] * (1.0f / BT);
}

// ---------------- host orchestration ----------------
extern "C" void kernel_launch(void* const* d_in, const int* in_sizes, int n_in,
                              void* d_out, int out_size, void* d_ws,
                              size_t ws_size, hipStream_t stream) {
  (void)in_sizes; (void)n_in; (void)out_size; (void)ws_size;
  const int* index = (const int*)d_in[0];
  const int* targets = (const int*)d_in[1];
  const float* tok_emb = (const float*)d_in[2];
  const float* pos_emb = (const float*)d_in[3];
  const float* wq = (const float*)d_in[4];
  const float* wk = (const float*)d_in[5];
  const float* wv = (const float*)d_in[6];
  const float* wo = (const float*)d_in[7];
  const float* bo = (const float*)d_in[8];
  const float* w1 = (const float*)d_in[9];
  const float* b1 = (const float*)d_in[10];
  const float* w2 = (const float*)d_in[11];
  const float* b2 = (const float*)d_in[12];
  const float* ln1_g = (const float*)d_in[13];
  const float* ln1_b = (const float*)d_in[14];
  const float* ln2_g = (const float*)d_in[15];
  const float* ln2_b = (const float*)d_in[16];
  const float* lnf_g = (const float*)d_in[17];
  const float* lnf_b = (const float*)d_in[18];
  const float* lm_w = (const float*)d_in[19];
  const float* lm_b = (const float*)d_in[20];

  float* logits = (float*)d_out;
  float* loss = logits + (size_t)BT * V;

  size_t off = 0;
  auto alloc = [&](size_t bytes) -> void* {
    off = (off + 255) & ~(size_t)255;
    void* p = (void*)((char*)d_ws + off);
    off += bytes;
    return p;
  };
  u16* wqkv_t = (u16*)alloc((size_t)L * C3 * C * 2);  // [L][3C][C]
  u16* wo_t = (u16*)alloc((size_t)L * C * C * 2);
  u16* w1_t = (u16*)alloc((size_t)L * C * C4 * 2);
  u16* w2_t = (u16*)alloc((size_t)L * C4 * C * 2);
  u16* lmw_t = (u16*)alloc((size_t)V * C * 2);
  float* x = (float*)alloc((size_t)BT * C * 4);
  float* tmp = (float*)alloc((size_t)BT * C * 4);
  u16* xb = (u16*)alloc((size_t)BT * C * 2);
  u16* qkvb = (u16*)alloc((size_t)BT * C3 * 2);
  u16* attb = (u16*)alloc((size_t)BT * C * 2);
  u16* hb = (u16*)alloc((size_t)BT * C4 * 2);
  float* rowloss = (float*)alloc((size_t)BT * 4);

  dim3 blk(256);
  dim3 blk5(512);
  k_transpose<<<dim3(C / 64, C / 64, L), blk, 0, stream>>>(
      wq, wqkv_t, C, C, (size_t)C * C, (size_t)C3 * C);
  k_transpose<<<dim3(C / 64, C / 64, L), blk, 0, stream>>>(
      wk, wqkv_t + (size_t)C * C, C, C, (size_t)C * C, (size_t)C3 * C);
  k_transpose<<<dim3(C / 64, C / 64, L), blk, 0, stream>>>(
      wv, wqkv_t + (size_t)2 * C * C, C, C, (size_t)C * C, (size_t)C3 * C);
  k_transpose<<<dim3(C / 64, C / 64, L), blk, 0, stream>>>(
      wo, wo_t, C, C, (size_t)C * C, (size_t)C * C);
  k_transpose<<<dim3(C4 / 64, C / 64, L), blk, 0, stream>>>(
      w1, w1_t, C, C4, (size_t)C * C4, (size_t)C * C4);
  k_transpose<<<dim3(C / 64, C4 / 64, L), blk, 0, stream>>>(
      w2, w2_t, C4, C, (size_t)C4 * C, (size_t)C4 * C);
  k_transpose<<<dim3(V / 64, C / 64, 1), blk, 0, stream>>>(
      lm_w, lmw_t, C, V, 0, 0);

  k_embed<<<BT, blk, 0, stream>>>(index, tok_emb, pos_emb, x, xb);

  dim3 gQKV(C3 / 128, BT / 128);   // 24 x 32 = 768 wg
  dim3 gCC(C / 128, BT / 128);     // 8 x 32 = 256 wg
  dim3 gC4(C4 / 256, BT / 256);    // 16 x 16 = 256 wg (256^2 tile)
  for (int l = 0; l < L; ++l) {
    const u16* wqkvt = wqkv_t + (size_t)l * C3 * C;
    const u16* wot = wo_t + (size_t)l * C * C;
    const u16* w1t = w1_t + (size_t)l * C * C4;
    const u16* w2t = w2_t + (size_t)l * C4 * C;

    k_gemm<1, 0, 0, 0><<<gQKV, blk, 0, stream>>>(
        xb, wqkvt, nullptr, nullptr, nullptr, qkvb, BT, C3, C);
    k_attn<<<B * H * (T / 64), blk, 0, stream>>>(qkvb, attb);
    k_gemm<0, 0, 1, 1><<<gCC, blk, 0, stream>>>(
        attb, wot, bo + (size_t)l * C, x, tmp, nullptr, BT, C, C);
    k_ln<<<BT, blk, 0, stream>>>(tmp, ln1_g + (size_t)l * C,
                                 ln1_b + (size_t)l * C, x, xb);
    k_gemm256<1, 1, 1, 0><<<gC4, blk5, 0, stream>>>(
        xb, w1t, b1 + (size_t)l * C4, nullptr, nullptr, hb, BT, C4, C);
    k_gemm<0, 0, 1, 1><<<gCC, blk, 0, stream>>>(
        hb, w2t, b2 + (size_t)l * C, x, tmp, nullptr, BT, C, C4);
    k_ln<<<BT, blk, 0, stream>>>(tmp, ln2_g + (size_t)l * C,
                                 ln2_b + (size_t)l * C, x, xb);
  }
  k_ln<<<BT, blk, 0, stream>>>(x, lnf_g, lnf_b, x, xb);
  k_gemm256<0, 0, 1, 0><<<dim3(V / 256, BT / 256), blk5, 0, stream>>>(
      xb, lmw_t, lm_b, nullptr, logits, nullptr, BT, V, C);
  k_rowloss<<<BT, blk, 0, stream>>>(logits, targets, rowloss);
  k_lossreduce<<<1, blk, 0, stream>>>(rowloss, loss);
}

// Round 5
// 2946.961 us; speedup vs baseline: 1.2032x; 1.1051x over previous
//
#include <hip/hip_runtime.h>

typedef unsigned short u16;
typedef __attribute__((ext_vector_type(4))) float f32x4;
typedef __attribute__((ext_vector_type(8))) short s16x8;

static constexpr int V = 32000;
static constexpr int C = 1024;
static constexpr int T = 1024;
static constexpr int H = 16;
static constexpr int L = 8;
static constexpr int B = 4;
static constexpr int HS = 64;
static constexpr int BT = B * T;   // 4096
static constexpr int C4 = 4 * C;   // 4096
static constexpr int C3 = 3 * C;   // 3072

__device__ __forceinline__ u16 f2bf(float f) {
  union { float f; unsigned u; } v; v.f = f;
  unsigned r = v.u + 0x7fffu + ((v.u >> 16) & 1u);
  return (u16)(r >> 16);
}

__device__ __forceinline__ void gload16(const u16* g, u16* l) {
  __builtin_amdgcn_global_load_lds(
      (const __attribute__((address_space(1))) void*)g,
      (__attribute__((address_space(3))) void*)l, 16, 0, 0);
}

// ---------- block reduction (256 threads) ----------
__device__ __forceinline__ float blockReduceSum(float v) {
  __shared__ float red[4];
  int lane = threadIdx.x & 63, w = threadIdx.x >> 6;
#pragma unroll
  for (int m = 32; m >= 1; m >>= 1) v += __shfl_xor(v, m, 64);
  if (lane == 0) red[w] = v;
  __syncthreads();
  float r = red[0] + red[1] + red[2] + red[3];
  __syncthreads();
  return r;
}

// ---------- embed ----------
__global__ __launch_bounds__(256) void k_embed(
    const int* __restrict__ idx, const float* __restrict__ tok,
    const float* __restrict__ pos, float* __restrict__ x, u16* __restrict__ xb) {
  int bt = blockIdx.x;
  int t = bt & (T - 1);
  int row = idx[bt];
  const float* te = tok + (size_t)row * C;
  const float* pe = pos + (size_t)t * C;
  float* xo = x + (size_t)bt * C;
  u16* xbo = xb + (size_t)bt * C;
  for (int c = threadIdx.x; c < C; c += 256) {
    float v = te[c] + pe[c];
    xo[c] = v;
    xbo[c] = f2bf(v);
  }
}

// ---------- weight convert+transpose: fp32 [K,N] -> bf16 [N,K] ----------
__global__ __launch_bounds__(256) void k_transpose(
    const float* __restrict__ W, u16* __restrict__ Wt, int K, int N,
    size_t sW, size_t sWt) {
  __shared__ float tile[64][65];
  const float* Wz = W + sW * blockIdx.z;
  u16* Wtz = Wt + sWt * blockIdx.z;
  int n0 = blockIdx.x * 64, k0 = blockIdx.y * 64;
  int tc = threadIdx.x & 63, tr = threadIdx.x >> 6;
#pragma unroll
  for (int i = 0; i < 16; ++i) {
    int r = tr + i * 4;
    tile[r][tc] = Wz[(size_t)(k0 + r) * N + (n0 + tc)];
  }
  __syncthreads();
#pragma unroll
  for (int i = 0; i < 16; ++i) {
    int r = tr + i * 4;  // n-offset within tile
    Wtz[(size_t)(n0 + r) * K + (k0 + tc)] = f2bf(tile[tc][r]);
  }
}

// ---------- V transpose: qkv V-part [T][64] -> vt [64][T] per (b,h) ----------
__global__ __launch_bounds__(256) void k_vtrans(
    const u16* __restrict__ qkv, u16* __restrict__ vt) {
  __shared__ u16 tile[64][72];
  int bid = blockIdx.x;  // tc | h | b
  int tc = bid & 15, h = (bid >> 4) & 15, b = bid >> 8;
  int t0 = tc * 64;
  const size_t base = (size_t)b * T * C3 + 2 * C + (size_t)h * HS;
  int tid = threadIdx.x;
  int r = tid >> 3, c8 = (tid & 7) * 8;
#pragma unroll
  for (int it = 0; it < 2; ++it) {
    int row = r + it * 32;
    *(s16x8*)&tile[row][c8] =
        *(const s16x8*)&qkv[base + (size_t)(t0 + row) * C3 + c8];
  }
  __syncthreads();
  const size_t vbase = (size_t)(b * H + h) * HS * T + t0;
#pragma unroll
  for (int it = 0; it < 2; ++it) {
    int d = (tid >> 3) + it * 32;
    s16x8 o;
#pragma unroll
    for (int j = 0; j < 8; ++j) o[j] = (short)tile[c8 + j][d];
    *(s16x8*)&vt[vbase + (size_t)d * T + c8] = o;
  }
}

// ---------- GEMM 128x128 (m97 structure) for small-N shapes ----------
template <int OUT_BF16, int RELU, int HAS_BIAS, int HAS_RES>
__global__ __launch_bounds__(256, 2) void k_gemm(
    const u16* __restrict__ A, const u16* __restrict__ Bt,
    const float* __restrict__ bias, const float* __restrict__ Res,
    float* __restrict__ Cf, u16* __restrict__ Cb, int M, int N, int K) {
  __shared__ u16 As[128 * 32];
  __shared__ u16 Bs[128 * 32];
  int tid = threadIdx.x;
  int lane = tid & 63, wid = tid >> 6;
  int lm = lane & 15, lg = lane >> 4;
  int wm = wid >> 1, wn = wid & 1;

  unsigned nbx = gridDim.x;
  unsigned nwg = nbx * gridDim.y;
  unsigned orig = blockIdx.y * nbx + blockIdx.x;
  unsigned f = ((nwg & 7u) == 0u) ? (orig & 7u) * (nwg >> 3) + (orig >> 3) : orig;
  int mb = (int)(f / nbx) * 128, nb = (int)(f % nbx) * 128;

  f32x4 acc[4][4];
#pragma unroll
  for (int i = 0; i < 4; ++i)
#pragma unroll
    for (int j = 0; j < 4; ++j) acc[i][j] = f32x4{0.f, 0.f, 0.f, 0.f};

  int r0 = tid >> 2, q0 = tid & 3;
  int r1 = (256 + tid) >> 2, q1 = tid & 3;
  const u16* a0 = A + (size_t)(mb + r0) * K + q0 * 8;
  const u16* a1 = A + (size_t)(mb + r1) * K + q1 * 8;
  const u16* b0 = Bt + (size_t)(nb + r0) * K + q0 * 8;
  const u16* b1 = Bt + (size_t)(nb + r1) * K + q1 * 8;
  u16* lA0 = &As[wid * 512];
  u16* lA1 = &As[2048 + wid * 512];
  u16* lB0 = &Bs[wid * 512];
  u16* lB1 = &Bs[2048 + wid * 512];

  int nK = K >> 5;
  for (int kb = 0; kb < nK; ++kb) {
    __syncthreads();
    int ko = kb * 32;
    gload16(a0 + ko, lA0);
    gload16(a1 + ko, lA1);
    gload16(b0 + ko, lB0);
    gload16(b1 + ko, lB1);
    __syncthreads();
    s16x8 af[4], bfr[4];
#pragma unroll
    for (int m = 0; m < 4; ++m)
      af[m] = *(const s16x8*)&As[(wm * 64 + m * 16 + lm) * 32 + lg * 8];
#pragma unroll
    for (int n = 0; n < 4; ++n)
      bfr[n] = *(const s16x8*)&Bs[(wn * 64 + n * 16 + lm) * 32 + lg * 8];
#pragma unroll
    for (int m = 0; m < 4; ++m)
#pragma unroll
      for (int n = 0; n < 4; ++n)
        acc[m][n] = __builtin_amdgcn_mfma_f32_16x16x32_bf16(af[m], bfr[n],
                                                            acc[m][n], 0, 0, 0);
  }
#pragma unroll
  for (int m = 0; m < 4; ++m) {
#pragma unroll
    for (int n = 0; n < 4; ++n) {
      int col = nb + wn * 64 + n * 16 + lm;
      float bv = HAS_BIAS ? bias[col] : 0.0f;
#pragma unroll
      for (int r = 0; r < 4; ++r) {
        int row = mb + wm * 64 + m * 16 + lg * 4 + r;
        float v = acc[m][n][r] + bv;
        if (HAS_RES) v += Res[(size_t)row * N + col];
        if (RELU) v = v > 0.f ? v : 0.f;
        if (OUT_BF16)
          Cb[(size_t)row * N + col] = f2bf(v);
        else
          Cf[(size_t)row * N + col] = v;
      }
    }
  }
}

// ---------- GEMM 256x256 8-phase (T2+T3+T4+T5) for big-N shapes ----------
template <int OUT_BF16, int RELU, int HAS_BIAS, int HAS_RES>
__global__ __launch_bounds__(512) void k_gemm256(
    const u16* __restrict__ A, const u16* __restrict__ Bt,
    const float* __restrict__ bias, const float* __restrict__ Res,
    float* __restrict__ Cf, u16* __restrict__ Cb, int M, int N, int K) {
  __shared__ u16 As[2][16384];
  __shared__ u16 Bs[2][16384];
  const int tid = threadIdx.x;
  const int lane = tid & 63, wid = tid >> 6;
  const int lm = lane & 15, lg = lane >> 4;
  const int wr = wid >> 2, wc = wid & 3;

  unsigned nbx = gridDim.x;
  unsigned nwg = nbx * gridDim.y;
  unsigned orig = blockIdx.y * nbx + blockIdx.x;
  unsigned f = ((nwg & 7u) == 0u) ? (orig & 7u) * (nwg >> 3) + (orig >> 3) : orig;
  const int mb = (int)(f / nbx) * 256, nb = (int)(f % nbx) * 256;

  int aoff[4], boff[4], ldso[4];
#pragma unroll
  for (int h = 0; h < 4; ++h) {
    const int kk = h >> 1, p = h & 1;
    int rem = p * 512 + tid;
    int rblk = rem >> 6;
    int rem2 = rem & 63;
    int row16 = rem2 >> 2, psl = rem2 & 3;
    int sl = psl ^ ((row16 >> 1) & 3);
    int grow = rblk * 16 + row16;
    int gk = kk * 32 + sl * 8;
    aoff[h] = (mb + grow) * K + gk;
    boff[h] = (nb + grow) * K + gk;
    ldso[h] = kk * 8192 + p * 4096 + wid * 512;
  }
  const int lo = lm * 32 + ((lg ^ ((lm >> 1) & 3)) << 3);

  f32x4 acc[8][4];
#pragma unroll
  for (int i = 0; i < 8; ++i)
#pragma unroll
    for (int j = 0; j < 4; ++j) acc[i][j] = f32x4{0.f, 0.f, 0.f, 0.f};

  const int nK = K >> 6;
  gload16(A + aoff[0], &As[0][ldso[0]]);
  gload16(A + aoff[1], &As[0][ldso[1]]);
  gload16(Bt + boff[0], &Bs[0][ldso[0]]);
  gload16(Bt + boff[1], &Bs[0][ldso[1]]);
  gload16(A + aoff[2], &As[0][ldso[2]]);
  gload16(A + aoff[3], &As[0][ldso[3]]);
  gload16(Bt + boff[2], &Bs[0][ldso[2]]);
  gload16(Bt + boff[3], &Bs[0][ldso[3]]);
  asm volatile("s_waitcnt vmcnt(4)" ::: "memory");
  __builtin_amdgcn_s_barrier();

  for (int t = 0; t < nK; ++t) {
    const int buf = t & 1, nbuf = buf ^ 1;
    const bool pre = (t + 1 < nK);
    const int nk64 = (t + 1) * 64;
    s16x8 af[4], bfr[4];
    // P1: kk0 A m0-3 + B; stage Ak0(t+1)
#pragma unroll
    for (int m = 0; m < 4; ++m)
      af[m] = *(const s16x8*)&As[buf][(wr * 8 + m) * 512 + lo];
#pragma unroll
    for (int n = 0; n < 4; ++n)
      bfr[n] = *(const s16x8*)&Bs[buf][(wc * 4 + n) * 512 + lo];
    if (pre) {
      gload16(A + aoff[0] + nk64, &As[nbuf][ldso[0]]);
      gload16(A + aoff[1] + nk64, &As[nbuf][ldso[1]]);
    }
    __builtin_amdgcn_s_barrier();
    __builtin_amdgcn_s_setprio(1);
#pragma unroll
    for (int m = 0; m < 4; ++m)
#pragma unroll
      for (int n = 0; n < 4; ++n)
        acc[m][n] = __builtin_amdgcn_mfma_f32_16x16x32_bf16(af[m], bfr[n],
                                                            acc[m][n], 0, 0, 0);
    __builtin_amdgcn_s_setprio(0);
    __builtin_amdgcn_s_barrier();
    // P2: kk0 A m4-7; stage Bk0(t+1)
#pragma unroll
    for (int m = 0; m < 4; ++m)
      af[m] = *(const s16x8*)&As[buf][(wr * 8 + 4 + m) * 512 + lo];
    if (pre) {
      gload16(Bt + boff[0] + nk64, &Bs[nbuf][ldso[0]]);
      gload16(Bt + boff[1] + nk64, &Bs[nbuf][ldso[1]]);
    }
    __builtin_amdgcn_s_barrier();
    __builtin_amdgcn_s_setprio(1);
#pragma unroll
    for (int m = 0; m < 4; ++m)
#pragma unroll
      for (int n = 0; n < 4; ++n)
        acc[m + 4][n] = __builtin_amdgcn_mfma_f32_16x16x32_bf16(
            af[m], bfr[n], acc[m + 4][n], 0, 0, 0);
    __builtin_amdgcn_s_setprio(0);
    __builtin_amdgcn_s_barrier();
    // P3: kk1 A m0-3 + B; stage Ak1(t+1); gate kk1(t)
#pragma unroll
    for (int m = 0; m < 4; ++m)
      af[m] = *(const s16x8*)&As[buf][8192 + (wr * 8 + m) * 512 + lo];
#pragma unroll
    for (int n = 0; n < 4; ++n)
      bfr[n] = *(const s16x8*)&Bs[buf][8192 + (wc * 4 + n) * 512 + lo];
    if (pre) {
      gload16(A + aoff[2] + nk64, &As[nbuf][ldso[2]]);
      gload16(A + aoff[3] + nk64, &As[nbuf][ldso[3]]);
      asm volatile("s_waitcnt vmcnt(6)" ::: "memory");
    } else {
      asm volatile("s_waitcnt vmcnt(0)" ::: "memory");
    }
    __builtin_amdgcn_s_barrier();
    __builtin_amdgcn_s_setprio(1);
#pragma unroll
    for (int m = 0; m < 4; ++m)
#pragma unroll
      for (int n = 0; n < 4; ++n)
        acc[m][n] = __builtin_amdgcn_mfma_f32_16x16x32_bf16(af[m], bfr[n],
                                                            acc[m][n], 0, 0, 0);
    __builtin_amdgcn_s_setprio(0);
    __builtin_amdgcn_s_barrier();
    // P4: kk1 A m4-7; stage Bk1(t+1); gate kk0(t+1)
#pragma unroll
    for (int m = 0; m < 4; ++m)
      af[m] = *(const s16x8*)&As[buf][8192 + (wr * 8 + 4 + m) * 512 + lo];
    if (pre) {
      gload16(Bt + boff[2] + nk64, &Bs[nbuf][ldso[2]]);
      gload16(Bt + boff[3] + nk64, &Bs[nbuf][ldso[3]]);
      asm volatile("s_waitcnt vmcnt(4)" ::: "memory");
    }
    __builtin_amdgcn_s_barrier();
    __builtin_amdgcn_s_setprio(1);
#pragma unroll
    for (int m = 0; m < 4; ++m)
#pragma unroll
      for (int n = 0; n < 4; ++n)
        acc[m + 4][n] = __builtin_amdgcn_mfma_f32_16x16x32_bf16(
            af[m], bfr[n], acc[m + 4][n], 0, 0, 0);
    __builtin_amdgcn_s_setprio(0);
    __builtin_amdgcn_s_barrier();
  }
  // epilogue: n-inner (256B contiguous per row)
  float bv[4];
#pragma unroll
  for (int n = 0; n < 4; ++n)
    bv[n] = HAS_BIAS ? bias[nb + wc * 64 + n * 16 + lm] : 0.0f;
#pragma unroll
  for (int m = 0; m < 8; ++m) {
#pragma unroll
    for (int r = 0; r < 4; ++r) {
      int row = mb + wr * 128 + m * 16 + lg * 4 + r;
#pragma unroll
      for (int n = 0; n < 4; ++n) {
        int col = nb + wc * 64 + n * 16 + lm;
        float v = acc[m][n][r] + bv[n];
        if (HAS_RES) v += Res[(size_t)row * N + col];
        if (RELU) v = v > 0.f ? v : 0.f;
        if (OUT_BF16)
          Cb[(size_t)row * N + col] = f2bf(v);
        else
          Cf[(size_t)row * N + col] = v;
      }
    }
  }
}

// ---------- flash attention v2: KVBLK=64, gload_lds-staged K and Vt ----------
// 64 q-rows/block (4 waves x 16). K tile [64 kv][64 d], Vt tile [64 d][64 t],
// both 128B rows with chunk XOR-swizzle (c ^ (row&7)) on the global source,
// matching XOR on the ds_read. Only the diagonal tile masks.
__global__ __launch_bounds__(256) void k_attn(
    const u16* __restrict__ qkv, const u16* __restrict__ vt,
    u16* __restrict__ o) {
  constexpr int PP = 72;
  __shared__ u16 Ks[64 * 64];
  __shared__ u16 Vs[64 * 64];
  __shared__ u16 Ps[4][16 * PP];
  int bid = blockIdx.x;  // qt | h | b
  int qt = bid & 15, h = (bid >> 4) & 15, b = bid >> 8;
  int tid = threadIdx.x, lane = tid & 63, wid = tid >> 6;
  int lm = lane & 15, lg = lane >> 4;
  const size_t rowbase = (size_t)b * T * C3 + (size_t)h * HS;
  const u16* kbase = qkv + rowbase + C;
  const u16* vbase = vt + (size_t)(b * H + h) * HS * T;
  int qb = qt * 64;
  int qw = qb + wid * 16;
  const float scale = 0.125f;

  s16x8 qf[2];
#pragma unroll
  for (int s = 0; s < 2; ++s)
    qf[s] = *(const s16x8*)&qkv[rowbase + (size_t)(qw + lm) * C3 + s * 32 + lg * 8];

  float m_[4], l_[4];
  f32x4 oacc[4];
#pragma unroll
  for (int r = 0; r < 4; ++r) { m_[r] = -3e38f; l_[r] = 0.f; }
#pragma unroll
  for (int n = 0; n < 4; ++n) oacc[n] = f32x4{0.f, 0.f, 0.f, 0.f};

  // staging coords: ci = it*256 + tid; row = ci>>3, cs = ci&7; src chunk
  // c = cs ^ (row&7)  ((row+32)&7 == row&7, so same for both its)
  const int sr = tid >> 3, scs = (tid & 7) ^ (sr & 7);
  // read-side swizzled chunk offsets (u16): ((ks*4+lg) ^ (lm&7)) * 8
  const int swz0 = ((lg) ^ (lm & 7)) * 8;
  const int swz1 = ((4 + lg) ^ (lm & 7)) * 8;

  for (int kt = 0; kt <= qt; ++kt) {
    __syncthreads();
    gload16(kbase + (size_t)(kt * 64 + sr) * C3 + scs * 8, &Ks[wid * 512]);
    gload16(kbase + (size_t)(kt * 64 + sr + 32) * C3 + scs * 8,
            &Ks[2048 + wid * 512]);
    gload16(vbase + (size_t)sr * T + kt * 64 + scs * 8, &Vs[wid * 512]);
    gload16(vbase + (size_t)(sr + 32) * T + kt * 64 + scs * 8,
            &Vs[2048 + wid * 512]);
    __syncthreads();  // drains vmcnt before barrier

    // S = Q K^T: [16 q][64 kv]
    f32x4 s[4];
#pragma unroll
    for (int ch = 0; ch < 4; ++ch) s[ch] = f32x4{0.f, 0.f, 0.f, 0.f};
#pragma unroll
    for (int ch = 0; ch < 4; ++ch) {
      s16x8 k0 = *(const s16x8*)&Ks[(ch * 16 + lm) * 64 + swz0];
      s16x8 k1 = *(const s16x8*)&Ks[(ch * 16 + lm) * 64 + swz1];
      s[ch] = __builtin_amdgcn_mfma_f32_16x16x32_bf16(qf[0], k0, s[ch], 0, 0, 0);
      s[ch] = __builtin_amdgcn_mfma_f32_16x16x32_bf16(qf[1], k1, s[ch], 0, 0, 0);
    }
    // scale (+mask only on diagonal tile)
    if (kt == qt) {
#pragma unroll
      for (int ch = 0; ch < 4; ++ch) {
        int col = kt * 64 + ch * 16 + lm;
#pragma unroll
        for (int r = 0; r < 4; ++r) {
          int row = qw + lg * 4 + r;
          s[ch][r] = (col <= row) ? s[ch][r] * scale : -3e38f;
        }
      }
    } else {
#pragma unroll
      for (int ch = 0; ch < 4; ++ch)
#pragma unroll
        for (int r = 0; r < 4; ++r) s[ch][r] *= scale;
    }
    // online softmax
    float rmax[4];
#pragma unroll
    for (int r = 0; r < 4; ++r)
      rmax[r] = fmaxf(fmaxf(s[0][r], s[1][r]), fmaxf(s[2][r], s[3][r]));
#pragma unroll
    for (int mm = 1; mm < 16; mm <<= 1)
#pragma unroll
      for (int r = 0; r < 4; ++r)
        rmax[r] = fmaxf(rmax[r], __shfl_xor(rmax[r], mm, 16));
    float alpha[4], rsum[4];
#pragma unroll
    for (int r = 0; r < 4; ++r) {
      float mn = fmaxf(m_[r], rmax[r]);
      alpha[r] = __expf(m_[r] - mn);
      m_[r] = mn;
      rsum[r] = 0.f;
    }
#pragma unroll
    for (int ch = 0; ch < 4; ++ch)
#pragma unroll
      for (int r = 0; r < 4; ++r) {
        float e = __expf(s[ch][r] - m_[r]);
        s[ch][r] = e;
        rsum[r] += e;
      }
#pragma unroll
    for (int mm = 1; mm < 16; mm <<= 1)
#pragma unroll
      for (int r = 0; r < 4; ++r) rsum[r] += __shfl_xor(rsum[r], mm, 16);
#pragma unroll
    for (int r = 0; r < 4; ++r) l_[r] = l_[r] * alpha[r] + rsum[r];
#pragma unroll
    for (int n = 0; n < 4; ++n)
#pragma unroll
      for (int r = 0; r < 4; ++r) oacc[n][r] *= alpha[r];
    // P -> bf16 via per-wave LDS transpose (C/D layout -> A-frag layout)
#pragma unroll
    for (int r = 0; r < 4; ++r) {
      int pr = lg * 4 + r;
#pragma unroll
      for (int ch = 0; ch < 4; ++ch)
        Ps[wid][pr * PP + ch * 16 + lm] = f2bf(s[ch][r]);
    }
    s16x8 pa0 = *(const s16x8*)&Ps[wid][lm * PP + lg * 8];
    s16x8 pa1 = *(const s16x8*)&Ps[wid][lm * PP + 32 + lg * 8];
    // O += P V  (B-frag rows = Vt d-rows)
#pragma unroll
    for (int n = 0; n < 4; ++n) {
      s16x8 v0 = *(const s16x8*)&Vs[(n * 16 + lm) * 64 + swz0];
      s16x8 v1 = *(const s16x8*)&Vs[(n * 16 + lm) * 64 + swz1];
      oacc[n] = __builtin_amdgcn_mfma_f32_16x16x32_bf16(pa0, v0, oacc[n], 0, 0, 0);
      oacc[n] = __builtin_amdgcn_mfma_f32_16x16x32_bf16(pa1, v1, oacc[n], 0, 0, 0);
    }
  }
  const size_t obase = (size_t)b * T * C + (size_t)h * HS;
  float inv[4];
#pragma unroll
  for (int r = 0; r < 4; ++r) inv[r] = 1.0f / l_[r];
#pragma unroll
  for (int n = 0; n < 4; ++n)
#pragma unroll
    for (int r = 0; r < 4; ++r)
      o[obase + (size_t)(qw + lg * 4 + r) * C + n * 16 + lm] =
          f2bf(oacc[n][r] * inv[r]);
}

// ---------- LayerNorm ----------
__global__ __launch_bounds__(256) void k_ln(
    const float* __restrict__ in, const float* __restrict__ g,
    const float* __restrict__ bsh, float* __restrict__ xout,
    u16* __restrict__ xbout) {
  int row = blockIdx.x;
  const float* xr = in + (size_t)row * C;
  int tid = threadIdx.x;
  float vals[4];
  float s = 0.f;
#pragma unroll
  for (int i = 0; i < 4; ++i) {
    float vv = xr[tid + i * 256];
    vals[i] = vv;
    s += vv;
  }
  s = blockReduceSum(s);
  float mean = s * (1.0f / C);
  float s2 = 0.f;
#pragma unroll
  for (int i = 0; i < 4; ++i) {
    float d = vals[i] - mean;
    s2 += d * d;
  }
  s2 = blockReduceSum(s2);
  float rstd = rsqrtf(s2 * (1.0f / C) + 1e-5f);
#pragma unroll
  for (int i = 0; i < 4; ++i) {
    int c = tid + i * 256;
    float y = (vals[i] - mean) * rstd * g[c] + bsh[c];
    xout[(size_t)row * C + c] = y;
    xbout[(size_t)row * C + c] = f2bf(y);
  }
}

// ---------- loss: single-pass online logsumexp per row ----------
__global__ __launch_bounds__(256) void k_rowloss(
    const float* __restrict__ logits, const int* __restrict__ tgt,
    float* __restrict__ rowloss) {
  int row = blockIdx.x;
  const float* lr = logits + (size_t)row * V;
  const f32x4* lr4 = (const f32x4*)lr;
  int tid = threadIdx.x;
  float m = -3e38f, s = 0.f;
  for (int i = tid; i < V / 4; i += 256) {
    f32x4 v = lr4[i];
#pragma unroll
    for (int j = 0; j < 4; ++j) {
      float x = v[j];
      if (x > m) {
        s = s * __expf(m - x) + 1.f;
        m = x;
      } else {
        s += __expf(x - m);
      }
    }
  }
#pragma unroll
  for (int d = 1; d < 64; d <<= 1) {
    float mo = __shfl_xor(m, d, 64), so = __shfl_xor(s, d, 64);
    float mn = fmaxf(m, mo);
    s = s * __expf(m - mn) + so * __expf(mo - mn);
    m = mn;
  }
  __shared__ float sm[4], ss[4];
  int w = tid >> 6;
  if ((tid & 63) == 0) { sm[w] = m; ss[w] = s; }
  __syncthreads();
  if (tid == 0) {
    float M = fmaxf(fmaxf(sm[0], sm[1]), fmaxf(sm[2], sm[3]));
    float S = ss[0] * __expf(sm[0] - M) + ss[1] * __expf(sm[1] - M) +
              ss[2] * __expf(sm[2] - M) + ss[3] * __expf(sm[3] - M);
    rowloss[row] = (M + logf(S)) - lr[tgt[row]];
  }
}

__global__ __launch_bounds__(256) void k_lossreduce(
    const float* __restrict__ rowloss, float* __restrict__ out) {
  __shared__ float red[256];
  int tid = threadIdx.x;
  float s = 0.f;
  for (int i = tid; i < BT; i += 256) s += rowloss[i];
  red[tid] = s;
  __syncthreads();
  for (int m = 128; m >= 1; m >>= 1) {
    if (tid < m) red[tid] += red[tid + m];
    __syncthreads();
  }
  if (tid == 0) out[0] = red[0] * (1.0f / BT);
}

// ---------------- host orchestration ----------------
extern "C" void kernel_launch(void* const* d_in, const int* in_sizes, int n_in,
                              void* d_out, int out_size, void* d_ws,
                              size_t ws_size, hipStream_t stream) {
  (void)in_sizes; (void)n_in; (void)out_size; (void)ws_size;
  const int* index = (const int*)d_in[0];
  const int* targets = (const int*)d_in[1];
  const float* tok_emb = (const float*)d_in[2];
  const float* pos_emb = (const float*)d_in[3];
  const float* wq = (const float*)d_in[4];
  const float* wk = (const float*)d_in[5];
  const float* wv = (const float*)d_in[6];
  const float* wo = (const float*)d_in[7];
  const float* bo = (const float*)d_in[8];
  const float* w1 = (const float*)d_in[9];
  const float* b1 = (const float*)d_in[10];
  const float* w2 = (const float*)d_in[11];
  const float* b2 = (const float*)d_in[12];
  const float* ln1_g = (const float*)d_in[13];
  const float* ln1_b = (const float*)d_in[14];
  const float* ln2_g = (const float*)d_in[15];
  const float* ln2_b = (const float*)d_in[16];
  const float* lnf_g = (const float*)d_in[17];
  const float* lnf_b = (const float*)d_in[18];
  const float* lm_w = (const float*)d_in[19];
  const float* lm_b = (const float*)d_in[20];

  float* logits = (float*)d_out;
  float* loss = logits + (size_t)BT * V;

  size_t off = 0;
  auto alloc = [&](size_t bytes) -> void* {
    off = (off + 255) & ~(size_t)255;
    void* p = (void*)((char*)d_ws + off);
    off += bytes;
    return p;
  };
  u16* wqkv_t = (u16*)alloc((size_t)L * C3 * C * 2);  // [L][3C][C]
  u16* wo_t = (u16*)alloc((size_t)L * C * C * 2);
  u16* w1_t = (u16*)alloc((size_t)L * C * C4 * 2);
  u16* w2_t = (u16*)alloc((size_t)L * C4 * C * 2);
  u16* lmw_t = (u16*)alloc((size_t)V * C * 2);
  float* x = (float*)alloc((size_t)BT * C * 4);
  float* tmp = (float*)alloc((size_t)BT * C * 4);
  u16* xb = (u16*)alloc((size_t)BT * C * 2);
  u16* qkvb = (u16*)alloc((size_t)BT * C3 * 2);
  u16* vtb = (u16*)alloc((size_t)BT * C * 2);   // V transposed per (b,h)
  u16* attb = (u16*)alloc((size_t)BT * C * 2);
  u16* hb = (u16*)alloc((size_t)BT * C4 * 2);
  float* rowloss = (float*)alloc((size_t)BT * 4);

  dim3 blk(256);
  dim3 blk5(512);
  k_transpose<<<dim3(C / 64, C / 64, L), blk, 0, stream>>>(
      wq, wqkv_t, C, C, (size_t)C * C, (size_t)C3 * C);
  k_transpose<<<dim3(C / 64, C / 64, L), blk, 0, stream>>>(
      wk, wqkv_t + (size_t)C * C, C, C, (size_t)C * C, (size_t)C3 * C);
  k_transpose<<<dim3(C / 64, C / 64, L), blk, 0, stream>>>(
      wv, wqkv_t + (size_t)2 * C * C, C, C, (size_t)C * C, (size_t)C3 * C);
  k_transpose<<<dim3(C / 64, C / 64, L), blk, 0, stream>>>(
      wo, wo_t, C, C, (size_t)C * C, (size_t)C * C);
  k_transpose<<<dim3(C4 / 64, C / 64, L), blk, 0, stream>>>(
      w1, w1_t, C, C4, (size_t)C * C4, (size_t)C * C4);
  k_transpose<<<dim3(C / 64, C4 / 64, L), blk, 0, stream>>>(
      w2, w2_t, C4, C, (size_t)C4 * C, (size_t)C4 * C);
  k_transpose<<<dim3(V / 64, C / 64, 1), blk, 0, stream>>>(
      lm_w, lmw_t, C, V, 0, 0);

  k_embed<<<BT, blk, 0, stream>>>(index, tok_emb, pos_emb, x, xb);

  dim3 gQKV(C3 / 128, BT / 128);   // 768 wg
  dim3 gCC(C / 128, BT / 128);     // 256 wg
  dim3 gC4(C4 / 256, BT / 256);    // 256 wg (256^2 tile)
  for (int l = 0; l < L; ++l) {
    const u16* wqkvt = wqkv_t + (size_t)l * C3 * C;
    const u16* wot = wo_t + (size_t)l * C * C;
    const u16* w1t = w1_t + (size_t)l * C * C4;
    const u16* w2t = w2_t + (size_t)l * C4 * C;

    k_gemm<1, 0, 0, 0><<<gQKV, blk, 0, stream>>>(
        xb, wqkvt, nullptr, nullptr, nullptr, qkvb, BT, C3, C);
    k_vtrans<<<B * H * (T / 64), blk, 0, stream>>>(qkvb, vtb);
    k_attn<<<B * H * (T / 64), blk, 0, stream>>>(qkvb, vtb, attb);
    k_gemm<0, 0, 1, 1><<<gCC, blk, 0, stream>>>(
        attb, wot, bo + (size_t)l * C, x, tmp, nullptr, BT, C, C);
    k_ln<<<BT, blk, 0, stream>>>(tmp, ln1_g + (size_t)l * C,
                                 ln1_b + (size_t)l * C, x, xb);
    k_gemm256<1, 1, 1, 0><<<gC4, blk5, 0, stream>>>(
        xb, w1t, b1 + (size_t)l * C4, nullptr, nullptr, hb, BT, C4, C);
    k_gemm<0, 0, 1, 1><<<gCC, blk, 0, stream>>>(
        hb, w2t, b2 + (size_t)l * C, x, tmp, nullptr, BT, C, C4);
    k_ln<<<BT, blk, 0, stream>>>(tmp, ln2_g + (size_t)l * C,
                                 ln2_b + (size_t)l * C, x, xb);
  }
  k_ln<<<BT, blk, 0, stream>>>(x, lnf_g, lnf_b, x, xb);
  k_gemm256<0, 0, 1, 0><<<dim3(V / 256, BT / 256), blk5, 0, stream>>>(
      xb, lmw_t, lm_b, nullptr, logits, nullptr, BT, V, C);
  k_rowloss<<<BT, blk, 0, stream>>>(logits, targets, rowloss);
  k_lossreduce<<<1, blk, 0, stream>>>(rowloss, loss);
}

// Round 6
// 2891.100 us; speedup vs baseline: 1.2265x; 1.0193x over previous
//
#include <hip/hip_runtime.h>

typedef unsigned short u16;
typedef __attribute__((ext_vector_type(4))) float f32x4;
typedef __attribute__((ext_vector_type(8))) short s16x8;
typedef __attribute__((ext_vector_type(4))) short s16x4;

static constexpr int V = 32000;
static constexpr int C = 1024;
static constexpr int T = 1024;
static constexpr int H = 16;
static constexpr int L = 8;
static constexpr int B = 4;
static constexpr int HS = 64;
static constexpr int BT = B * T;   // 4096
static constexpr int C4 = 4 * C;   // 4096
static constexpr int C3 = 3 * C;   // 3072

__device__ __forceinline__ u16 f2bf(float f) {
  union { float f; unsigned u; } v; v.f = f;
  unsigned r = v.u + 0x7fffu + ((v.u >> 16) & 1u);
  return (u16)(r >> 16);
}

__device__ __forceinline__ void gload16(const u16* g, u16* l) {
  __builtin_amdgcn_global_load_lds(
      (const __attribute__((address_space(1))) void*)g,
      (__attribute__((address_space(3))) void*)l, 16, 0, 0);
}

// ---------- block reduction (256 threads) ----------
__device__ __forceinline__ float blockReduceSum(float v) {
  __shared__ float red[4];
  int lane = threadIdx.x & 63, w = threadIdx.x >> 6;
#pragma unroll
  for (int m = 32; m >= 1; m >>= 1) v += __shfl_xor(v, m, 64);
  if (lane == 0) red[w] = v;
  __syncthreads();
  float r = red[0] + red[1] + red[2] + red[3];
  __syncthreads();
  return r;
}

// ---------- embed ----------
__global__ __launch_bounds__(256) void k_embed(
    const int* __restrict__ idx, const float* __restrict__ tok,
    const float* __restrict__ pos, float* __restrict__ x, u16* __restrict__ xb) {
  int bt = blockIdx.x;
  int t = bt & (T - 1);
  int row = idx[bt];
  const float* te = tok + (size_t)row * C;
  const float* pe = pos + (size_t)t * C;
  float* xo = x + (size_t)bt * C;
  u16* xbo = xb + (size_t)bt * C;
  for (int c = threadIdx.x; c < C; c += 256) {
    float v = te[c] + pe[c];
    xo[c] = v;
    xbo[c] = f2bf(v);
  }
}

// ---------- weight convert+transpose: fp32 [K,N] -> bf16 [N,K] ----------
__global__ __launch_bounds__(256) void k_transpose(
    const float* __restrict__ W, u16* __restrict__ Wt, int K, int N,
    size_t sW, size_t sWt) {
  __shared__ float tile[64][65];
  const float* Wz = W + sW * blockIdx.z;
  u16* Wtz = Wt + sWt * blockIdx.z;
  int n0 = blockIdx.x * 64, k0 = blockIdx.y * 64;
  int tc = threadIdx.x & 63, tr = threadIdx.x >> 6;
#pragma unroll
  for (int i = 0; i < 16; ++i) {
    int r = tr + i * 4;
    tile[r][tc] = Wz[(size_t)(k0 + r) * N + (n0 + tc)];
  }
  __syncthreads();
#pragma unroll
  for (int i = 0; i < 16; ++i) {
    int r = tr + i * 4;  // n-offset within tile
    Wtz[(size_t)(n0 + r) * K + (k0 + tc)] = f2bf(tile[tc][r]);
  }
}

// ---------- GEMM 128x128 (m97 structure) for small-N shapes ----------
template <int OUT_BF16, int RELU, int HAS_BIAS, int HAS_RES>
__global__ __launch_bounds__(256, 2) void k_gemm(
    const u16* __restrict__ A, const u16* __restrict__ Bt,
    const float* __restrict__ bias, const float* __restrict__ Res,
    float* __restrict__ Cf, u16* __restrict__ Cb, int M, int N, int K) {
  __shared__ u16 As[128 * 32];
  __shared__ u16 Bs[128 * 32];
  int tid = threadIdx.x;
  int lane = tid & 63, wid = tid >> 6;
  int lm = lane & 15, lg = lane >> 4;
  int wm = wid >> 1, wn = wid & 1;

  unsigned nbx = gridDim.x;
  unsigned nwg = nbx * gridDim.y;
  unsigned orig = blockIdx.y * nbx + blockIdx.x;
  unsigned f = ((nwg & 7u) == 0u) ? (orig & 7u) * (nwg >> 3) + (orig >> 3) : orig;
  int mb = (int)(f / nbx) * 128, nb = (int)(f % nbx) * 128;

  f32x4 acc[4][4];
#pragma unroll
  for (int i = 0; i < 4; ++i)
#pragma unroll
    for (int j = 0; j < 4; ++j) acc[i][j] = f32x4{0.f, 0.f, 0.f, 0.f};

  int r0 = tid >> 2, q0 = tid & 3;
  int r1 = (256 + tid) >> 2, q1 = tid & 3;
  const u16* a0 = A + (size_t)(mb + r0) * K + q0 * 8;
  const u16* a1 = A + (size_t)(mb + r1) * K + q1 * 8;
  const u16* b0 = Bt + (size_t)(nb + r0) * K + q0 * 8;
  const u16* b1 = Bt + (size_t)(nb + r1) * K + q1 * 8;
  u16* lA0 = &As[wid * 512];
  u16* lA1 = &As[2048 + wid * 512];
  u16* lB0 = &Bs[wid * 512];
  u16* lB1 = &Bs[2048 + wid * 512];

  int nK = K >> 5;
  for (int kb = 0; kb < nK; ++kb) {
    __syncthreads();
    int ko = kb * 32;
    gload16(a0 + ko, lA0);
    gload16(a1 + ko, lA1);
    gload16(b0 + ko, lB0);
    gload16(b1 + ko, lB1);
    __syncthreads();
    s16x8 af[4], bfr[4];
#pragma unroll
    for (int m = 0; m < 4; ++m)
      af[m] = *(const s16x8*)&As[(wm * 64 + m * 16 + lm) * 32 + lg * 8];
#pragma unroll
    for (int n = 0; n < 4; ++n)
      bfr[n] = *(const s16x8*)&Bs[(wn * 64 + n * 16 + lm) * 32 + lg * 8];
#pragma unroll
    for (int m = 0; m < 4; ++m)
#pragma unroll
      for (int n = 0; n < 4; ++n)
        acc[m][n] = __builtin_amdgcn_mfma_f32_16x16x32_bf16(af[m], bfr[n],
                                                            acc[m][n], 0, 0, 0);
  }
#pragma unroll
  for (int m = 0; m < 4; ++m) {
#pragma unroll
    for (int n = 0; n < 4; ++n) {
      int col = nb + wn * 64 + n * 16 + lm;
      float bv = HAS_BIAS ? bias[col] : 0.0f;
#pragma unroll
      for (int r = 0; r < 4; ++r) {
        int row = mb + wm * 64 + m * 16 + lg * 4 + r;
        float v = acc[m][n][r] + bv;
        if (HAS_RES) v += Res[(size_t)row * N + col];
        if (RELU) v = v > 0.f ? v : 0.f;
        if (OUT_BF16)
          Cb[(size_t)row * N + col] = f2bf(v);
        else
          Cf[(size_t)row * N + col] = v;
      }
    }
  }
}

// ---------- GEMM 256x256 8-phase (T2+T3+T4+T5) for big-N shapes ----------
// VT=1 (QKV): blocks with nb>=2C write the V projection transposed into Vt
// as [b*H+h][d][t] (8B packs of 4 consecutive t), skipping the normal write.
template <int OUT_BF16, int RELU, int HAS_BIAS, int HAS_RES, int VT>
__global__ __launch_bounds__(512) void k_gemm256(
    const u16* __restrict__ A, const u16* __restrict__ Bt,
    const float* __restrict__ bias, const float* __restrict__ Res,
    float* __restrict__ Cf, u16* __restrict__ Cb, u16* __restrict__ Vtp,
    int M, int N, int K) {
  __shared__ u16 As[2][16384];
  __shared__ u16 Bs[2][16384];
  const int tid = threadIdx.x;
  const int lane = tid & 63, wid = tid >> 6;
  const int lm = lane & 15, lg = lane >> 4;
  const int wr = wid >> 2, wc = wid & 3;

  unsigned nbx = gridDim.x;
  unsigned nwg = nbx * gridDim.y;
  unsigned orig = blockIdx.y * nbx + blockIdx.x;
  unsigned f = ((nwg & 7u) == 0u) ? (orig & 7u) * (nwg >> 3) + (orig >> 3) : orig;
  const int mb = (int)(f / nbx) * 256, nb = (int)(f % nbx) * 256;

  int aoff[4], boff[4], ldso[4];
#pragma unroll
  for (int h = 0; h < 4; ++h) {
    const int kk = h >> 1, p = h & 1;
    int rem = p * 512 + tid;
    int rblk = rem >> 6;
    int rem2 = rem & 63;
    int row16 = rem2 >> 2, psl = rem2 & 3;
    int sl = psl ^ ((row16 >> 1) & 3);
    int grow = rblk * 16 + row16;
    int gk = kk * 32 + sl * 8;
    aoff[h] = (mb + grow) * K + gk;
    boff[h] = (nb + grow) * K + gk;
    ldso[h] = kk * 8192 + p * 4096 + wid * 512;
  }
  const int lo = lm * 32 + ((lg ^ ((lm >> 1) & 3)) << 3);

  f32x4 acc[8][4];
#pragma unroll
  for (int i = 0; i < 8; ++i)
#pragma unroll
    for (int j = 0; j < 4; ++j) acc[i][j] = f32x4{0.f, 0.f, 0.f, 0.f};

  const int nK = K >> 6;
  gload16(A + aoff[0], &As[0][ldso[0]]);
  gload16(A + aoff[1], &As[0][ldso[1]]);
  gload16(Bt + boff[0], &Bs[0][ldso[0]]);
  gload16(Bt + boff[1], &Bs[0][ldso[1]]);
  gload16(A + aoff[2], &As[0][ldso[2]]);
  gload16(A + aoff[3], &As[0][ldso[3]]);
  gload16(Bt + boff[2], &Bs[0][ldso[2]]);
  gload16(Bt + boff[3], &Bs[0][ldso[3]]);
  asm volatile("s_waitcnt vmcnt(4)" ::: "memory");
  __builtin_amdgcn_s_barrier();

  for (int t = 0; t < nK; ++t) {
    const int buf = t & 1, nbuf = buf ^ 1;
    const bool pre = (t + 1 < nK);
    const int nk64 = (t + 1) * 64;
    s16x8 af[4], bfr[4];
    // P1: kk0 A m0-3 + B; stage Ak0(t+1)
#pragma unroll
    for (int m = 0; m < 4; ++m)
      af[m] = *(const s16x8*)&As[buf][(wr * 8 + m) * 512 + lo];
#pragma unroll
    for (int n = 0; n < 4; ++n)
      bfr[n] = *(const s16x8*)&Bs[buf][(wc * 4 + n) * 512 + lo];
    if (pre) {
      gload16(A + aoff[0] + nk64, &As[nbuf][ldso[0]]);
      gload16(A + aoff[1] + nk64, &As[nbuf][ldso[1]]);
    }
    __builtin_amdgcn_s_barrier();
    __builtin_amdgcn_s_setprio(1);
#pragma unroll
    for (int m = 0; m < 4; ++m)
#pragma unroll
      for (int n = 0; n < 4; ++n)
        acc[m][n] = __builtin_amdgcn_mfma_f32_16x16x32_bf16(af[m], bfr[n],
                                                            acc[m][n], 0, 0, 0);
    __builtin_amdgcn_s_setprio(0);
    __builtin_amdgcn_s_barrier();
    // P2: kk0 A m4-7; stage Bk0(t+1)
#pragma unroll
    for (int m = 0; m < 4; ++m)
      af[m] = *(const s16x8*)&As[buf][(wr * 8 + 4 + m) * 512 + lo];
    if (pre) {
      gload16(Bt + boff[0] + nk64, &Bs[nbuf][ldso[0]]);
      gload16(Bt + boff[1] + nk64, &Bs[nbuf][ldso[1]]);
    }
    __builtin_amdgcn_s_barrier();
    __builtin_amdgcn_s_setprio(1);
#pragma unroll
    for (int m = 0; m < 4; ++m)
#pragma unroll
      for (int n = 0; n < 4; ++n)
        acc[m + 4][n] = __builtin_amdgcn_mfma_f32_16x16x32_bf16(
            af[m], bfr[n], acc[m + 4][n], 0, 0, 0);
    __builtin_amdgcn_s_setprio(0);
    __builtin_amdgcn_s_barrier();
    // P3: kk1 A m0-3 + B; stage Ak1(t+1); gate kk1(t)
#pragma unroll
    for (int m = 0; m < 4; ++m)
      af[m] = *(const s16x8*)&As[buf][8192 + (wr * 8 + m) * 512 + lo];
#pragma unroll
    for (int n = 0; n < 4; ++n)
      bfr[n] = *(const s16x8*)&Bs[buf][8192 + (wc * 4 + n) * 512 + lo];
    if (pre) {
      gload16(A + aoff[2] + nk64, &As[nbuf][ldso[2]]);
      gload16(A + aoff[3] + nk64, &As[nbuf][ldso[3]]);
      asm volatile("s_waitcnt vmcnt(6)" ::: "memory");
    } else {
      asm volatile("s_waitcnt vmcnt(0)" ::: "memory");
    }
    __builtin_amdgcn_s_barrier();
    __builtin_amdgcn_s_setprio(1);
#pragma unroll
    for (int m = 0; m < 4; ++m)
#pragma unroll
      for (int n = 0; n < 4; ++n)
        acc[m][n] = __builtin_amdgcn_mfma_f32_16x16x32_bf16(af[m], bfr[n],
                                                            acc[m][n], 0, 0, 0);
    __builtin_amdgcn_s_setprio(0);
    __builtin_amdgcn_s_barrier();
    // P4: kk1 A m4-7; stage Bk1(t+1); gate kk0(t+1)
#pragma unroll
    for (int m = 0; m < 4; ++m)
      af[m] = *(const s16x8*)&As[buf][8192 + (wr * 8 + 4 + m) * 512 + lo];
    if (pre) {
      gload16(Bt + boff[2] + nk64, &Bs[nbuf][ldso[2]]);
      gload16(Bt + boff[3] + nk64, &Bs[nbuf][ldso[3]]);
      asm volatile("s_waitcnt vmcnt(4)" ::: "memory");
    }
    __builtin_amdgcn_s_barrier();
    __builtin_amdgcn_s_setprio(1);
#pragma unroll
    for (int m = 0; m < 4; ++m)
#pragma unroll
      for (int n = 0; n < 4; ++n)
        acc[m + 4][n] = __builtin_amdgcn_mfma_f32_16x16x32_bf16(
            af[m], bfr[n], acc[m + 4][n], 0, 0, 0);
    __builtin_amdgcn_s_setprio(0);
    __builtin_amdgcn_s_barrier();
  }
  // ---- epilogue ----
  if (VT && nb >= 2 * C) {
    // V-projection block: write transposed [d][t] per (b,h)
    int hh = ((nb - 2 * C) >> 6) + wc;  // head index (uniform per wave)
#pragma unroll
    for (int m = 0; m < 8; ++m) {
      int t0 = mb + wr * 128 + m * 16 + lg * 4;
      int bb = t0 >> 10, tt = t0 & (T - 1);
      size_t vbase = ((size_t)(bb * H + hh) * HS) * T + tt;
#pragma unroll
      for (int n = 0; n < 4; ++n) {
        int d = n * 16 + lm;
        s16x4 pk;
#pragma unroll
        for (int r = 0; r < 4; ++r) pk[r] = (short)f2bf(acc[m][n][r]);
        *(s16x4*)&Vtp[vbase + (size_t)d * T] = pk;
      }
    }
    return;
  }
  float bv[4];
#pragma unroll
  for (int n = 0; n < 4; ++n)
    bv[n] = HAS_BIAS ? bias[nb + wc * 64 + n * 16 + lm] : 0.0f;
#pragma unroll
  for (int m = 0; m < 8; ++m) {
#pragma unroll
    for (int r = 0; r < 4; ++r) {
      int row = mb + wr * 128 + m * 16 + lg * 4 + r;
#pragma unroll
      for (int n = 0; n < 4; ++n) {
        int col = nb + wc * 64 + n * 16 + lm;
        float v = acc[m][n][r] + bv[n];
        if (HAS_RES) v += Res[(size_t)row * N + col];
        if (RELU) v = v > 0.f ? v : 0.f;
        if (OUT_BF16)
          Cb[(size_t)row * N + col] = f2bf(v);
        else
          Cf[(size_t)row * N + col] = v;
      }
    }
  }
}

// ---------- flash attention v3: QBLK=128 (4 waves x 32 q-rows), KVBLK=64 ----
// K tile [64 kv][64 d] and Vt tile [64 d][64 t] staged via gload_lds with
// chunk XOR-swizzle on the source, matching XOR on ds_read. Per (wave,group)
// mask branch only where the diagonal intersects.
__global__ __launch_bounds__(256) void k_attn(
    const u16* __restrict__ qkv, const u16* __restrict__ vt,
    u16* __restrict__ o) {
  constexpr int PP = 72;
  __shared__ u16 Ks[64 * 64];
  __shared__ u16 Vs[64 * 64];
  __shared__ u16 Ps[4][32 * PP];
  int bid = blockIdx.x;  // qt | h | b
  int qt = bid & 7, h = (bid >> 3) & 15, b = bid >> 7;
  int tid = threadIdx.x, lane = tid & 63, wid = tid >> 6;
  int lm = lane & 15, lg = lane >> 4;
  const size_t rowbase = (size_t)b * T * C3 + (size_t)h * HS;
  const u16* kbase = qkv + rowbase + C;
  const u16* vbase = vt + (size_t)(b * H + h) * HS * T;
  int qb = qt * 128;
  int qw = qb + wid * 32;
  const float scale = 0.125f;

  s16x8 qf[2][2];
#pragma unroll
  for (int g = 0; g < 2; ++g)
#pragma unroll
    for (int s = 0; s < 2; ++s)
      qf[g][s] = *(const s16x8*)&qkv[rowbase +
          (size_t)(qw + g * 16 + lm) * C3 + s * 32 + lg * 8];

  float m_[2][4], l_[2][4];
  f32x4 oacc[2][4];
#pragma unroll
  for (int g = 0; g < 2; ++g)
#pragma unroll
    for (int r = 0; r < 4; ++r) { m_[g][r] = -3e38f; l_[g][r] = 0.f; }
#pragma unroll
  for (int g = 0; g < 2; ++g)
#pragma unroll
    for (int n = 0; n < 4; ++n) oacc[g][n] = f32x4{0.f, 0.f, 0.f, 0.f};

  const int nkt = (qb + 128) >> 6;
  const int sr = tid >> 3, scs = (tid & 7) ^ (sr & 7);
  const int swz0 = (lg ^ (lm & 7)) * 8;
  const int swz1 = ((4 + lg) ^ (lm & 7)) * 8;

  for (int kt = 0; kt < nkt; ++kt) {
    __syncthreads();
    gload16(kbase + (size_t)(kt * 64 + sr) * C3 + scs * 8, &Ks[wid * 512]);
    gload16(kbase + (size_t)(kt * 64 + sr + 32) * C3 + scs * 8,
            &Ks[2048 + wid * 512]);
    gload16(vbase + (size_t)sr * T + kt * 64 + scs * 8, &Vs[wid * 512]);
    gload16(vbase + (size_t)(sr + 32) * T + kt * 64 + scs * 8,
            &Vs[2048 + wid * 512]);
    __syncthreads();  // drains vmcnt before barrier

    s16x8 k0[4], k1[4];
#pragma unroll
    for (int ch = 0; ch < 4; ++ch) {
      k0[ch] = *(const s16x8*)&Ks[(ch * 16 + lm) * 64 + swz0];
      k1[ch] = *(const s16x8*)&Ks[(ch * 16 + lm) * 64 + swz1];
    }
#pragma unroll
    for (int g = 0; g < 2; ++g) {
      f32x4 s[4];
#pragma unroll
      for (int ch = 0; ch < 4; ++ch) {
        s[ch] = f32x4{0.f, 0.f, 0.f, 0.f};
        s[ch] = __builtin_amdgcn_mfma_f32_16x16x32_bf16(qf[g][0], k0[ch],
                                                        s[ch], 0, 0, 0);
        s[ch] = __builtin_amdgcn_mfma_f32_16x16x32_bf16(qf[g][1], k1[ch],
                                                        s[ch], 0, 0, 0);
      }
      int grow = qw + g * 16;
      if (kt * 64 + 63 > grow) {  // diagonal intersects this group
#pragma unroll
        for (int ch = 0; ch < 4; ++ch) {
          int col = kt * 64 + ch * 16 + lm;
#pragma unroll
          for (int r = 0; r < 4; ++r) {
            int row = grow + lg * 4 + r;
            s[ch][r] = (col <= row) ? s[ch][r] * scale : -3e38f;
          }
        }
      } else {
#pragma unroll
        for (int ch = 0; ch < 4; ++ch)
#pragma unroll
          for (int r = 0; r < 4; ++r) s[ch][r] *= scale;
      }
      float rmax[4];
#pragma unroll
      for (int r = 0; r < 4; ++r)
        rmax[r] = fmaxf(fmaxf(s[0][r], s[1][r]), fmaxf(s[2][r], s[3][r]));
#pragma unroll
      for (int mm = 1; mm < 16; mm <<= 1)
#pragma unroll
        for (int r = 0; r < 4; ++r)
          rmax[r] = fmaxf(rmax[r], __shfl_xor(rmax[r], mm, 16));
      float alpha[4], rsum[4];
#pragma unroll
      for (int r = 0; r < 4; ++r) {
        float mn = fmaxf(m_[g][r], rmax[r]);
        alpha[r] = __expf(m_[g][r] - mn);
        m_[g][r] = mn;
        rsum[r] = 0.f;
      }
#pragma unroll
      for (int ch = 0; ch < 4; ++ch)
#pragma unroll
        for (int r = 0; r < 4; ++r) {
          float e = __expf(s[ch][r] - m_[g][r]);
          s[ch][r] = e;
          rsum[r] += e;
        }
#pragma unroll
      for (int mm = 1; mm < 16; mm <<= 1)
#pragma unroll
        for (int r = 0; r < 4; ++r) rsum[r] += __shfl_xor(rsum[r], mm, 16);
#pragma unroll
      for (int r = 0; r < 4; ++r) l_[g][r] = l_[g][r] * alpha[r] + rsum[r];
#pragma unroll
      for (int n = 0; n < 4; ++n)
#pragma unroll
        for (int r = 0; r < 4; ++r) oacc[g][n][r] *= alpha[r];
#pragma unroll
      for (int r = 0; r < 4; ++r) {
        int pr = g * 16 + lg * 4 + r;
#pragma unroll
        for (int ch = 0; ch < 4; ++ch)
          Ps[wid][pr * PP + ch * 16 + lm] = f2bf(s[ch][r]);
      }
    }
    // PV: V frags shared across both groups
    s16x8 v0[4], v1[4];
#pragma unroll
    for (int n = 0; n < 4; ++n) {
      v0[n] = *(const s16x8*)&Vs[(n * 16 + lm) * 64 + swz0];
      v1[n] = *(const s16x8*)&Vs[(n * 16 + lm) * 64 + swz1];
    }
#pragma unroll
    for (int g = 0; g < 2; ++g) {
      s16x8 pa0 = *(const s16x8*)&Ps[wid][(g * 16 + lm) * PP + lg * 8];
      s16x8 pa1 = *(const s16x8*)&Ps[wid][(g * 16 + lm) * PP + 32 + lg * 8];
#pragma unroll
      for (int n = 0; n < 4; ++n) {
        oacc[g][n] = __builtin_amdgcn_mfma_f32_16x16x32_bf16(pa0, v0[n],
                                                             oacc[g][n], 0, 0, 0);
        oacc[g][n] = __builtin_amdgcn_mfma_f32_16x16x32_bf16(pa1, v1[n],
                                                             oacc[g][n], 0, 0, 0);
      }
    }
  }
  const size_t obase = (size_t)b * T * C + (size_t)h * HS;
#pragma unroll
  for (int g = 0; g < 2; ++g) {
    float inv[4];
#pragma unroll
    for (int r = 0; r < 4; ++r) inv[r] = 1.0f / l_[g][r];
#pragma unroll
    for (int n = 0; n < 4; ++n)
#pragma unroll
      for (int r = 0; r < 4; ++r)
        o[obase + (size_t)(qw + g * 16 + lg * 4 + r) * C + n * 16 + lm] =
            f2bf(oacc[g][n][r] * inv[r]);
  }
}

// ---------- LayerNorm ----------
__global__ __launch_bounds__(256) void k_ln(
    const float* __restrict__ in, const float* __restrict__ g,
    const float* __restrict__ bsh, float* __restrict__ xout,
    u16* __restrict__ xbout) {
  int row = blockIdx.x;
  const float* xr = in + (size_t)row * C;
  int tid = threadIdx.x;
  float vals[4];
  float s = 0.f;
#pragma unroll
  for (int i = 0; i < 4; ++i) {
    float vv = xr[tid + i * 256];
    vals[i] = vv;
    s += vv;
  }
  s = blockReduceSum(s);
  float mean = s * (1.0f / C);
  float s2 = 0.f;
#pragma unroll
  for (int i = 0; i < 4; ++i) {
    float d = vals[i] - mean;
    s2 += d * d;
  }
  s2 = blockReduceSum(s2);
  float rstd = rsqrtf(s2 * (1.0f / C) + 1e-5f);
#pragma unroll
  for (int i = 0; i < 4; ++i) {
    int c = tid + i * 256;
    float y = (vals[i] - mean) * rstd * g[c] + bsh[c];
    xout[(size_t)row * C + c] = y;
    xbout[(size_t)row * C + c] = f2bf(y);
  }
}

// ---------- loss: single-pass online logsumexp per row ----------
__global__ __launch_bounds__(256) void k_rowloss(
    const float* __restrict__ logits, const int* __restrict__ tgt,
    float* __restrict__ rowloss) {
  int row = blockIdx.x;
  const float* lr = logits + (size_t)row * V;
  const f32x4* lr4 = (const f32x4*)lr;
  int tid = threadIdx.x;
  float m = -3e38f, s = 0.f;
  for (int i = tid; i < V / 4; i += 256) {
    f32x4 v = lr4[i];
#pragma unroll
    for (int j = 0; j < 4; ++j) {
      float x = v[j];
      if (x > m) {
        s = s * __expf(m - x) + 1.f;
        m = x;
      } else {
        s += __expf(x - m);
      }
    }
  }
#pragma unroll
  for (int d = 1; d < 64; d <<= 1) {
    float mo = __shfl_xor(m, d, 64), so = __shfl_xor(s, d, 64);
    float mn = fmaxf(m, mo);
    s = s * __expf(m - mn) + so * __expf(mo - mn);
    m = mn;
  }
  __shared__ float sm[4], ss[4];
  int w = tid >> 6;
  if ((tid & 63) == 0) { sm[w] = m; ss[w] = s; }
  __syncthreads();
  if (tid == 0) {
    float M = fmaxf(fmaxf(sm[0], sm[1]), fmaxf(sm[2], sm[3]));
    float S = ss[0] * __expf(sm[0] - M) + ss[1] * __expf(sm[1] - M) +
              ss[2] * __expf(sm[2] - M) + ss[3] * __expf(sm[3] - M);
    rowloss[row] = (M + logf(S)) - lr[tgt[row]];
  }
}

__global__ __launch_bounds__(256) void k_lossreduce(
    const float* __restrict__ rowloss, float* __restrict__ out) {
  __shared__ float red[256];
  int tid = threadIdx.x;
  float s = 0.f;
  for (int i = tid; i < BT; i += 256) s += rowloss[i];
  red[tid] = s;
  __syncthreads();
  for (int m = 128; m >= 1; m >>= 1) {
    if (tid < m) red[tid] += red[tid + m];
    __syncthreads();
  }
  if (tid == 0) out[0] = red[0] * (1.0f / BT);
}

// ---------------- host orchestration ----------------
extern "C" void kernel_launch(void* const* d_in, const int* in_sizes, int n_in,
                              void* d_out, int out_size, void* d_ws,
                              size_t ws_size, hipStream_t stream) {
  (void)in_sizes; (void)n_in; (void)out_size; (void)ws_size;
  const int* index = (const int*)d_in[0];
  const int* targets = (const int*)d_in[1];
  const float* tok_emb = (const float*)d_in[2];
  const float* pos_emb = (const float*)d_in[3];
  const float* wq = (const float*)d_in[4];
  const float* wk = (const float*)d_in[5];
  const float* wv = (const float*)d_in[6];
  const float* wo = (const float*)d_in[7];
  const float* bo = (const float*)d_in[8];
  const float* w1 = (const float*)d_in[9];
  const float* b1 = (const float*)d_in[10];
  const float* w2 = (const float*)d_in[11];
  const float* b2 = (const float*)d_in[12];
  const float* ln1_g = (const float*)d_in[13];
  const float* ln1_b = (const float*)d_in[14];
  const float* ln2_g = (const float*)d_in[15];
  const float* ln2_b = (const float*)d_in[16];
  const float* lnf_g = (const float*)d_in[17];
  const float* lnf_b = (const float*)d_in[18];
  const float* lm_w = (const float*)d_in[19];
  const float* lm_b = (const float*)d_in[20];

  float* logits = (float*)d_out;
  float* loss = logits + (size_t)BT * V;

  size_t off = 0;
  auto alloc = [&](size_t bytes) -> void* {
    off = (off + 255) & ~(size_t)255;
    void* p = (void*)((char*)d_ws + off);
    off += bytes;
    return p;
  };
  u16* wqkv_t = (u16*)alloc((size_t)L * C3 * C * 2);  // [L][3C][C]
  u16* wo_t = (u16*)alloc((size_t)L * C * C * 2);
  u16* w1_t = (u16*)alloc((size_t)L * C * C4 * 2);
  u16* w2_t = (u16*)alloc((size_t)L * C4 * C * 2);
  u16* lmw_t = (u16*)alloc((size_t)V * C * 2);
  float* x = (float*)alloc((size_t)BT * C * 4);
  float* tmp = (float*)alloc((size_t)BT * C * 4);
  u16* xb = (u16*)alloc((size_t)BT * C * 2);
  u16* qkvb = (u16*)alloc((size_t)BT * C3 * 2);
  u16* vtb = (u16*)alloc((size_t)BT * C * 2);   // V transposed per (b,h)
  u16* attb = (u16*)alloc((size_t)BT * C * 2);
  u16* hb = (u16*)alloc((size_t)BT * C4 * 2);
  float* rowloss = (float*)alloc((size_t)BT * 4);

  dim3 blk(256);
  dim3 blk5(512);
  k_transpose<<<dim3(C / 64, C / 64, L), blk, 0, stream>>>(
      wq, wqkv_t, C, C, (size_t)C * C, (size_t)C3 * C);
  k_transpose<<<dim3(C / 64, C / 64, L), blk, 0, stream>>>(
      wk, wqkv_t + (size_t)C * C, C, C, (size_t)C * C, (size_t)C3 * C);
  k_transpose<<<dim3(C / 64, C / 64, L), blk, 0, stream>>>(
      wv, wqkv_t + (size_t)2 * C * C, C, C, (size_t)C * C, (size_t)C3 * C);
  k_transpose<<<dim3(C / 64, C / 64, L), blk, 0, stream>>>(
      wo, wo_t, C, C, (size_t)C * C, (size_t)C * C);
  k_transpose<<<dim3(C4 / 64, C / 64, L), blk, 0, stream>>>(
      w1, w1_t, C, C4, (size_t)C * C4, (size_t)C * C4);
  k_transpose<<<dim3(C / 64, C4 / 64, L), blk, 0, stream>>>(
      w2, w2_t, C4, C, (size_t)C4 * C, (size_t)C4 * C);
  k_transpose<<<dim3(V / 64, C / 64, 1), blk, 0, stream>>>(
      lm_w, lmw_t, C, V, 0, 0);

  k_embed<<<BT, blk, 0, stream>>>(index, tok_emb, pos_emb, x, xb);

  dim3 gQKV(C3 / 256, BT / 256);   // 12 x 16 = 192 wg (256^2)
  dim3 gCC(C / 128, BT / 128);     // 256 wg (128^2)
  dim3 gC4(C4 / 256, BT / 256);    // 256 wg (256^2)
  for (int l = 0; l < L; ++l) {
    const u16* wqkvt = wqkv_t + (size_t)l * C3 * C;
    const u16* wot = wo_t + (size_t)l * C * C;
    const u16* w1t = w1_t + (size_t)l * C * C4;
    const u16* w2t = w2_t + (size_t)l * C4 * C;

    k_gemm256<1, 0, 0, 0, 1><<<gQKV, blk5, 0, stream>>>(
        xb, wqkvt, nullptr, nullptr, nullptr, qkvb, vtb, BT, C3, C);
    k_attn<<<B * H * (T / 128), blk, 0, stream>>>(qkvb, vtb, attb);
    k_gemm<0, 0, 1, 1><<<gCC, blk, 0, stream>>>(
        attb, wot, bo + (size_t)l * C, x, tmp, nullptr, BT, C, C);
    k_ln<<<BT, blk, 0, stream>>>(tmp, ln1_g + (size_t)l * C,
                                 ln1_b + (size_t)l * C, x, xb);
    k_gemm256<1, 1, 1, 0, 0><<<gC4, blk5, 0, stream>>>(
        xb, w1t, b1 + (size_t)l * C4, nullptr, nullptr, hb, nullptr, BT, C4, C);
    k_gemm<0, 0, 1, 1><<<gCC, blk, 0, stream>>>(
        hb, w2t, b2 + (size_t)l * C, x, tmp, nullptr, BT, C, C4);
    k_ln<<<BT, blk, 0, stream>>>(tmp, ln2_g + (size_t)l * C,
                                 ln2_b + (size_t)l * C, x, xb);
  }
  k_ln<<<BT, blk, 0, stream>>>(x, lnf_g, lnf_b, x, xb);
  k_gemm256<0, 0, 1, 0, 0><<<dim3(V / 256, BT / 256), blk5, 0, stream>>>(
      xb, lmw_t, lm_b, nullptr, logits, nullptr, nullptr, BT, V, C);
  k_rowloss<<<BT, blk, 0, stream>>>(logits, targets, rowloss);
  k_lossreduce<<<1, blk, 0, stream>>>(rowloss, loss);
}

// Round 7
// 2718.511 us; speedup vs baseline: 1.3043x; 1.0635x over previous
//
#include <hip/hip_runtime.h>

typedef unsigned short u16;
typedef __attribute__((ext_vector_type(4))) float f32x4;
typedef __attribute__((ext_vector_type(8))) short s16x8;
typedef __attribute__((ext_vector_type(4))) short s16x4;

static constexpr int V = 32000;
static constexpr int C = 1024;
static constexpr int T = 1024;
static constexpr int H = 16;
static constexpr int L = 8;
static constexpr int B = 4;
static constexpr int HS = 64;
static constexpr int BT = B * T;   // 4096
static constexpr int C4 = 4 * C;   // 4096
static constexpr int C3 = 3 * C;   // 3072

__device__ __forceinline__ u16 f2bf(float f) {
  union { float f; unsigned u; } v; v.f = f;
  unsigned r = v.u + 0x7fffu + ((v.u >> 16) & 1u);
  return (u16)(r >> 16);
}

__device__ __forceinline__ void gload16(const u16* g, u16* l) {
  __builtin_amdgcn_global_load_lds(
      (const __attribute__((address_space(1))) void*)g,
      (__attribute__((address_space(3))) void*)l, 16, 0, 0);
}

// ---------- block reduction (256 threads) ----------
__device__ __forceinline__ float blockReduceSum(float v) {
  __shared__ float red[4];
  int lane = threadIdx.x & 63, w = threadIdx.x >> 6;
#pragma unroll
  for (int m = 32; m >= 1; m >>= 1) v += __shfl_xor(v, m, 64);
  if (lane == 0) red[w] = v;
  __syncthreads();
  float r = red[0] + red[1] + red[2] + red[3];
  __syncthreads();
  return r;
}

// ---------- embed ----------
__global__ __launch_bounds__(256) void k_embed(
    const int* __restrict__ idx, const float* __restrict__ tok,
    const float* __restrict__ pos, float* __restrict__ x, u16* __restrict__ xb) {
  int bt = blockIdx.x;
  int t = bt & (T - 1);
  int row = idx[bt];
  const float* te = tok + (size_t)row * C;
  const float* pe = pos + (size_t)t * C;
  float* xo = x + (size_t)bt * C;
  u16* xbo = xb + (size_t)bt * C;
  for (int c = threadIdx.x; c < C; c += 256) {
    float v = te[c] + pe[c];
    xo[c] = v;
    xbo[c] = f2bf(v);
  }
}

// ---------- weight convert+transpose: fp32 [K,N] -> bf16 [N,K] ----------
__global__ __launch_bounds__(256) void k_transpose(
    const float* __restrict__ W, u16* __restrict__ Wt, int K, int N,
    size_t sW, size_t sWt) {
  __shared__ float tile[64][65];
  const float* Wz = W + sW * blockIdx.z;
  u16* Wtz = Wt + sWt * blockIdx.z;
  int n0 = blockIdx.x * 64, k0 = blockIdx.y * 64;
  int tc = threadIdx.x & 63, tr = threadIdx.x >> 6;
#pragma unroll
  for (int i = 0; i < 16; ++i) {
    int r = tr + i * 4;
    tile[r][tc] = Wz[(size_t)(k0 + r) * N + (n0 + tc)];
  }
  __syncthreads();
#pragma unroll
  for (int i = 0; i < 16; ++i) {
    int r = tr + i * 4;  // n-offset within tile
    Wtz[(size_t)(n0 + r) * K + (k0 + tc)] = f2bf(tile[tc][r]);
  }
}

// ---------- GEMM 128x128 (m97 structure) for small-N shapes ----------
template <int OUT_BF16, int RELU, int HAS_BIAS, int HAS_RES>
__global__ __launch_bounds__(256, 2) void k_gemm(
    const u16* __restrict__ A, const u16* __restrict__ Bt,
    const float* __restrict__ bias, const float* __restrict__ Res,
    float* __restrict__ Cf, u16* __restrict__ Cb, int M, int N, int K) {
  __shared__ u16 As[128 * 32];
  __shared__ u16 Bs[128 * 32];
  int tid = threadIdx.x;
  int lane = tid & 63, wid = tid >> 6;
  int lm = lane & 15, lg = lane >> 4;
  int wm = wid >> 1, wn = wid & 1;

  unsigned nbx = gridDim.x;
  unsigned nwg = nbx * gridDim.y;
  unsigned orig = blockIdx.y * nbx + blockIdx.x;
  unsigned f = ((nwg & 7u) == 0u) ? (orig & 7u) * (nwg >> 3) + (orig >> 3) : orig;
  int mb = (int)(f / nbx) * 128, nb = (int)(f % nbx) * 128;

  f32x4 acc[4][4];
#pragma unroll
  for (int i = 0; i < 4; ++i)
#pragma unroll
    for (int j = 0; j < 4; ++j) acc[i][j] = f32x4{0.f, 0.f, 0.f, 0.f};

  int r0 = tid >> 2, q0 = tid & 3;
  int r1 = (256 + tid) >> 2, q1 = tid & 3;
  const u16* a0 = A + (size_t)(mb + r0) * K + q0 * 8;
  const u16* a1 = A + (size_t)(mb + r1) * K + q1 * 8;
  const u16* b0 = Bt + (size_t)(nb + r0) * K + q0 * 8;
  const u16* b1 = Bt + (size_t)(nb + r1) * K + q1 * 8;
  u16* lA0 = &As[wid * 512];
  u16* lA1 = &As[2048 + wid * 512];
  u16* lB0 = &Bs[wid * 512];
  u16* lB1 = &Bs[2048 + wid * 512];

  int nK = K >> 5;
  for (int kb = 0; kb < nK; ++kb) {
    __syncthreads();
    int ko = kb * 32;
    gload16(a0 + ko, lA0);
    gload16(a1 + ko, lA1);
    gload16(b0 + ko, lB0);
    gload16(b1 + ko, lB1);
    __syncthreads();
    s16x8 af[4], bfr[4];
#pragma unroll
    for (int m = 0; m < 4; ++m)
      af[m] = *(const s16x8*)&As[(wm * 64 + m * 16 + lm) * 32 + lg * 8];
#pragma unroll
    for (int n = 0; n < 4; ++n)
      bfr[n] = *(const s16x8*)&Bs[(wn * 64 + n * 16 + lm) * 32 + lg * 8];
#pragma unroll
    for (int m = 0; m < 4; ++m)
#pragma unroll
      for (int n = 0; n < 4; ++n)
        acc[m][n] = __builtin_amdgcn_mfma_f32_16x16x32_bf16(af[m], bfr[n],
                                                            acc[m][n], 0, 0, 0);
  }
#pragma unroll
  for (int m = 0; m < 4; ++m) {
#pragma unroll
    for (int n = 0; n < 4; ++n) {
      int col = nb + wn * 64 + n * 16 + lm;
      float bv = HAS_BIAS ? bias[col] : 0.0f;
#pragma unroll
      for (int r = 0; r < 4; ++r) {
        int row = mb + wm * 64 + m * 16 + lg * 4 + r;
        float v = acc[m][n][r] + bv;
        if (HAS_RES) v += Res[(size_t)row * N + col];
        if (RELU) v = v > 0.f ? v : 0.f;
        if (OUT_BF16)
          Cb[(size_t)row * N + col] = f2bf(v);
        else
          Cf[(size_t)row * N + col] = v;
      }
    }
  }
}

// ---------- GEMM 256x256 8-phase (T2+T3+T4+T5) for big-N shapes ----------
// VT=1 (QKV): blocks with nb>=2C write the V projection transposed into Vt.
// LOSS=1 (lm_head): epilogue also emits per-(row, 256-col block) online
// softmax stats (max, sumexp) into Pp[row*128 + nb/256].
template <int OUT_BF16, int RELU, int HAS_BIAS, int HAS_RES, int VT, int LOSS>
__global__ __launch_bounds__(512) void k_gemm256(
    const u16* __restrict__ A, const u16* __restrict__ Bt,
    const float* __restrict__ bias, const float* __restrict__ Res,
    float* __restrict__ Cf, u16* __restrict__ Cb, u16* __restrict__ Vtp,
    float2* __restrict__ Pp, int M, int N, int K) {
  __shared__ u16 As[2][16384];
  __shared__ u16 Bs[2][16384];
  const int tid = threadIdx.x;
  const int lane = tid & 63, wid = tid >> 6;
  const int lm = lane & 15, lg = lane >> 4;
  const int wr = wid >> 2, wc = wid & 3;

  unsigned nbx = gridDim.x;
  unsigned nwg = nbx * gridDim.y;
  unsigned orig = blockIdx.y * nbx + blockIdx.x;
  unsigned f = ((nwg & 7u) == 0u) ? (orig & 7u) * (nwg >> 3) + (orig >> 3) : orig;
  const int mb = (int)(f / nbx) * 256, nb = (int)(f % nbx) * 256;

  int aoff[4], boff[4], ldso[4];
#pragma unroll
  for (int h = 0; h < 4; ++h) {
    const int kk = h >> 1, p = h & 1;
    int rem = p * 512 + tid;
    int rblk = rem >> 6;
    int rem2 = rem & 63;
    int row16 = rem2 >> 2, psl = rem2 & 3;
    int sl = psl ^ ((row16 >> 1) & 3);
    int grow = rblk * 16 + row16;
    int gk = kk * 32 + sl * 8;
    aoff[h] = (mb + grow) * K + gk;
    boff[h] = (nb + grow) * K + gk;
    ldso[h] = kk * 8192 + p * 4096 + wid * 512;
  }
  const int lo = lm * 32 + ((lg ^ ((lm >> 1) & 3)) << 3);

  f32x4 acc[8][4];
#pragma unroll
  for (int i = 0; i < 8; ++i)
#pragma unroll
    for (int j = 0; j < 4; ++j) acc[i][j] = f32x4{0.f, 0.f, 0.f, 0.f};

  const int nK = K >> 6;
  gload16(A + aoff[0], &As[0][ldso[0]]);
  gload16(A + aoff[1], &As[0][ldso[1]]);
  gload16(Bt + boff[0], &Bs[0][ldso[0]]);
  gload16(Bt + boff[1], &Bs[0][ldso[1]]);
  gload16(A + aoff[2], &As[0][ldso[2]]);
  gload16(A + aoff[3], &As[0][ldso[3]]);
  gload16(Bt + boff[2], &Bs[0][ldso[2]]);
  gload16(Bt + boff[3], &Bs[0][ldso[3]]);
  asm volatile("s_waitcnt vmcnt(4)" ::: "memory");
  __builtin_amdgcn_s_barrier();

  for (int t = 0; t < nK; ++t) {
    const int buf = t & 1, nbuf = buf ^ 1;
    const bool pre = (t + 1 < nK);
    const int nk64 = (t + 1) * 64;
    s16x8 af[4], bfr[4];
    // P1: kk0 A m0-3 + B; stage Ak0(t+1)
#pragma unroll
    for (int m = 0; m < 4; ++m)
      af[m] = *(const s16x8*)&As[buf][(wr * 8 + m) * 512 + lo];
#pragma unroll
    for (int n = 0; n < 4; ++n)
      bfr[n] = *(const s16x8*)&Bs[buf][(wc * 4 + n) * 512 + lo];
    if (pre) {
      gload16(A + aoff[0] + nk64, &As[nbuf][ldso[0]]);
      gload16(A + aoff[1] + nk64, &As[nbuf][ldso[1]]);
    }
    __builtin_amdgcn_s_barrier();
    __builtin_amdgcn_s_setprio(1);
#pragma unroll
    for (int m = 0; m < 4; ++m)
#pragma unroll
      for (int n = 0; n < 4; ++n)
        acc[m][n] = __builtin_amdgcn_mfma_f32_16x16x32_bf16(af[m], bfr[n],
                                                            acc[m][n], 0, 0, 0);
    __builtin_amdgcn_s_setprio(0);
    __builtin_amdgcn_s_barrier();
    // P2: kk0 A m4-7; stage Bk0(t+1)
#pragma unroll
    for (int m = 0; m < 4; ++m)
      af[m] = *(const s16x8*)&As[buf][(wr * 8 + 4 + m) * 512 + lo];
    if (pre) {
      gload16(Bt + boff[0] + nk64, &Bs[nbuf][ldso[0]]);
      gload16(Bt + boff[1] + nk64, &Bs[nbuf][ldso[1]]);
    }
    __builtin_amdgcn_s_barrier();
    __builtin_amdgcn_s_setprio(1);
#pragma unroll
    for (int m = 0; m < 4; ++m)
#pragma unroll
      for (int n = 0; n < 4; ++n)
        acc[m + 4][n] = __builtin_amdgcn_mfma_f32_16x16x32_bf16(
            af[m], bfr[n], acc[m + 4][n], 0, 0, 0);
    __builtin_amdgcn_s_setprio(0);
    __builtin_amdgcn_s_barrier();
    // P3: kk1 A m0-3 + B; stage Ak1(t+1); gate kk1(t)
#pragma unroll
    for (int m = 0; m < 4; ++m)
      af[m] = *(const s16x8*)&As[buf][8192 + (wr * 8 + m) * 512 + lo];
#pragma unroll
    for (int n = 0; n < 4; ++n)
      bfr[n] = *(const s16x8*)&Bs[buf][8192 + (wc * 4 + n) * 512 + lo];
    if (pre) {
      gload16(A + aoff[2] + nk64, &As[nbuf][ldso[2]]);
      gload16(A + aoff[3] + nk64, &As[nbuf][ldso[3]]);
      asm volatile("s_waitcnt vmcnt(6)" ::: "memory");
    } else {
      asm volatile("s_waitcnt vmcnt(0)" ::: "memory");
    }
    __builtin_amdgcn_s_barrier();
    __builtin_amdgcn_s_setprio(1);
#pragma unroll
    for (int m = 0; m < 4; ++m)
#pragma unroll
      for (int n = 0; n < 4; ++n)
        acc[m][n] = __builtin_amdgcn_mfma_f32_16x16x32_bf16(af[m], bfr[n],
                                                            acc[m][n], 0, 0, 0);
    __builtin_amdgcn_s_setprio(0);
    __builtin_amdgcn_s_barrier();
    // P4: kk1 A m4-7; stage Bk1(t+1); gate kk0(t+1)
#pragma unroll
    for (int m = 0; m < 4; ++m)
      af[m] = *(const s16x8*)&As[buf][8192 + (wr * 8 + 4 + m) * 512 + lo];
    if (pre) {
      gload16(Bt + boff[2] + nk64, &Bs[nbuf][ldso[2]]);
      gload16(Bt + boff[3] + nk64, &Bs[nbuf][ldso[3]]);
      asm volatile("s_waitcnt vmcnt(4)" ::: "memory");
    }
    __builtin_amdgcn_s_barrier();
    __builtin_amdgcn_s_setprio(1);
#pragma unroll
    for (int m = 0; m < 4; ++m)
#pragma unroll
      for (int n = 0; n < 4; ++n)
        acc[m + 4][n] = __builtin_amdgcn_mfma_f32_16x16x32_bf16(
            af[m], bfr[n], acc[m + 4][n], 0, 0, 0);
    __builtin_amdgcn_s_setprio(0);
    __builtin_amdgcn_s_barrier();
  }
  // ---- epilogue ----
  if (VT && nb >= 2 * C) {
    int hh = ((nb - 2 * C) >> 6) + wc;  // head index (uniform per wave)
#pragma unroll
    for (int m = 0; m < 8; ++m) {
      int t0 = mb + wr * 128 + m * 16 + lg * 4;
      int bb = t0 >> 10, tt = t0 & (T - 1);
      size_t vbase = ((size_t)(bb * H + hh) * HS) * T + tt;
#pragma unroll
      for (int n = 0; n < 4; ++n) {
        int d = n * 16 + lm;
        s16x4 pk;
#pragma unroll
        for (int r = 0; r < 4; ++r) pk[r] = (short)f2bf(acc[m][n][r]);
        *(s16x4*)&Vtp[vbase + (size_t)d * T] = pk;
      }
    }
    return;
  }
  float bv[4];
#pragma unroll
  for (int n = 0; n < 4; ++n)
    bv[n] = HAS_BIAS ? bias[nb + wc * 64 + n * 16 + lm] : 0.0f;
#pragma unroll
  for (int m = 0; m < 8; ++m) {
#pragma unroll
    for (int r = 0; r < 4; ++r) {
      int row = mb + wr * 128 + m * 16 + lg * 4 + r;
#pragma unroll
      for (int n = 0; n < 4; ++n) {
        int col = nb + wc * 64 + n * 16 + lm;
        float v = acc[m][n][r] + bv[n];
        if (HAS_RES) v += Res[(size_t)row * N + col];
        if (RELU) v = v > 0.f ? v : 0.f;
        if (OUT_BF16)
          Cb[(size_t)row * N + col] = f2bf(v);
        else
          Cf[(size_t)row * N + col] = v;
      }
    }
  }
  if (LOSS) {
    // per-row (max, sumexp) over this block's 256 cols -> Pp[row*128+nblk]
    __syncthreads();
    float* red = (float*)&As[0][0];  // 256 rows x 4 waves x 4B = 4KB
    float Mx[8][4], Sx[8][4];
#pragma unroll
    for (int m = 0; m < 8; ++m)
#pragma unroll
      for (int r = 0; r < 4; ++r) {
        float v0 = acc[m][0][r] + bv[0];
        float v1 = acc[m][1][r] + bv[1];
        float v2 = acc[m][2][r] + bv[2];
        float v3 = acc[m][3][r] + bv[3];
        Mx[m][r] = fmaxf(fmaxf(v0, v1), fmaxf(v2, v3));
      }
#pragma unroll
    for (int d = 1; d < 16; d <<= 1)
#pragma unroll
      for (int m = 0; m < 8; ++m)
#pragma unroll
        for (int r = 0; r < 4; ++r)
          Mx[m][r] = fmaxf(Mx[m][r], __shfl_xor(Mx[m][r], d, 16));
    if (lm == 0) {
#pragma unroll
      for (int m = 0; m < 8; ++m)
#pragma unroll
        for (int r = 0; r < 4; ++r)
          red[(wr * 128 + m * 16 + lg * 4 + r) * 4 + wc] = Mx[m][r];
    }
    __syncthreads();
#pragma unroll
    for (int m = 0; m < 8; ++m)
#pragma unroll
      for (int r = 0; r < 4; ++r) {
        int rl = wr * 128 + m * 16 + lg * 4 + r;
        Mx[m][r] = fmaxf(fmaxf(red[rl * 4 + 0], red[rl * 4 + 1]),
                         fmaxf(red[rl * 4 + 2], red[rl * 4 + 3]));
      }
    __syncthreads();
#pragma unroll
    for (int m = 0; m < 8; ++m)
#pragma unroll
      for (int r = 0; r < 4; ++r)
        Sx[m][r] = __expf(acc[m][0][r] + bv[0] - Mx[m][r]) +
                   __expf(acc[m][1][r] + bv[1] - Mx[m][r]) +
                   __expf(acc[m][2][r] + bv[2] - Mx[m][r]) +
                   __expf(acc[m][3][r] + bv[3] - Mx[m][r]);
#pragma unroll
    for (int d = 1; d < 16; d <<= 1)
#pragma unroll
      for (int m = 0; m < 8; ++m)
#pragma unroll
        for (int r = 0; r < 4; ++r)
          Sx[m][r] += __shfl_xor(Sx[m][r], d, 16);
    if (lm == 0) {
#pragma unroll
      for (int m = 0; m < 8; ++m)
#pragma unroll
        for (int r = 0; r < 4; ++r)
          red[(wr * 128 + m * 16 + lg * 4 + r) * 4 + wc] = Sx[m][r];
    }
    __syncthreads();
    if (wc == 0 && lm == 0) {
      int nblk = nb >> 8;
#pragma unroll
      for (int m = 0; m < 8; ++m)
#pragma unroll
        for (int r = 0; r < 4; ++r) {
          int rl = wr * 128 + m * 16 + lg * 4 + r;
          float ss = red[rl * 4 + 0] + red[rl * 4 + 1] + red[rl * 4 + 2] +
                     red[rl * 4 + 3];
          Pp[(size_t)(mb + rl) * 128 + nblk] = float2{Mx[m][r], ss};
        }
    }
  }
}

// ---------- flash attention v4: QBLK=64, paired q-tiles {p, 15-p} ----------
// Uniform 17 k-tile units per block -> immune to block->XCD mapping skew.
// K tile [64 kv][64 d], Vt tile [64 d][64 t] staged via gload_lds with chunk
// XOR-swizzle on the source, matching XOR on ds_read.
__global__ __launch_bounds__(256) void k_attn(
    const u16* __restrict__ qkv, const u16* __restrict__ vt,
    u16* __restrict__ o) {
  constexpr int PP = 72;
  __shared__ u16 Ks[64 * 64];
  __shared__ u16 Vs[64 * 64];
  __shared__ u16 Ps[4][16 * PP];
  int bid = blockIdx.x;  // p | h | b
  int p = bid & 7, h = (bid >> 3) & 15, b = bid >> 7;
  int tid = threadIdx.x, lane = tid & 63, wid = tid >> 6;
  int lm = lane & 15, lg = lane >> 4;
  const size_t rowbase = (size_t)b * T * C3 + (size_t)h * HS;
  const u16* kbase = qkv + rowbase + C;
  const u16* vbase = vt + (size_t)(b * H + h) * HS * T;
  const size_t obase = (size_t)b * T * C + (size_t)h * HS;
  const float scale = 0.125f;
  const int sr = tid >> 3, scs = (tid & 7) ^ (sr & 7);
  const int swz0 = (lg ^ (lm & 7)) * 8;
  const int swz1 = ((4 + lg) ^ (lm & 7)) * 8;

  for (int qi = 0; qi < 2; ++qi) {
    int qt = qi ? (15 - p) : p;
    int qw = qt * 64 + wid * 16;
    s16x8 qf[2];
#pragma unroll
    for (int s = 0; s < 2; ++s)
      qf[s] = *(const s16x8*)&qkv[rowbase + (size_t)(qw + lm) * C3 + s * 32 +
                                  lg * 8];
    float m_[4], l_[4];
    f32x4 oacc[4];
#pragma unroll
    for (int r = 0; r < 4; ++r) { m_[r] = -3e38f; l_[r] = 0.f; }
#pragma unroll
    for (int n = 0; n < 4; ++n) oacc[n] = f32x4{0.f, 0.f, 0.f, 0.f};

    for (int kt = 0; kt <= qt; ++kt) {
      __syncthreads();
      gload16(kbase + (size_t)(kt * 64 + sr) * C3 + scs * 8, &Ks[wid * 512]);
      gload16(kbase + (size_t)(kt * 64 + sr + 32) * C3 + scs * 8,
              &Ks[2048 + wid * 512]);
      gload16(vbase + (size_t)sr * T + kt * 64 + scs * 8, &Vs[wid * 512]);
      gload16(vbase + (size_t)(sr + 32) * T + kt * 64 + scs * 8,
              &Vs[2048 + wid * 512]);
      __syncthreads();  // drains vmcnt before barrier

      f32x4 s[4];
#pragma unroll
      for (int ch = 0; ch < 4; ++ch) {
        s16x8 k0 = *(const s16x8*)&Ks[(ch * 16 + lm) * 64 + swz0];
        s16x8 k1 = *(const s16x8*)&Ks[(ch * 16 + lm) * 64 + swz1];
        s[ch] = f32x4{0.f, 0.f, 0.f, 0.f};
        s[ch] = __builtin_amdgcn_mfma_f32_16x16x32_bf16(qf[0], k0, s[ch], 0, 0, 0);
        s[ch] = __builtin_amdgcn_mfma_f32_16x16x32_bf16(qf[1], k1, s[ch], 0, 0, 0);
      }
      if (kt == qt) {  // diagonal tile: mask
#pragma unroll
        for (int ch = 0; ch < 4; ++ch) {
          int col = kt * 64 + ch * 16 + lm;
#pragma unroll
          for (int r = 0; r < 4; ++r) {
            int row = qw + lg * 4 + r;
            s[ch][r] = (col <= row) ? s[ch][r] * scale : -3e38f;
          }
        }
      } else {
#pragma unroll
        for (int ch = 0; ch < 4; ++ch)
#pragma unroll
          for (int r = 0; r < 4; ++r) s[ch][r] *= scale;
      }
      float rmax[4];
#pragma unroll
      for (int r = 0; r < 4; ++r)
        rmax[r] = fmaxf(fmaxf(s[0][r], s[1][r]), fmaxf(s[2][r], s[3][r]));
#pragma unroll
      for (int mm = 1; mm < 16; mm <<= 1)
#pragma unroll
        for (int r = 0; r < 4; ++r)
          rmax[r] = fmaxf(rmax[r], __shfl_xor(rmax[r], mm, 16));
      float alpha[4], rsum[4];
#pragma unroll
      for (int r = 0; r < 4; ++r) {
        float mn = fmaxf(m_[r], rmax[r]);
        alpha[r] = __expf(m_[r] - mn);
        m_[r] = mn;
        rsum[r] = 0.f;
      }
#pragma unroll
      for (int ch = 0; ch < 4; ++ch)
#pragma unroll
        for (int r = 0; r < 4; ++r) {
          float e = __expf(s[ch][r] - m_[r]);
          s[ch][r] = e;
          rsum[r] += e;
        }
#pragma unroll
      for (int mm = 1; mm < 16; mm <<= 1)
#pragma unroll
        for (int r = 0; r < 4; ++r) rsum[r] += __shfl_xor(rsum[r], mm, 16);
#pragma unroll
      for (int r = 0; r < 4; ++r) l_[r] = l_[r] * alpha[r] + rsum[r];
#pragma unroll
      for (int n = 0; n < 4; ++n)
#pragma unroll
        for (int r = 0; r < 4; ++r) oacc[n][r] *= alpha[r];
#pragma unroll
      for (int r = 0; r < 4; ++r) {
        int pr = lg * 4 + r;
#pragma unroll
        for (int ch = 0; ch < 4; ++ch)
          Ps[wid][pr * PP + ch * 16 + lm] = f2bf(s[ch][r]);
      }
      s16x8 pa0 = *(const s16x8*)&Ps[wid][lm * PP + lg * 8];
      s16x8 pa1 = *(const s16x8*)&Ps[wid][lm * PP + 32 + lg * 8];
#pragma unroll
      for (int n = 0; n < 4; ++n) {
        s16x8 v0 = *(const s16x8*)&Vs[(n * 16 + lm) * 64 + swz0];
        s16x8 v1 = *(const s16x8*)&Vs[(n * 16 + lm) * 64 + swz1];
        oacc[n] =
            __builtin_amdgcn_mfma_f32_16x16x32_bf16(pa0, v0, oacc[n], 0, 0, 0);
        oacc[n] =
            __builtin_amdgcn_mfma_f32_16x16x32_bf16(pa1, v1, oacc[n], 0, 0, 0);
      }
    }
    float inv[4];
#pragma unroll
    for (int r = 0; r < 4; ++r) inv[r] = 1.0f / l_[r];
#pragma unroll
    for (int n = 0; n < 4; ++n)
#pragma unroll
      for (int r = 0; r < 4; ++r)
        o[obase + (size_t)(qw + lg * 4 + r) * C + n * 16 + lm] =
            f2bf(oacc[n][r] * inv[r]);
  }
}

// ---------- LayerNorm ----------
__global__ __launch_bounds__(256) void k_ln(
    const float* __restrict__ in, const float* __restrict__ g,
    const float* __restrict__ bsh, float* __restrict__ xout,
    u16* __restrict__ xbout) {
  int row = blockIdx.x;
  const float* xr = in + (size_t)row * C;
  int tid = threadIdx.x;
  float vals[4];
  float s = 0.f;
#pragma unroll
  for (int i = 0; i < 4; ++i) {
    float vv = xr[tid + i * 256];
    vals[i] = vv;
    s += vv;
  }
  s = blockReduceSum(s);
  float mean = s * (1.0f / C);
  float s2 = 0.f;
#pragma unroll
  for (int i = 0; i < 4; ++i) {
    float d = vals[i] - mean;
    s2 += d * d;
  }
  s2 = blockReduceSum(s2);
  float rstd = rsqrtf(s2 * (1.0f / C) + 1e-5f);
#pragma unroll
  for (int i = 0; i < 4; ++i) {
    int c = tid + i * 256;
    float y = (vals[i] - mean) * rstd * g[c] + bsh[c];
    xout[(size_t)row * C + c] = y;
    xbout[(size_t)row * C + c] = f2bf(y);
  }
}

// ---------- loss: merge per-block stats + target logit ----------
__global__ __launch_bounds__(128) void k_rowloss2(
    const float2* __restrict__ pairs, const float* __restrict__ logits,
    const int* __restrict__ tgt, float* __restrict__ rowloss) {
  int row = blockIdx.x;
  int tid = threadIdx.x;
  float m = -3e38f, s = 0.f;
  if (tid < 125) {
    float2 pv = pairs[(size_t)row * 128 + tid];
    m = pv.x;
    s = pv.y;
  }
#pragma unroll
  for (int d = 1; d < 64; d <<= 1) {
    float mo = __shfl_xor(m, d, 64), so = __shfl_xor(s, d, 64);
    float mn = fmaxf(m, mo);
    s = s * __expf(m - mn) + so * __expf(mo - mn);
    m = mn;
  }
  __shared__ float sm[2], ss[2];
  if ((tid & 63) == 0) { sm[tid >> 6] = m; ss[tid >> 6] = s; }
  __syncthreads();
  if (tid == 0) {
    float M = fmaxf(sm[0], sm[1]);
    float S = ss[0] * __expf(sm[0] - M) + ss[1] * __expf(sm[1] - M);
    rowloss[row] = (M + logf(S)) - logits[(size_t)row * V + tgt[row]];
  }
}

__global__ __launch_bounds__(256) void k_lossreduce(
    const float* __restrict__ rowloss, float* __restrict__ out) {
  __shared__ float red[256];
  int tid = threadIdx.x;
  float s = 0.f;
  for (int i = tid; i < BT; i += 256) s += rowloss[i];
  red[tid] = s;
  __syncthreads();
  for (int m = 128; m >= 1; m >>= 1) {
    if (tid < m) red[tid] += red[tid + m];
    __syncthreads();
  }
  if (tid == 0) out[0] = red[0] * (1.0f / BT);
}

// ---------------- host orchestration ----------------
extern "C" void kernel_launch(void* const* d_in, const int* in_sizes, int n_in,
                              void* d_out, int out_size, void* d_ws,
                              size_t ws_size, hipStream_t stream) {
  (void)in_sizes; (void)n_in; (void)out_size; (void)ws_size;
  const int* index = (const int*)d_in[0];
  const int* targets = (const int*)d_in[1];
  const float* tok_emb = (const float*)d_in[2];
  const float* pos_emb = (const float*)d_in[3];
  const float* wq = (const float*)d_in[4];
  const float* wk = (const float*)d_in[5];
  const float* wv = (const float*)d_in[6];
  const float* wo = (const float*)d_in[7];
  const float* bo = (const float*)d_in[8];
  const float* w1 = (const float*)d_in[9];
  const float* b1 = (const float*)d_in[10];
  const float* w2 = (const float*)d_in[11];
  const float* b2 = (const float*)d_in[12];
  const float* ln1_g = (const float*)d_in[13];
  const float* ln1_b = (const float*)d_in[14];
  const float* ln2_g = (const float*)d_in[15];
  const float* ln2_b = (const float*)d_in[16];
  const float* lnf_g = (const float*)d_in[17];
  const float* lnf_b = (const float*)d_in[18];
  const float* lm_w = (const float*)d_in[19];
  const float* lm_b = (const float*)d_in[20];

  float* logits = (float*)d_out;
  float* loss = logits + (size_t)BT * V;

  size_t off = 0;
  auto alloc = [&](size_t bytes) -> void* {
    off = (off + 255) & ~(size_t)255;
    void* p = (void*)((char*)d_ws + off);
    off += bytes;
    return p;
  };
  u16* wqkv_t = (u16*)alloc((size_t)L * C3 * C * 2);  // [L][3C][C]
  u16* wo_t = (u16*)alloc((size_t)L * C * C * 2);
  u16* w1_t = (u16*)alloc((size_t)L * C * C4 * 2);
  u16* w2_t = (u16*)alloc((size_t)L * C4 * C * 2);
  u16* lmw_t = (u16*)alloc((size_t)V * C * 2);
  float* x = (float*)alloc((size_t)BT * C * 4);
  float* tmp = (float*)alloc((size_t)BT * C * 4);
  u16* xb = (u16*)alloc((size_t)BT * C * 2);
  u16* qkvb = (u16*)alloc((size_t)BT * C3 * 2);
  u16* vtb = (u16*)alloc((size_t)BT * C * 2);   // V transposed per (b,h)
  u16* attb = (u16*)alloc((size_t)BT * C * 2);
  u16* hb = (u16*)alloc((size_t)BT * C4 * 2);
  float* rowloss = (float*)alloc((size_t)BT * 4);
  float2* pairs = (float2*)alloc((size_t)BT * 128 * 8);

  dim3 blk(256);
  dim3 blk5(512);
  k_transpose<<<dim3(C / 64, C / 64, L), blk, 0, stream>>>(
      wq, wqkv_t, C, C, (size_t)C * C, (size_t)C3 * C);
  k_transpose<<<dim3(C / 64, C / 64, L), blk, 0, stream>>>(
      wk, wqkv_t + (size_t)C * C, C, C, (size_t)C * C, (size_t)C3 * C);
  k_transpose<<<dim3(C / 64, C / 64, L), blk, 0, stream>>>(
      wv, wqkv_t + (size_t)2 * C * C, C, C, (size_t)C * C, (size_t)C3 * C);
  k_transpose<<<dim3(C / 64, C / 64, L), blk, 0, stream>>>(
      wo, wo_t, C, C, (size_t)C * C, (size_t)C * C);
  k_transpose<<<dim3(C4 / 64, C / 64, L), blk, 0, stream>>>(
      w1, w1_t, C, C4, (size_t)C * C4, (size_t)C * C4);
  k_transpose<<<dim3(C / 64, C4 / 64, L), blk, 0, stream>>>(
      w2, w2_t, C4, C, (size_t)C4 * C, (size_t)C4 * C);
  k_transpose<<<dim3(V / 64, C / 64, 1), blk, 0, stream>>>(
      lm_w, lmw_t, C, V, 0, 0);

  k_embed<<<BT, blk, 0, stream>>>(index, tok_emb, pos_emb, x, xb);

  dim3 gQKV(C3 / 256, BT / 256);   // 12 x 16 = 192 wg (256^2)
  dim3 gCC(C / 128, BT / 128);     // 256 wg (128^2)
  dim3 gC4(C4 / 256, BT / 256);    // 256 wg (256^2)
  for (int l = 0; l < L; ++l) {
    const u16* wqkvt = wqkv_t + (size_t)l * C3 * C;
    const u16* wot = wo_t + (size_t)l * C * C;
    const u16* w1t = w1_t + (size_t)l * C * C4;
    const u16* w2t = w2_t + (size_t)l * C4 * C;

    k_gemm256<1, 0, 0, 0, 1, 0><<<gQKV, blk5, 0, stream>>>(
        xb, wqkvt, nullptr, nullptr, nullptr, qkvb, vtb, nullptr, BT, C3, C);
    k_attn<<<B * H * 8, blk, 0, stream>>>(qkvb, vtb, attb);
    k_gemm<0, 0, 1, 1><<<gCC, blk, 0, stream>>>(
        attb, wot, bo + (size_t)l * C, x, tmp, nullptr, BT, C, C);
    k_ln<<<BT, blk, 0, stream>>>(tmp, ln1_g + (size_t)l * C,
                                 ln1_b + (size_t)l * C, x, xb);
    k_gemm256<1, 1, 1, 0, 0, 0><<<gC4, blk5, 0, stream>>>(
        xb, w1t, b1 + (size_t)l * C4, nullptr, nullptr, hb, nullptr, nullptr,
        BT, C4, C);
    k_gemm<0, 0, 1, 1><<<gCC, blk, 0, stream>>>(
        hb, w2t, b2 + (size_t)l * C, x, tmp, nullptr, BT, C, C4);
    k_ln<<<BT, blk, 0, stream>>>(tmp, ln2_g + (size_t)l * C,
                                 ln2_b + (size_t)l * C, x, xb);
  }
  k_ln<<<BT, blk, 0, stream>>>(x, lnf_g, lnf_b, x, xb);
  k_gemm256<0, 0, 1, 0, 0, 1><<<dim3(V / 256, BT / 256), blk5, 0, stream>>>(
      xb, lmw_t, lm_b, nullptr, logits, nullptr, nullptr, pairs, BT, V, C);
  k_rowloss2<<<BT, dim3(128), 0, stream>>>(pairs, logits, targets, rowloss);
  k_lossreduce<<<1, blk, 0, stream>>>(rowloss, loss);
}

// Round 8
// 2679.978 us; speedup vs baseline: 1.3231x; 1.0144x over previous
//
#include <hip/hip_runtime.h>

typedef unsigned short u16;
typedef __attribute__((ext_vector_type(4))) float f32x4;
typedef __attribute__((ext_vector_type(8))) short s16x8;
typedef __attribute__((ext_vector_type(4))) short s16x4;

static constexpr int V = 32000;
static constexpr int C = 1024;
static constexpr int T = 1024;
static constexpr int H = 16;
static constexpr int L = 8;
static constexpr int B = 4;
static constexpr int HS = 64;
static constexpr int BT = B * T;   // 4096
static constexpr int C4 = 4 * C;   // 4096
static constexpr int C3 = 3 * C;   // 3072

__device__ __forceinline__ u16 f2bf(float f) {
  union { float f; unsigned u; } v; v.f = f;
  unsigned r = v.u + 0x7fffu + ((v.u >> 16) & 1u);
  return (u16)(r >> 16);
}

__device__ __forceinline__ void gload16(const u16* g, u16* l) {
  __builtin_amdgcn_global_load_lds(
      (const __attribute__((address_space(1))) void*)g,
      (__attribute__((address_space(3))) void*)l, 16, 0, 0);
}

// ---------- block reduction (256 threads) ----------
__device__ __forceinline__ float blockReduceSum(float v) {
  __shared__ float red[4];
  int lane = threadIdx.x & 63, w = threadIdx.x >> 6;
#pragma unroll
  for (int m = 32; m >= 1; m >>= 1) v += __shfl_xor(v, m, 64);
  if (lane == 0) red[w] = v;
  __syncthreads();
  float r = red[0] + red[1] + red[2] + red[3];
  __syncthreads();
  return r;
}

// ---------- embed (vectorized: one float4 per thread) ----------
__global__ __launch_bounds__(256) void k_embed(
    const int* __restrict__ idx, const float* __restrict__ tok,
    const float* __restrict__ pos, float* __restrict__ x, u16* __restrict__ xb) {
  int bt = blockIdx.x;
  int t = bt & (T - 1);
  int row = idx[bt];
  int tid = threadIdx.x;
  f32x4 tv = ((const f32x4*)(tok + (size_t)row * C))[tid];
  f32x4 pv = ((const f32x4*)(pos + (size_t)t * C))[tid];
  f32x4 y;
  s16x4 yb;
#pragma unroll
  for (int j = 0; j < 4; ++j) {
    y[j] = tv[j] + pv[j];
    yb[j] = (short)f2bf(y[j]);
  }
  ((f32x4*)(x + (size_t)bt * C))[tid] = y;
  ((s16x4*)(xb + (size_t)bt * C))[tid] = yb;
}

// ---------- weight convert+transpose: fp32 [K,N] -> bf16 [N,K] ----------
__global__ __launch_bounds__(256) void k_transpose(
    const float* __restrict__ W, u16* __restrict__ Wt, int K, int N,
    size_t sW, size_t sWt) {
  __shared__ float tile[64][65];
  const float* Wz = W + sW * blockIdx.z;
  u16* Wtz = Wt + sWt * blockIdx.z;
  int n0 = blockIdx.x * 64, k0 = blockIdx.y * 64;
  int tc = threadIdx.x & 63, tr = threadIdx.x >> 6;
#pragma unroll
  for (int i = 0; i < 16; ++i) {
    int r = tr + i * 4;
    tile[r][tc] = Wz[(size_t)(k0 + r) * N + (n0 + tc)];
  }
  __syncthreads();
#pragma unroll
  for (int i = 0; i < 16; ++i) {
    int r = tr + i * 4;  // n-offset within tile
    Wtz[(size_t)(n0 + r) * K + (k0 + tc)] = f2bf(tile[tc][r]);
  }
}

// ---------- GEMM 128x128 (m97 structure) for small-N shapes ----------
template <int OUT_BF16, int RELU, int HAS_BIAS, int HAS_RES>
__global__ __launch_bounds__(256, 2) void k_gemm(
    const u16* __restrict__ A, const u16* __restrict__ Bt,
    const float* __restrict__ bias, const float* __restrict__ Res,
    float* __restrict__ Cf, u16* __restrict__ Cb, int M, int N, int K) {
  __shared__ u16 As[128 * 32];
  __shared__ u16 Bs[128 * 32];
  int tid = threadIdx.x;
  int lane = tid & 63, wid = tid >> 6;
  int lm = lane & 15, lg = lane >> 4;
  int wm = wid >> 1, wn = wid & 1;

  unsigned nbx = gridDim.x;
  unsigned nwg = nbx * gridDim.y;
  unsigned orig = blockIdx.y * nbx + blockIdx.x;
  unsigned f = ((nwg & 7u) == 0u) ? (orig & 7u) * (nwg >> 3) + (orig >> 3) : orig;
  int mb = (int)(f / nbx) * 128, nb = (int)(f % nbx) * 128;

  f32x4 acc[4][4];
#pragma unroll
  for (int i = 0; i < 4; ++i)
#pragma unroll
    for (int j = 0; j < 4; ++j) acc[i][j] = f32x4{0.f, 0.f, 0.f, 0.f};

  int r0 = tid >> 2, q0 = tid & 3;
  int r1 = (256 + tid) >> 2, q1 = tid & 3;
  const u16* a0 = A + (size_t)(mb + r0) * K + q0 * 8;
  const u16* a1 = A + (size_t)(mb + r1) * K + q1 * 8;
  const u16* b0 = Bt + (size_t)(nb + r0) * K + q0 * 8;
  const u16* b1 = Bt + (size_t)(nb + r1) * K + q1 * 8;
  u16* lA0 = &As[wid * 512];
  u16* lA1 = &As[2048 + wid * 512];
  u16* lB0 = &Bs[wid * 512];
  u16* lB1 = &Bs[2048 + wid * 512];

  int nK = K >> 5;
  for (int kb = 0; kb < nK; ++kb) {
    __syncthreads();
    int ko = kb * 32;
    gload16(a0 + ko, lA0);
    gload16(a1 + ko, lA1);
    gload16(b0 + ko, lB0);
    gload16(b1 + ko, lB1);
    __syncthreads();
    s16x8 af[4], bfr[4];
#pragma unroll
    for (int m = 0; m < 4; ++m)
      af[m] = *(const s16x8*)&As[(wm * 64 + m * 16 + lm) * 32 + lg * 8];
#pragma unroll
    for (int n = 0; n < 4; ++n)
      bfr[n] = *(const s16x8*)&Bs[(wn * 64 + n * 16 + lm) * 32 + lg * 8];
#pragma unroll
    for (int m = 0; m < 4; ++m)
#pragma unroll
      for (int n = 0; n < 4; ++n)
        acc[m][n] = __builtin_amdgcn_mfma_f32_16x16x32_bf16(af[m], bfr[n],
                                                            acc[m][n], 0, 0, 0);
  }
#pragma unroll
  for (int m = 0; m < 4; ++m) {
#pragma unroll
    for (int n = 0; n < 4; ++n) {
      int col = nb + wn * 64 + n * 16 + lm;
      float bv = HAS_BIAS ? bias[col] : 0.0f;
#pragma unroll
      for (int r = 0; r < 4; ++r) {
        int row = mb + wm * 64 + m * 16 + lg * 4 + r;
        float v = acc[m][n][r] + bv;
        if (HAS_RES) v += Res[(size_t)row * N + col];
        if (RELU) v = v > 0.f ? v : 0.f;
        if (OUT_BF16)
          Cb[(size_t)row * N + col] = f2bf(v);
        else
          Cf[(size_t)row * N + col] = v;
      }
    }
  }
}

// ---------- GEMM 256x256 8-phase (T2+T3+T4+T5) for big-N shapes ----------
// VT=1 (QKV): blocks with nb>=2C write the V projection transposed into Vt.
// LOSS=1 (lm_head): epilogue emits per-(row, 256-col block) softmax stats
// (max, sumexp) into Pp[nblk][row] with one coalesced 2KB write per block.
template <int OUT_BF16, int RELU, int HAS_BIAS, int HAS_RES, int VT, int LOSS>
__global__ __launch_bounds__(512) void k_gemm256(
    const u16* __restrict__ A, const u16* __restrict__ Bt,
    const float* __restrict__ bias, const float* __restrict__ Res,
    float* __restrict__ Cf, u16* __restrict__ Cb, u16* __restrict__ Vtp,
    float2* __restrict__ Pp, int M, int N, int K) {
  __shared__ u16 As[2][16384];
  __shared__ u16 Bs[2][16384];
  const int tid = threadIdx.x;
  const int lane = tid & 63, wid = tid >> 6;
  const int lm = lane & 15, lg = lane >> 4;
  const int wr = wid >> 2, wc = wid & 3;

  unsigned nbx = gridDim.x;
  unsigned nwg = nbx * gridDim.y;
  unsigned orig = blockIdx.y * nbx + blockIdx.x;
  unsigned f = ((nwg & 7u) == 0u) ? (orig & 7u) * (nwg >> 3) + (orig >> 3) : orig;
  const int mb = (int)(f / nbx) * 256, nb = (int)(f % nbx) * 256;

  int aoff[4], boff[4], ldso[4];
#pragma unroll
  for (int h = 0; h < 4; ++h) {
    const int kk = h >> 1, p = h & 1;
    int rem = p * 512 + tid;
    int rblk = rem >> 6;
    int rem2 = rem & 63;
    int row16 = rem2 >> 2, psl = rem2 & 3;
    int sl = psl ^ ((row16 >> 1) & 3);
    int grow = rblk * 16 + row16;
    int gk = kk * 32 + sl * 8;
    aoff[h] = (mb + grow) * K + gk;
    boff[h] = (nb + grow) * K + gk;
    ldso[h] = kk * 8192 + p * 4096 + wid * 512;
  }
  const int lo = lm * 32 + ((lg ^ ((lm >> 1) & 3)) << 3);

  f32x4 acc[8][4];
#pragma unroll
  for (int i = 0; i < 8; ++i)
#pragma unroll
    for (int j = 0; j < 4; ++j) acc[i][j] = f32x4{0.f, 0.f, 0.f, 0.f};

  const int nK = K >> 6;
  gload16(A + aoff[0], &As[0][ldso[0]]);
  gload16(A + aoff[1], &As[0][ldso[1]]);
  gload16(Bt + boff[0], &Bs[0][ldso[0]]);
  gload16(Bt + boff[1], &Bs[0][ldso[1]]);
  gload16(A + aoff[2], &As[0][ldso[2]]);
  gload16(A + aoff[3], &As[0][ldso[3]]);
  gload16(Bt + boff[2], &Bs[0][ldso[2]]);
  gload16(Bt + boff[3], &Bs[0][ldso[3]]);
  asm volatile("s_waitcnt vmcnt(4)" ::: "memory");
  __builtin_amdgcn_s_barrier();

  for (int t = 0; t < nK; ++t) {
    const int buf = t & 1, nbuf = buf ^ 1;
    const bool pre = (t + 1 < nK);
    const int nk64 = (t + 1) * 64;
    s16x8 af[4], bfr[4];
    // P1: kk0 A m0-3 + B; stage Ak0(t+1)
#pragma unroll
    for (int m = 0; m < 4; ++m)
      af[m] = *(const s16x8*)&As[buf][(wr * 8 + m) * 512 + lo];
#pragma unroll
    for (int n = 0; n < 4; ++n)
      bfr[n] = *(const s16x8*)&Bs[buf][(wc * 4 + n) * 512 + lo];
    if (pre) {
      gload16(A + aoff[0] + nk64, &As[nbuf][ldso[0]]);
      gload16(A + aoff[1] + nk64, &As[nbuf][ldso[1]]);
    }
    __builtin_amdgcn_s_barrier();
    __builtin_amdgcn_s_setprio(1);
#pragma unroll
    for (int m = 0; m < 4; ++m)
#pragma unroll
      for (int n = 0; n < 4; ++n)
        acc[m][n] = __builtin_amdgcn_mfma_f32_16x16x32_bf16(af[m], bfr[n],
                                                            acc[m][n], 0, 0, 0);
    __builtin_amdgcn_s_setprio(0);
    __builtin_amdgcn_s_barrier();
    // P2: kk0 A m4-7; stage Bk0(t+1)
#pragma unroll
    for (int m = 0; m < 4; ++m)
      af[m] = *(const s16x8*)&As[buf][(wr * 8 + 4 + m) * 512 + lo];
    if (pre) {
      gload16(Bt + boff[0] + nk64, &Bs[nbuf][ldso[0]]);
      gload16(Bt + boff[1] + nk64, &Bs[nbuf][ldso[1]]);
    }
    __builtin_amdgcn_s_barrier();
    __builtin_amdgcn_s_setprio(1);
#pragma unroll
    for (int m = 0; m < 4; ++m)
#pragma unroll
      for (int n = 0; n < 4; ++n)
        acc[m + 4][n] = __builtin_amdgcn_mfma_f32_16x16x32_bf16(
            af[m], bfr[n], acc[m + 4][n], 0, 0, 0);
    __builtin_amdgcn_s_setprio(0);
    __builtin_amdgcn_s_barrier();
    // P3: kk1 A m0-3 + B; stage Ak1(t+1); gate kk1(t)
#pragma unroll
    for (int m = 0; m < 4; ++m)
      af[m] = *(const s16x8*)&As[buf][8192 + (wr * 8 + m) * 512 + lo];
#pragma unroll
    for (int n = 0; n < 4; ++n)
      bfr[n] = *(const s16x8*)&Bs[buf][8192 + (wc * 4 + n) * 512 + lo];
    if (pre) {
      gload16(A + aoff[2] + nk64, &As[nbuf][ldso[2]]);
      gload16(A + aoff[3] + nk64, &As[nbuf][ldso[3]]);
      asm volatile("s_waitcnt vmcnt(6)" ::: "memory");
    } else {
      asm volatile("s_waitcnt vmcnt(0)" ::: "memory");
    }
    __builtin_amdgcn_s_barrier();
    __builtin_amdgcn_s_setprio(1);
#pragma unroll
    for (int m = 0; m < 4; ++m)
#pragma unroll
      for (int n = 0; n < 4; ++n)
        acc[m][n] = __builtin_amdgcn_mfma_f32_16x16x32_bf16(af[m], bfr[n],
                                                            acc[m][n], 0, 0, 0);
    __builtin_amdgcn_s_setprio(0);
    __builtin_amdgcn_s_barrier();
    // P4: kk1 A m4-7; stage Bk1(t+1); gate kk0(t+1)
#pragma unroll
    for (int m = 0; m < 4; ++m)
      af[m] = *(const s16x8*)&As[buf][8192 + (wr * 8 + 4 + m) * 512 + lo];
    if (pre) {
      gload16(Bt + boff[2] + nk64, &Bs[nbuf][ldso[2]]);
      gload16(Bt + boff[3] + nk64, &Bs[nbuf][ldso[3]]);
      asm volatile("s_waitcnt vmcnt(4)" ::: "memory");
    }
    __builtin_amdgcn_s_barrier();
    __builtin_amdgcn_s_setprio(1);
#pragma unroll
    for (int m = 0; m < 4; ++m)
#pragma unroll
      for (int n = 0; n < 4; ++n)
        acc[m + 4][n] = __builtin_amdgcn_mfma_f32_16x16x32_bf16(
            af[m], bfr[n], acc[m + 4][n], 0, 0, 0);
    __builtin_amdgcn_s_setprio(0);
    __builtin_amdgcn_s_barrier();
  }
  // ---- epilogue ----
  if (VT && nb >= 2 * C) {
    int hh = ((nb - 2 * C) >> 6) + wc;  // head index (uniform per wave)
#pragma unroll
    for (int m = 0; m < 8; ++m) {
      int t0 = mb + wr * 128 + m * 16 + lg * 4;
      int bb = t0 >> 10, tt = t0 & (T - 1);
      size_t vbase = ((size_t)(bb * H + hh) * HS) * T + tt;
#pragma unroll
      for (int n = 0; n < 4; ++n) {
        int d = n * 16 + lm;
        s16x4 pk;
#pragma unroll
        for (int r = 0; r < 4; ++r) pk[r] = (short)f2bf(acc[m][n][r]);
        *(s16x4*)&Vtp[vbase + (size_t)d * T] = pk;
      }
    }
    return;
  }
  float bv[4];
#pragma unroll
  for (int n = 0; n < 4; ++n)
    bv[n] = HAS_BIAS ? bias[nb + wc * 64 + n * 16 + lm] : 0.0f;
#pragma unroll
  for (int m = 0; m < 8; ++m) {
#pragma unroll
    for (int r = 0; r < 4; ++r) {
      int row = mb + wr * 128 + m * 16 + lg * 4 + r;
#pragma unroll
      for (int n = 0; n < 4; ++n) {
        int col = nb + wc * 64 + n * 16 + lm;
        float v = acc[m][n][r] + bv[n];
        if (HAS_RES) v += Res[(size_t)row * N + col];
        if (RELU) v = v > 0.f ? v : 0.f;
        if (OUT_BF16)
          Cb[(size_t)row * N + col] = f2bf(v);
        else
          Cf[(size_t)row * N + col] = v;
      }
    }
  }
  if (LOSS) {
    // per-row (max, sumexp) over this block's 256 cols -> Pp[nblk][row]
    __syncthreads();
    float* redM = (float*)&As[0][0];   // 256 rows x 4 waves
    float* redS = redM + 1024;
    float Mx[8][4];
#pragma unroll
    for (int m = 0; m < 8; ++m)
#pragma unroll
      for (int r = 0; r < 4; ++r) {
        float v0 = acc[m][0][r] + bv[0];
        float v1 = acc[m][1][r] + bv[1];
        float v2 = acc[m][2][r] + bv[2];
        float v3 = acc[m][3][r] + bv[3];
        Mx[m][r] = fmaxf(fmaxf(v0, v1), fmaxf(v2, v3));
      }
#pragma unroll
    for (int d = 1; d < 16; d <<= 1)
#pragma unroll
      for (int m = 0; m < 8; ++m)
#pragma unroll
        for (int r = 0; r < 4; ++r)
          Mx[m][r] = fmaxf(Mx[m][r], __shfl_xor(Mx[m][r], d, 16));
    if (lm == 0) {
#pragma unroll
      for (int m = 0; m < 8; ++m)
#pragma unroll
        for (int r = 0; r < 4; ++r)
          redM[(wr * 128 + m * 16 + lg * 4 + r) * 4 + wc] = Mx[m][r];
    }
    __syncthreads();
    float Sx[8][4];
#pragma unroll
    for (int m = 0; m < 8; ++m)
#pragma unroll
      for (int r = 0; r < 4; ++r) {
        int rl = wr * 128 + m * 16 + lg * 4 + r;
        float mm = fmaxf(fmaxf(redM[rl * 4 + 0], redM[rl * 4 + 1]),
                         fmaxf(redM[rl * 4 + 2], redM[rl * 4 + 3]));
        Sx[m][r] = __expf(acc[m][0][r] + bv[0] - mm) +
                   __expf(acc[m][1][r] + bv[1] - mm) +
                   __expf(acc[m][2][r] + bv[2] - mm) +
                   __expf(acc[m][3][r] + bv[3] - mm);
      }
#pragma unroll
    for (int d = 1; d < 16; d <<= 1)
#pragma unroll
      for (int m = 0; m < 8; ++m)
#pragma unroll
        for (int r = 0; r < 4; ++r)
          Sx[m][r] += __shfl_xor(Sx[m][r], d, 16);
    if (lm == 0) {
#pragma unroll
      for (int m = 0; m < 8; ++m)
#pragma unroll
        for (int r = 0; r < 4; ++r)
          redS[(wr * 128 + m * 16 + lg * 4 + r) * 4 + wc] = Sx[m][r];
    }
    __syncthreads();
    if (tid < 256) {
      float mrow = fmaxf(fmaxf(redM[tid * 4 + 0], redM[tid * 4 + 1]),
                         fmaxf(redM[tid * 4 + 2], redM[tid * 4 + 3]));
      float srow = redS[tid * 4 + 0] + redS[tid * 4 + 1] + redS[tid * 4 + 2] +
                   redS[tid * 4 + 3];
      Pp[(size_t)(nb >> 8) * M + mb + tid] = float2{mrow, srow};
    }
  }
}

// ---------- flash attention v5: paired q-tiles + double-buffered staging ----
// QBLK=64, blocks process q-tile pair {p, 15-p} (uniform 17 units). K/V tiles
// double-buffered in LDS; stage kt+1 during compute of kt; counted vmcnt(4)
// + raw s_barrier (no __syncthreads: it would drain vmcnt and kill prefetch).
__global__ __launch_bounds__(256) void k_attn(
    const u16* __restrict__ qkv, const u16* __restrict__ vt,
    u16* __restrict__ o) {
  constexpr int PP = 72;
  __shared__ u16 Ks[2][64 * 64];
  __shared__ u16 Vs[2][64 * 64];
  __shared__ u16 Ps[4][16 * PP];
  int bid = blockIdx.x;  // p | h | b
  int p = bid & 7, h = (bid >> 3) & 15, b = bid >> 7;
  int tid = threadIdx.x, lane = tid & 63, wid = tid >> 6;
  int lm = lane & 15, lg = lane >> 4;
  const size_t rowbase = (size_t)b * T * C3 + (size_t)h * HS;
  const u16* kbase = qkv + rowbase + C;
  const u16* vbase = vt + (size_t)(b * H + h) * HS * T;
  const size_t obase = (size_t)b * T * C + (size_t)h * HS;
  const float scale = 0.125f;
  const int sr = tid >> 3, scs = (tid & 7) ^ (sr & 7);
  const int swz0 = (lg ^ (lm & 7)) * 8;
  const int swz1 = ((4 + lg) ^ (lm & 7)) * 8;

  for (int qi = 0; qi < 2; ++qi) {
    int qt = qi ? (15 - p) : p;
    int qw = qt * 64 + wid * 16;
    s16x8 qf[2];
#pragma unroll
    for (int s = 0; s < 2; ++s)
      qf[s] = *(const s16x8*)&qkv[rowbase + (size_t)(qw + lm) * C3 + s * 32 +
                                  lg * 8];
    float m_[4], l_[4];
    f32x4 oacc[4];
#pragma unroll
    for (int r = 0; r < 4; ++r) { m_[r] = -3e38f; l_[r] = 0.f; }
#pragma unroll
    for (int n = 0; n < 4; ++n) oacc[n] = f32x4{0.f, 0.f, 0.f, 0.f};

    // prologue: stage tile 0 into buffer 0
    gload16(kbase + (size_t)sr * C3 + scs * 8, &Ks[0][wid * 512]);
    gload16(kbase + (size_t)(sr + 32) * C3 + scs * 8, &Ks[0][2048 + wid * 512]);
    gload16(vbase + (size_t)sr * T + scs * 8, &Vs[0][wid * 512]);
    gload16(vbase + (size_t)(sr + 32) * T + scs * 8, &Vs[0][2048 + wid * 512]);

    for (int kt = 0; kt <= qt; ++kt) {
      int buf = kt & 1;
      bool pre = kt < qt;
      if (pre) {  // stage kt+1 into the other buffer
        int nk = (kt + 1) * 64;
        int nbuf = buf ^ 1;
        gload16(kbase + (size_t)(nk + sr) * C3 + scs * 8, &Ks[nbuf][wid * 512]);
        gload16(kbase + (size_t)(nk + sr + 32) * C3 + scs * 8,
                &Ks[nbuf][2048 + wid * 512]);
        gload16(vbase + (size_t)sr * T + nk + scs * 8, &Vs[nbuf][wid * 512]);
        gload16(vbase + (size_t)(sr + 32) * T + nk + scs * 8,
                &Vs[nbuf][2048 + wid * 512]);
        asm volatile("s_waitcnt vmcnt(4)" ::: "memory");
      } else {
        asm volatile("s_waitcnt vmcnt(0)" ::: "memory");
      }
      __builtin_amdgcn_s_barrier();

      f32x4 s[4];
#pragma unroll
      for (int ch = 0; ch < 4; ++ch) {
        s16x8 k0 = *(const s16x8*)&Ks[buf][(ch * 16 + lm) * 64 + swz0];
        s16x8 k1 = *(const s16x8*)&Ks[buf][(ch * 16 + lm) * 64 + swz1];
        s[ch] = f32x4{0.f, 0.f, 0.f, 0.f};
        s[ch] = __builtin_amdgcn_mfma_f32_16x16x32_bf16(qf[0], k0, s[ch], 0, 0, 0);
        s[ch] = __builtin_amdgcn_mfma_f32_16x16x32_bf16(qf[1], k1, s[ch], 0, 0, 0);
      }
      if (kt == qt) {  // diagonal tile: mask
#pragma unroll
        for (int ch = 0; ch < 4; ++ch) {
          int col = kt * 64 + ch * 16 + lm;
#pragma unroll
          for (int r = 0; r < 4; ++r) {
            int row = qw + lg * 4 + r;
            s[ch][r] = (col <= row) ? s[ch][r] * scale : -3e38f;
          }
        }
      } else {
#pragma unroll
        for (int ch = 0; ch < 4; ++ch)
#pragma unroll
          for (int r = 0; r < 4; ++r) s[ch][r] *= scale;
      }
      float rmax[4];
#pragma unroll
      for (int r = 0; r < 4; ++r)
        rmax[r] = fmaxf(fmaxf(s[0][r], s[1][r]), fmaxf(s[2][r], s[3][r]));
#pragma unroll
      for (int mm = 1; mm < 16; mm <<= 1)
#pragma unroll
        for (int r = 0; r < 4; ++r)
          rmax[r] = fmaxf(rmax[r], __shfl_xor(rmax[r], mm, 16));
      float alpha[4], rsum[4];
#pragma unroll
      for (int r = 0; r < 4; ++r) {
        float mn = fmaxf(m_[r], rmax[r]);
        alpha[r] = __expf(m_[r] - mn);
        m_[r] = mn;
        rsum[r] = 0.f;
      }
#pragma unroll
      for (int ch = 0; ch < 4; ++ch)
#pragma unroll
        for (int r = 0; r < 4; ++r) {
          float e = __expf(s[ch][r] - m_[r]);
          s[ch][r] = e;
          rsum[r] += e;
        }
#pragma unroll
      for (int mm = 1; mm < 16; mm <<= 1)
#pragma unroll
        for (int r = 0; r < 4; ++r) rsum[r] += __shfl_xor(rsum[r], mm, 16);
#pragma unroll
      for (int r = 0; r < 4; ++r) l_[r] = l_[r] * alpha[r] + rsum[r];
#pragma unroll
      for (int n = 0; n < 4; ++n)
#pragma unroll
        for (int r = 0; r < 4; ++r) oacc[n][r] *= alpha[r];
#pragma unroll
      for (int r = 0; r < 4; ++r) {
        int pr = lg * 4 + r;
#pragma unroll
        for (int ch = 0; ch < 4; ++ch)
          Ps[wid][pr * PP + ch * 16 + lm] = f2bf(s[ch][r]);
      }
      s16x8 pa0 = *(const s16x8*)&Ps[wid][lm * PP + lg * 8];
      s16x8 pa1 = *(const s16x8*)&Ps[wid][lm * PP + 32 + lg * 8];
#pragma unroll
      for (int n = 0; n < 4; ++n) {
        s16x8 v0 = *(const s16x8*)&Vs[buf][(n * 16 + lm) * 64 + swz0];
        s16x8 v1 = *(const s16x8*)&Vs[buf][(n * 16 + lm) * 64 + swz1];
        oacc[n] =
            __builtin_amdgcn_mfma_f32_16x16x32_bf16(pa0, v0, oacc[n], 0, 0, 0);
        oacc[n] =
            __builtin_amdgcn_mfma_f32_16x16x32_bf16(pa1, v1, oacc[n], 0, 0, 0);
      }
      __builtin_amdgcn_s_barrier();  // all reads of buf done before overwrite
    }
    float inv[4];
#pragma unroll
    for (int r = 0; r < 4; ++r) inv[r] = 1.0f / l_[r];
#pragma unroll
    for (int n = 0; n < 4; ++n)
#pragma unroll
      for (int r = 0; r < 4; ++r)
        o[obase + (size_t)(qw + lg * 4 + r) * C + n * 16 + lm] =
            f2bf(oacc[n][r] * inv[r]);
  }
}

// ---------- LayerNorm (vectorized: one float4 per thread) ----------
__global__ __launch_bounds__(256) void k_ln(
    const float* __restrict__ in, const float* __restrict__ g,
    const float* __restrict__ bsh, float* __restrict__ xout,
    u16* __restrict__ xbout) {
  int row = blockIdx.x;
  int tid = threadIdx.x;
  f32x4 v = ((const f32x4*)(in + (size_t)row * C))[tid];
  float s = v[0] + v[1] + v[2] + v[3];
  s = blockReduceSum(s);
  float mean = s * (1.0f / C);
  float s2 = 0.f;
#pragma unroll
  for (int j = 0; j < 4; ++j) {
    float d = v[j] - mean;
    s2 += d * d;
  }
  s2 = blockReduceSum(s2);
  float rstd = rsqrtf(s2 * (1.0f / C) + 1e-5f);
  f32x4 gv = ((const f32x4*)g)[tid];
  f32x4 bv = ((const f32x4*)bsh)[tid];
  f32x4 y;
  s16x4 yb;
#pragma unroll
  for (int j = 0; j < 4; ++j) {
    y[j] = (v[j] - mean) * rstd * gv[j] + bv[j];
    yb[j] = (short)f2bf(y[j]);
  }
  ((f32x4*)(xout + (size_t)row * C))[tid] = y;
  ((s16x4*)(xbout + (size_t)row * C))[tid] = yb;
}

// ---------- loss: merge per-block stats + target logit ----------
__global__ __launch_bounds__(128) void k_rowloss2(
    const float2* __restrict__ pairs, const float* __restrict__ logits,
    const int* __restrict__ tgt, float* __restrict__ rowloss) {
  int row = blockIdx.x;
  int tid = threadIdx.x;
  float m = -3e38f, s = 0.f;
  if (tid < 125) {
    float2 pv = pairs[(size_t)tid * BT + row];
    m = pv.x;
    s = pv.y;
  }
#pragma unroll
  for (int d = 1; d < 64; d <<= 1) {
    float mo = __shfl_xor(m, d, 64), so = __shfl_xor(s, d, 64);
    float mn = fmaxf(m, mo);
    s = s * __expf(m - mn) + so * __expf(mo - mn);
    m = mn;
  }
  __shared__ float sm[2], ss[2];
  if ((tid & 63) == 0) { sm[tid >> 6] = m; ss[tid >> 6] = s; }
  __syncthreads();
  if (tid == 0) {
    float M = fmaxf(sm[0], sm[1]);
    float S = ss[0] * __expf(sm[0] - M) + ss[1] * __expf(sm[1] - M);
    rowloss[row] = (M + logf(S)) - logits[(size_t)row * V + tgt[row]];
  }
}

__global__ __launch_bounds__(256) void k_lossreduce(
    const float* __restrict__ rowloss, float* __restrict__ out) {
  __shared__ float red[256];
  int tid = threadIdx.x;
  float s = 0.f;
  for (int i = tid; i < BT; i += 256) s += rowloss[i];
  red[tid] = s;
  __syncthreads();
  for (int m = 128; m >= 1; m >>= 1) {
    if (tid < m) red[tid] += red[tid + m];
    __syncthreads();
  }
  if (tid == 0) out[0] = red[0] * (1.0f / BT);
}

// ---------------- host orchestration ----------------
extern "C" void kernel_launch(void* const* d_in, const int* in_sizes, int n_in,
                              void* d_out, int out_size, void* d_ws,
                              size_t ws_size, hipStream_t stream) {
  (void)in_sizes; (void)n_in; (void)out_size; (void)ws_size;
  const int* index = (const int*)d_in[0];
  const int* targets = (const int*)d_in[1];
  const float* tok_emb = (const float*)d_in[2];
  const float* pos_emb = (const float*)d_in[3];
  const float* wq = (const float*)d_in[4];
  const float* wk = (const float*)d_in[5];
  const float* wv = (const float*)d_in[6];
  const float* wo = (const float*)d_in[7];
  const float* bo = (const float*)d_in[8];
  const float* w1 = (const float*)d_in[9];
  const float* b1 = (const float*)d_in[10];
  const float* w2 = (const float*)d_in[11];
  const float* b2 = (const float*)d_in[12];
  const float* ln1_g = (const float*)d_in[13];
  const float* ln1_b = (const float*)d_in[14];
  const float* ln2_g = (const float*)d_in[15];
  const float* ln2_b = (const float*)d_in[16];
  const float* lnf_g = (const float*)d_in[17];
  const float* lnf_b = (const float*)d_in[18];
  const float* lm_w = (const float*)d_in[19];
  const float* lm_b = (const float*)d_in[20];

  float* logits = (float*)d_out;
  float* loss = logits + (size_t)BT * V;

  size_t off = 0;
  auto alloc = [&](size_t bytes) -> void* {
    off = (off + 255) & ~(size_t)255;
    void* p = (void*)((char*)d_ws + off);
    off += bytes;
    return p;
  };
  u16* wqkv_t = (u16*)alloc((size_t)L * C3 * C * 2);  // [L][3C][C]
  u16* wo_t = (u16*)alloc((size_t)L * C * C * 2);
  u16* w1_t = (u16*)alloc((size_t)L * C * C4 * 2);
  u16* w2_t = (u16*)alloc((size_t)L * C4 * C * 2);
  u16* lmw_t = (u16*)alloc((size_t)V * C * 2);
  float* x = (float*)alloc((size_t)BT * C * 4);
  float* tmp = (float*)alloc((size_t)BT * C * 4);
  u16* xb = (u16*)alloc((size_t)BT * C * 2);
  u16* qkvb = (u16*)alloc((size_t)BT * C3 * 2);
  u16* vtb = (u16*)alloc((size_t)BT * C * 2);   // V transposed per (b,h)
  u16* attb = (u16*)alloc((size_t)BT * C * 2);
  u16* hb = (u16*)alloc((size_t)BT * C4 * 2);
  float* rowloss = (float*)alloc((size_t)BT * 4);
  float2* pairs = (float2*)alloc((size_t)BT * 128 * 8);

  dim3 blk(256);
  dim3 blk5(512);
  k_transpose<<<dim3(C / 64, C / 64, L), blk, 0, stream>>>(
      wq, wqkv_t, C, C, (size_t)C * C, (size_t)C3 * C);
  k_transpose<<<dim3(C / 64, C / 64, L), blk, 0, stream>>>(
      wk, wqkv_t + (size_t)C * C, C, C, (size_t)C * C, (size_t)C3 * C);
  k_transpose<<<dim3(C / 64, C / 64, L), blk, 0, stream>>>(
      wv, wqkv_t + (size_t)2 * C * C, C, C, (size_t)C * C, (size_t)C3 * C);
  k_transpose<<<dim3(C / 64, C / 64, L), blk, 0, stream>>>(
      wo, wo_t, C, C, (size_t)C * C, (size_t)C * C);
  k_transpose<<<dim3(C4 / 64, C / 64, L), blk, 0, stream>>>(
      w1, w1_t, C, C4, (size_t)C * C4, (size_t)C * C4);
  k_transpose<<<dim3(C / 64, C4 / 64, L), blk, 0, stream>>>(
      w2, w2_t, C4, C, (size_t)C4 * C, (size_t)C4 * C);
  k_transpose<<<dim3(V / 64, C / 64, 1), blk, 0, stream>>>(
      lm_w, lmw_t, C, V, 0, 0);

  k_embed<<<BT, blk, 0, stream>>>(index, tok_emb, pos_emb, x, xb);

  dim3 gQKV(C3 / 256, BT / 256);   // 12 x 16 = 192 wg (256^2)
  dim3 gCC(C / 128, BT / 128);     // 256 wg (128^2)
  dim3 gC4(C4 / 256, BT / 256);    // 256 wg (256^2)
  for (int l = 0; l < L; ++l) {
    const u16* wqkvt = wqkv_t + (size_t)l * C3 * C;
    const u16* wot = wo_t + (size_t)l * C * C;
    const u16* w1t = w1_t + (size_t)l * C * C4;
    const u16* w2t = w2_t + (size_t)l * C4 * C;

    k_gemm256<1, 0, 0, 0, 1, 0><<<gQKV, blk5, 0, stream>>>(
        xb, wqkvt, nullptr, nullptr, nullptr, qkvb, vtb, nullptr, BT, C3, C);
    k_attn<<<B * H * 8, blk, 0, stream>>>(qkvb, vtb, attb);
    k_gemm<0, 0, 1, 1><<<gCC, blk, 0, stream>>>(
        attb, wot, bo + (size_t)l * C, x, tmp, nullptr, BT, C, C);
    k_ln<<<BT, blk, 0, stream>>>(tmp, ln1_g + (size_t)l * C,
                                 ln1_b + (size_t)l * C, x, xb);
    k_gemm256<1, 1, 1, 0, 0, 0><<<gC4, blk5, 0, stream>>>(
        xb, w1t, b1 + (size_t)l * C4, nullptr, nullptr, hb, nullptr, nullptr,
        BT, C4, C);
    k_gemm<0, 0, 1, 1><<<gCC, blk, 0, stream>>>(
        hb, w2t, b2 + (size_t)l * C, x, tmp, nullptr, BT, C, C4);
    k_ln<<<BT, blk, 0, stream>>>(tmp, ln2_g + (size_t)l * C,
                                 ln2_b + (size_t)l * C, x, xb);
  }
  k_ln<<<BT, blk, 0, stream>>>(x, lnf_g, lnf_b, x, xb);
  k_gemm256<0, 0, 1, 0, 0, 1><<<dim3(V / 256, BT / 256), blk5, 0, stream>>>(
      xb, lmw_t, lm_b, nullptr, logits, nullptr, nullptr, pairs, BT, V, C);
  k_rowloss2<<<BT, dim3(128), 0, stream>>>(pairs, logits, targets, rowloss);
  k_lossreduce<<<1, blk, 0, stream>>>(rowloss, loss);
}

// Round 9
// 2662.498 us; speedup vs baseline: 1.3318x; 1.0066x over previous
//
#include <hip/hip_runtime.h>

typedef unsigned short u16;
typedef __attribute__((ext_vector_type(4))) float f32x4;
typedef __attribute__((ext_vector_type(8))) short s16x8;
typedef __attribute__((ext_vector_type(4))) short s16x4;

static constexpr int V = 32000;
static constexpr int C = 1024;
static constexpr int T = 1024;
static constexpr int H = 16;
static constexpr int L = 8;
static constexpr int B = 4;
static constexpr int HS = 64;
static constexpr int BT = B * T;   // 4096
static constexpr int C4 = 4 * C;   // 4096
static constexpr int C3 = 3 * C;   // 3072

__device__ __forceinline__ u16 f2bf(float f) {
  union { float f; unsigned u; } v; v.f = f;
  unsigned r = v.u + 0x7fffu + ((v.u >> 16) & 1u);
  return (u16)(r >> 16);
}

__device__ __forceinline__ void gload16(const u16* g, u16* l) {
  __builtin_amdgcn_global_load_lds(
      (const __attribute__((address_space(1))) void*)g,
      (__attribute__((address_space(3))) void*)l, 16, 0, 0);
}

// ---------- block reduction (256 threads) ----------
__device__ __forceinline__ float blockReduceSum(float v) {
  __shared__ float red[4];
  int lane = threadIdx.x & 63, w = threadIdx.x >> 6;
#pragma unroll
  for (int m = 32; m >= 1; m >>= 1) v += __shfl_xor(v, m, 64);
  if (lane == 0) red[w] = v;
  __syncthreads();
  float r = red[0] + red[1] + red[2] + red[3];
  __syncthreads();
  return r;
}

// ---------- embed (vectorized: one float4 per thread) ----------
__global__ __launch_bounds__(256) void k_embed(
    const int* __restrict__ idx, const float* __restrict__ tok,
    const float* __restrict__ pos, float* __restrict__ x, u16* __restrict__ xb) {
  int bt = blockIdx.x;
  int t = bt & (T - 1);
  int row = idx[bt];
  int tid = threadIdx.x;
  f32x4 tv = ((const f32x4*)(tok + (size_t)row * C))[tid];
  f32x4 pv = ((const f32x4*)(pos + (size_t)t * C))[tid];
  f32x4 y;
  s16x4 yb;
#pragma unroll
  for (int j = 0; j < 4; ++j) {
    y[j] = tv[j] + pv[j];
    yb[j] = (short)f2bf(y[j]);
  }
  ((f32x4*)(x + (size_t)bt * C))[tid] = y;
  ((s16x4*)(xb + (size_t)bt * C))[tid] = yb;
}

// ---------- weight convert+transpose: fp32 [K,N] -> bf16 [N,K] ----------
__global__ __launch_bounds__(256) void k_transpose(
    const float* __restrict__ W, u16* __restrict__ Wt, int K, int N,
    size_t sW, size_t sWt) {
  __shared__ float tile[64][65];
  const float* Wz = W + sW * blockIdx.z;
  u16* Wtz = Wt + sWt * blockIdx.z;
  int n0 = blockIdx.x * 64, k0 = blockIdx.y * 64;
  int tc = threadIdx.x & 63, tr = threadIdx.x >> 6;
#pragma unroll
  for (int i = 0; i < 16; ++i) {
    int r = tr + i * 4;
    tile[r][tc] = Wz[(size_t)(k0 + r) * N + (n0 + tc)];
  }
  __syncthreads();
#pragma unroll
  for (int i = 0; i < 16; ++i) {
    int r = tr + i * 4;  // n-offset within tile
    Wtz[(size_t)(n0 + r) * K + (k0 + tc)] = f2bf(tile[tc][r]);
  }
}

// ---------- GEMM 128x128 (m97 structure) for small-N shapes ----------
template <int OUT_BF16, int RELU, int HAS_BIAS, int HAS_RES>
__global__ __launch_bounds__(256, 2) void k_gemm(
    const u16* __restrict__ A, const u16* __restrict__ Bt,
    const float* __restrict__ bias, const float* __restrict__ Res,
    float* __restrict__ Cf, u16* __restrict__ Cb, int M, int N, int K) {
  __shared__ u16 As[128 * 32];
  __shared__ u16 Bs[128 * 32];
  int tid = threadIdx.x;
  int lane = tid & 63, wid = tid >> 6;
  int lm = lane & 15, lg = lane >> 4;
  int wm = wid >> 1, wn = wid & 1;

  unsigned nbx = gridDim.x;
  unsigned nwg = nbx * gridDim.y;
  unsigned orig = blockIdx.y * nbx + blockIdx.x;
  unsigned f = ((nwg & 7u) == 0u) ? (orig & 7u) * (nwg >> 3) + (orig >> 3) : orig;
  int mb = (int)(f / nbx) * 128, nb = (int)(f % nbx) * 128;

  f32x4 acc[4][4];
#pragma unroll
  for (int i = 0; i < 4; ++i)
#pragma unroll
    for (int j = 0; j < 4; ++j) acc[i][j] = f32x4{0.f, 0.f, 0.f, 0.f};

  int r0 = tid >> 2, q0 = tid & 3;
  int r1 = (256 + tid) >> 2, q1 = tid & 3;
  const u16* a0 = A + (size_t)(mb + r0) * K + q0 * 8;
  const u16* a1 = A + (size_t)(mb + r1) * K + q1 * 8;
  const u16* b0 = Bt + (size_t)(nb + r0) * K + q0 * 8;
  const u16* b1 = Bt + (size_t)(nb + r1) * K + q1 * 8;
  u16* lA0 = &As[wid * 512];
  u16* lA1 = &As[2048 + wid * 512];
  u16* lB0 = &Bs[wid * 512];
  u16* lB1 = &Bs[2048 + wid * 512];

  int nK = K >> 5;
  for (int kb = 0; kb < nK; ++kb) {
    __syncthreads();
    int ko = kb * 32;
    gload16(a0 + ko, lA0);
    gload16(a1 + ko, lA1);
    gload16(b0 + ko, lB0);
    gload16(b1 + ko, lB1);
    __syncthreads();
    s16x8 af[4], bfr[4];
#pragma unroll
    for (int m = 0; m < 4; ++m)
      af[m] = *(const s16x8*)&As[(wm * 64 + m * 16 + lm) * 32 + lg * 8];
#pragma unroll
    for (int n = 0; n < 4; ++n)
      bfr[n] = *(const s16x8*)&Bs[(wn * 64 + n * 16 + lm) * 32 + lg * 8];
#pragma unroll
    for (int m = 0; m < 4; ++m)
#pragma unroll
      for (int n = 0; n < 4; ++n)
        acc[m][n] = __builtin_amdgcn_mfma_f32_16x16x32_bf16(af[m], bfr[n],
                                                            acc[m][n], 0, 0, 0);
  }
#pragma unroll
  for (int m = 0; m < 4; ++m) {
#pragma unroll
    for (int n = 0; n < 4; ++n) {
      int col = nb + wn * 64 + n * 16 + lm;
      float bv = HAS_BIAS ? bias[col] : 0.0f;
#pragma unroll
      for (int r = 0; r < 4; ++r) {
        int row = mb + wm * 64 + m * 16 + lg * 4 + r;
        float v = acc[m][n][r] + bv;
        if (HAS_RES) v += Res[(size_t)row * N + col];
        if (RELU) v = v > 0.f ? v : 0.f;
        if (OUT_BF16)
          Cb[(size_t)row * N + col] = f2bf(v);
        else
          Cf[(size_t)row * N + col] = v;
      }
    }
  }
}

// ---------- GEMM 256x256 8-phase (T2+T3+T4+T5) for big-N shapes ----------
// VT=1 (QKV): blocks with nb>=2C write the V projection transposed into Vt.
// LOSS=1 (lm_head): epilogue emits per-(row, 256-col block) sum-of-exp
// (max-free: logits are O(1), fp32 exp headroom is e^88) into Pp[nblk][row].
// XN=1: XCD swizzle partitions by N (each XCD owns an nb-slice, mb-major
// within it) -> W panel traffic /8 for W >> A shapes (lm_head).
template <int OUT_BF16, int RELU, int HAS_BIAS, int HAS_RES, int VT, int LOSS,
          int XN>
__global__ __launch_bounds__(512) void k_gemm256(
    const u16* __restrict__ A, const u16* __restrict__ Bt,
    const float* __restrict__ bias, const float* __restrict__ Res,
    float* __restrict__ Cf, u16* __restrict__ Cb, u16* __restrict__ Vtp,
    float* __restrict__ Pp, int M, int N, int K) {
  __shared__ u16 As[2][16384];
  __shared__ u16 Bs[2][16384];
  const int tid = threadIdx.x;
  const int lane = tid & 63, wid = tid >> 6;
  const int lm = lane & 15, lg = lane >> 4;
  const int wr = wid >> 2, wc = wid & 3;

  unsigned nbx = gridDim.x;
  unsigned nwg = nbx * gridDim.y;
  unsigned orig = blockIdx.y * nbx + blockIdx.x;
  int mb, nb;
  if (XN) {
    // N-partition: xcd owns a contiguous nb-slice, mb-major within it
    unsigned xcd = orig & 7u, idx = orig >> 3;
    unsigned g = xcd * (nwg >> 3) + idx;
    unsigned My = gridDim.y;  // M-tile count
    mb = (int)(g % My) * 256;
    nb = (int)(g / My) * 256;
  } else {
    unsigned f =
        ((nwg & 7u) == 0u) ? (orig & 7u) * (nwg >> 3) + (orig >> 3) : orig;
    mb = (int)(f / nbx) * 256;
    nb = (int)(f % nbx) * 256;
  }

  int aoff[4], boff[4], ldso[4];
#pragma unroll
  for (int h = 0; h < 4; ++h) {
    const int kk = h >> 1, p = h & 1;
    int rem = p * 512 + tid;
    int rblk = rem >> 6;
    int rem2 = rem & 63;
    int row16 = rem2 >> 2, psl = rem2 & 3;
    int sl = psl ^ ((row16 >> 1) & 3);
    int grow = rblk * 16 + row16;
    int gk = kk * 32 + sl * 8;
    aoff[h] = (mb + grow) * K + gk;
    boff[h] = (nb + grow) * K + gk;
    ldso[h] = kk * 8192 + p * 4096 + wid * 512;
  }
  const int lo = lm * 32 + ((lg ^ ((lm >> 1) & 3)) << 3);

  f32x4 acc[8][4];
#pragma unroll
  for (int i = 0; i < 8; ++i)
#pragma unroll
    for (int j = 0; j < 4; ++j) acc[i][j] = f32x4{0.f, 0.f, 0.f, 0.f};

  const int nK = K >> 6;
  gload16(A + aoff[0], &As[0][ldso[0]]);
  gload16(A + aoff[1], &As[0][ldso[1]]);
  gload16(Bt + boff[0], &Bs[0][ldso[0]]);
  gload16(Bt + boff[1], &Bs[0][ldso[1]]);
  gload16(A + aoff[2], &As[0][ldso[2]]);
  gload16(A + aoff[3], &As[0][ldso[3]]);
  gload16(Bt + boff[2], &Bs[0][ldso[2]]);
  gload16(Bt + boff[3], &Bs[0][ldso[3]]);
  asm volatile("s_waitcnt vmcnt(4)" ::: "memory");
  __builtin_amdgcn_s_barrier();

  for (int t = 0; t < nK; ++t) {
    const int buf = t & 1, nbuf = buf ^ 1;
    const bool pre = (t + 1 < nK);
    const int nk64 = (t + 1) * 64;
    s16x8 af[4], bfr[4];
    // P1: kk0 A m0-3 + B; stage Ak0(t+1)
#pragma unroll
    for (int m = 0; m < 4; ++m)
      af[m] = *(const s16x8*)&As[buf][(wr * 8 + m) * 512 + lo];
#pragma unroll
    for (int n = 0; n < 4; ++n)
      bfr[n] = *(const s16x8*)&Bs[buf][(wc * 4 + n) * 512 + lo];
    if (pre) {
      gload16(A + aoff[0] + nk64, &As[nbuf][ldso[0]]);
      gload16(A + aoff[1] + nk64, &As[nbuf][ldso[1]]);
    }
    __builtin_amdgcn_s_barrier();
    __builtin_amdgcn_s_setprio(1);
#pragma unroll
    for (int m = 0; m < 4; ++m)
#pragma unroll
      for (int n = 0; n < 4; ++n)
        acc[m][n] = __builtin_amdgcn_mfma_f32_16x16x32_bf16(af[m], bfr[n],
                                                            acc[m][n], 0, 0, 0);
    __builtin_amdgcn_s_setprio(0);
    __builtin_amdgcn_s_barrier();
    // P2: kk0 A m4-7; stage Bk0(t+1)
#pragma unroll
    for (int m = 0; m < 4; ++m)
      af[m] = *(const s16x8*)&As[buf][(wr * 8 + 4 + m) * 512 + lo];
    if (pre) {
      gload16(Bt + boff[0] + nk64, &Bs[nbuf][ldso[0]]);
      gload16(Bt + boff[1] + nk64, &Bs[nbuf][ldso[1]]);
    }
    __builtin_amdgcn_s_barrier();
    __builtin_amdgcn_s_setprio(1);
#pragma unroll
    for (int m = 0; m < 4; ++m)
#pragma unroll
      for (int n = 0; n < 4; ++n)
        acc[m + 4][n] = __builtin_amdgcn_mfma_f32_16x16x32_bf16(
            af[m], bfr[n], acc[m + 4][n], 0, 0, 0);
    __builtin_amdgcn_s_setprio(0);
    __builtin_amdgcn_s_barrier();
    // P3: kk1 A m0-3 + B; stage Ak1(t+1); gate kk1(t)
#pragma unroll
    for (int m = 0; m < 4; ++m)
      af[m] = *(const s16x8*)&As[buf][8192 + (wr * 8 + m) * 512 + lo];
#pragma unroll
    for (int n = 0; n < 4; ++n)
      bfr[n] = *(const s16x8*)&Bs[buf][8192 + (wc * 4 + n) * 512 + lo];
    if (pre) {
      gload16(A + aoff[2] + nk64, &As[nbuf][ldso[2]]);
      gload16(A + aoff[3] + nk64, &As[nbuf][ldso[3]]);
      asm volatile("s_waitcnt vmcnt(6)" ::: "memory");
    } else {
      asm volatile("s_waitcnt vmcnt(0)" ::: "memory");
    }
    __builtin_amdgcn_s_barrier();
    __builtin_amdgcn_s_setprio(1);
#pragma unroll
    for (int m = 0; m < 4; ++m)
#pragma unroll
      for (int n = 0; n < 4; ++n)
        acc[m][n] = __builtin_amdgcn_mfma_f32_16x16x32_bf16(af[m], bfr[n],
                                                            acc[m][n], 0, 0, 0);
    __builtin_amdgcn_s_setprio(0);
    __builtin_amdgcn_s_barrier();
    // P4: kk1 A m4-7; stage Bk1(t+1); gate kk0(t+1)
#pragma unroll
    for (int m = 0; m < 4; ++m)
      af[m] = *(const s16x8*)&As[buf][8192 + (wr * 8 + 4 + m) * 512 + lo];
    if (pre) {
      gload16(Bt + boff[2] + nk64, &Bs[nbuf][ldso[2]]);
      gload16(Bt + boff[3] + nk64, &Bs[nbuf][ldso[3]]);
      asm volatile("s_waitcnt vmcnt(4)" ::: "memory");
    }
    __builtin_amdgcn_s_barrier();
    __builtin_amdgcn_s_setprio(1);
#pragma unroll
    for (int m = 0; m < 4; ++m)
#pragma unroll
      for (int n = 0; n < 4; ++n)
        acc[m + 4][n] = __builtin_amdgcn_mfma_f32_16x16x32_bf16(
            af[m], bfr[n], acc[m + 4][n], 0, 0, 0);
    __builtin_amdgcn_s_setprio(0);
    __builtin_amdgcn_s_barrier();
  }
  // ---- epilogue ----
  if (VT && nb >= 2 * C) {
    int hh = ((nb - 2 * C) >> 6) + wc;  // head index (uniform per wave)
#pragma unroll
    for (int m = 0; m < 8; ++m) {
      int t0 = mb + wr * 128 + m * 16 + lg * 4;
      int bb = t0 >> 10, tt = t0 & (T - 1);
      size_t vbase = ((size_t)(bb * H + hh) * HS) * T + tt;
#pragma unroll
      for (int n = 0; n < 4; ++n) {
        int d = n * 16 + lm;
        s16x4 pk;
#pragma unroll
        for (int r = 0; r < 4; ++r) pk[r] = (short)f2bf(acc[m][n][r]);
        *(s16x4*)&Vtp[vbase + (size_t)d * T] = pk;
      }
    }
    return;
  }
  float bv[4];
#pragma unroll
  for (int n = 0; n < 4; ++n)
    bv[n] = HAS_BIAS ? bias[nb + wc * 64 + n * 16 + lm] : 0.0f;
#pragma unroll
  for (int m = 0; m < 8; ++m) {
#pragma unroll
    for (int r = 0; r < 4; ++r) {
      int row = mb + wr * 128 + m * 16 + lg * 4 + r;
#pragma unroll
      for (int n = 0; n < 4; ++n) {
        int col = nb + wc * 64 + n * 16 + lm;
        float v = acc[m][n][r] + bv[n];
        if (HAS_RES) v += Res[(size_t)row * N + col];
        if (RELU) v = v > 0.f ? v : 0.f;
        if (OUT_BF16)
          Cb[(size_t)row * N + col] = f2bf(v);
        else
          Cf[(size_t)row * N + col] = v;
      }
    }
  }
  if (LOSS) {
    // max-free per-row sum-of-exp over this block's 256 cols -> Pp[nblk][row]
    __syncthreads();
    float* redS = (float*)&As[0][0];  // 256 rows x 4 waves
    float Sx[8][4];
#pragma unroll
    for (int m = 0; m < 8; ++m)
#pragma unroll
      for (int r = 0; r < 4; ++r)
        Sx[m][r] = __expf(acc[m][0][r] + bv[0]) + __expf(acc[m][1][r] + bv[1]) +
                   __expf(acc[m][2][r] + bv[2]) + __expf(acc[m][3][r] + bv[3]);
#pragma unroll
    for (int d = 1; d < 16; d <<= 1)
#pragma unroll
      for (int m = 0; m < 8; ++m)
#pragma unroll
        for (int r = 0; r < 4; ++r)
          Sx[m][r] += __shfl_xor(Sx[m][r], d, 16);
    if (lm == 0) {
#pragma unroll
      for (int m = 0; m < 8; ++m)
#pragma unroll
        for (int r = 0; r < 4; ++r)
          redS[(wr * 128 + m * 16 + lg * 4 + r) * 4 + wc] = Sx[m][r];
    }
    __syncthreads();
    if (tid < 256) {
      float srow = redS[tid * 4 + 0] + redS[tid * 4 + 1] + redS[tid * 4 + 2] +
                   redS[tid * 4 + 3];
      Pp[(size_t)(nb >> 8) * M + mb + tid] = srow;
    }
  }
}

// ---------- flash attention v5: paired q-tiles + double-buffered staging ----
__global__ __launch_bounds__(256) void k_attn(
    const u16* __restrict__ qkv, const u16* __restrict__ vt,
    u16* __restrict__ o) {
  constexpr int PP = 72;
  __shared__ u16 Ks[2][64 * 64];
  __shared__ u16 Vs[2][64 * 64];
  __shared__ u16 Ps[4][16 * PP];
  int bid = blockIdx.x;  // p | h | b
  int p = bid & 7, h = (bid >> 3) & 15, b = bid >> 7;
  int tid = threadIdx.x, lane = tid & 63, wid = tid >> 6;
  int lm = lane & 15, lg = lane >> 4;
  const size_t rowbase = (size_t)b * T * C3 + (size_t)h * HS;
  const u16* kbase = qkv + rowbase + C;
  const u16* vbase = vt + (size_t)(b * H + h) * HS * T;
  const size_t obase = (size_t)b * T * C + (size_t)h * HS;
  const float scale = 0.125f;
  const int sr = tid >> 3, scs = (tid & 7) ^ (sr & 7);
  const int swz0 = (lg ^ (lm & 7)) * 8;
  const int swz1 = ((4 + lg) ^ (lm & 7)) * 8;

  for (int qi = 0; qi < 2; ++qi) {
    int qt = qi ? (15 - p) : p;
    int qw = qt * 64 + wid * 16;
    s16x8 qf[2];
#pragma unroll
    for (int s = 0; s < 2; ++s)
      qf[s] = *(const s16x8*)&qkv[rowbase + (size_t)(qw + lm) * C3 + s * 32 +
                                  lg * 8];
    float m_[4], l_[4];
    f32x4 oacc[4];
#pragma unroll
    for (int r = 0; r < 4; ++r) { m_[r] = -3e38f; l_[r] = 0.f; }
#pragma unroll
    for (int n = 0; n < 4; ++n) oacc[n] = f32x4{0.f, 0.f, 0.f, 0.f};

    // prologue: stage tile 0 into buffer 0
    gload16(kbase + (size_t)sr * C3 + scs * 8, &Ks[0][wid * 512]);
    gload16(kbase + (size_t)(sr + 32) * C3 + scs * 8, &Ks[0][2048 + wid * 512]);
    gload16(vbase + (size_t)sr * T + scs * 8, &Vs[0][wid * 512]);
    gload16(vbase + (size_t)(sr + 32) * T + scs * 8, &Vs[0][2048 + wid * 512]);

    for (int kt = 0; kt <= qt; ++kt) {
      int buf = kt & 1;
      bool pre = kt < qt;
      if (pre) {  // stage kt+1 into the other buffer
        int nk = (kt + 1) * 64;
        int nbuf = buf ^ 1;
        gload16(kbase + (size_t)(nk + sr) * C3 + scs * 8, &Ks[nbuf][wid * 512]);
        gload16(kbase + (size_t)(nk + sr + 32) * C3 + scs * 8,
                &Ks[nbuf][2048 + wid * 512]);
        gload16(vbase + (size_t)sr * T + nk + scs * 8, &Vs[nbuf][wid * 512]);
        gload16(vbase + (size_t)(sr + 32) * T + nk + scs * 8,
                &Vs[nbuf][2048 + wid * 512]);
        asm volatile("s_waitcnt vmcnt(4)" ::: "memory");
      } else {
        asm volatile("s_waitcnt vmcnt(0)" ::: "memory");
      }
      __builtin_amdgcn_s_barrier();

      f32x4 s[4];
#pragma unroll
      for (int ch = 0; ch < 4; ++ch) {
        s16x8 k0 = *(const s16x8*)&Ks[buf][(ch * 16 + lm) * 64 + swz0];
        s16x8 k1 = *(const s16x8*)&Ks[buf][(ch * 16 + lm) * 64 + swz1];
        s[ch] = f32x4{0.f, 0.f, 0.f, 0.f};
        s[ch] = __builtin_amdgcn_mfma_f32_16x16x32_bf16(qf[0], k0, s[ch], 0, 0, 0);
        s[ch] = __builtin_amdgcn_mfma_f32_16x16x32_bf16(qf[1], k1, s[ch], 0, 0, 0);
      }
      if (kt == qt) {  // diagonal tile: mask
#pragma unroll
        for (int ch = 0; ch < 4; ++ch) {
          int col = kt * 64 + ch * 16 + lm;
#pragma unroll
          for (int r = 0; r < 4; ++r) {
            int row = qw + lg * 4 + r;
            s[ch][r] = (col <= row) ? s[ch][r] * scale : -3e38f;
          }
        }
      } else {
#pragma unroll
        for (int ch = 0; ch < 4; ++ch)
#pragma unroll
          for (int r = 0; r < 4; ++r) s[ch][r] *= scale;
      }
      float rmax[4];
#pragma unroll
      for (int r = 0; r < 4; ++r)
        rmax[r] = fmaxf(fmaxf(s[0][r], s[1][r]), fmaxf(s[2][r], s[3][r]));
#pragma unroll
      for (int mm = 1; mm < 16; mm <<= 1)
#pragma unroll
        for (int r = 0; r < 4; ++r)
          rmax[r] = fmaxf(rmax[r], __shfl_xor(rmax[r], mm, 16));
      float alpha[4], rsum[4];
#pragma unroll
      for (int r = 0; r < 4; ++r) {
        float mn = fmaxf(m_[r], rmax[r]);
        alpha[r] = __expf(m_[r] - mn);
        m_[r] = mn;
        rsum[r] = 0.f;
      }
#pragma unroll
      for (int ch = 0; ch < 4; ++ch)
#pragma unroll
        for (int r = 0; r < 4; ++r) {
          float e = __expf(s[ch][r] - m_[r]);
          s[ch][r] = e;
          rsum[r] += e;
        }
#pragma unroll
      for (int mm = 1; mm < 16; mm <<= 1)
#pragma unroll
        for (int r = 0; r < 4; ++r) rsum[r] += __shfl_xor(rsum[r], mm, 16);
#pragma unroll
      for (int r = 0; r < 4; ++r) l_[r] = l_[r] * alpha[r] + rsum[r];
#pragma unroll
      for (int n = 0; n < 4; ++n)
#pragma unroll
        for (int r = 0; r < 4; ++r) oacc[n][r] *= alpha[r];
#pragma unroll
      for (int r = 0; r < 4; ++r) {
        int pr = lg * 4 + r;
#pragma unroll
        for (int ch = 0; ch < 4; ++ch)
          Ps[wid][pr * PP + ch * 16 + lm] = f2bf(s[ch][r]);
      }
      s16x8 pa0 = *(const s16x8*)&Ps[wid][lm * PP + lg * 8];
      s16x8 pa1 = *(const s16x8*)&Ps[wid][lm * PP + 32 + lg * 8];
#pragma unroll
      for (int n = 0; n < 4; ++n) {
        s16x8 v0 = *(const s16x8*)&Vs[buf][(n * 16 + lm) * 64 + swz0];
        s16x8 v1 = *(const s16x8*)&Vs[buf][(n * 16 + lm) * 64 + swz1];
        oacc[n] =
            __builtin_amdgcn_mfma_f32_16x16x32_bf16(pa0, v0, oacc[n], 0, 0, 0);
        oacc[n] =
            __builtin_amdgcn_mfma_f32_16x16x32_bf16(pa1, v1, oacc[n], 0, 0, 0);
      }
      __builtin_amdgcn_s_barrier();  // all reads of buf done before overwrite
    }
    float inv[4];
#pragma unroll
    for (int r = 0; r < 4; ++r) inv[r] = 1.0f / l_[r];
#pragma unroll
    for (int n = 0; n < 4; ++n)
#pragma unroll
      for (int r = 0; r < 4; ++r)
        o[obase + (size_t)(qw + lg * 4 + r) * C + n * 16 + lm] =
            f2bf(oacc[n][r] * inv[r]);
  }
}

// ---------- LayerNorm (vectorized: one float4 per thread) ----------
__global__ __launch_bounds__(256) void k_ln(
    const float* __restrict__ in, const float* __restrict__ g,
    const float* __restrict__ bsh, float* __restrict__ xout,
    u16* __restrict__ xbout) {
  int row = blockIdx.x;
  int tid = threadIdx.x;
  f32x4 v = ((const f32x4*)(in + (size_t)row * C))[tid];
  float s = v[0] + v[1] + v[2] + v[3];
  s = blockReduceSum(s);
  float mean = s * (1.0f / C);
  float s2 = 0.f;
#pragma unroll
  for (int j = 0; j < 4; ++j) {
    float d = v[j] - mean;
    s2 += d * d;
  }
  s2 = blockReduceSum(s2);
  float rstd = rsqrtf(s2 * (1.0f / C) + 1e-5f);
  f32x4 gv = ((const f32x4*)g)[tid];
  f32x4 bv = ((const f32x4*)bsh)[tid];
  f32x4 y;
  s16x4 yb;
#pragma unroll
  for (int j = 0; j < 4; ++j) {
    y[j] = (v[j] - mean) * rstd * gv[j] + bv[j];
    yb[j] = (short)f2bf(y[j]);
  }
  ((f32x4*)(xout + (size_t)row * C))[tid] = y;
  ((s16x4*)(xbout + (size_t)row * C))[tid] = yb;
}

// ---------- loss: merge per-block exp-sums + target logit ----------
__global__ __launch_bounds__(128) void k_rowloss2(
    const float* __restrict__ sums, const float* __restrict__ logits,
    const int* __restrict__ tgt, float* __restrict__ rowloss) {
  int row = blockIdx.x;
  int tid = threadIdx.x;
  float s = (tid < 125) ? sums[(size_t)tid * BT + row] : 0.f;
#pragma unroll
  for (int d = 1; d < 64; d <<= 1) s += __shfl_xor(s, d, 64);
  __shared__ float ss[2];
  if ((tid & 63) == 0) ss[tid >> 6] = s;
  __syncthreads();
  if (tid == 0)
    rowloss[row] = logf(ss[0] + ss[1]) - logits[(size_t)row * V + tgt[row]];
}

__global__ __launch_bounds__(256) void k_lossreduce(
    const float* __restrict__ rowloss, float* __restrict__ out) {
  __shared__ float red[256];
  int tid = threadIdx.x;
  float s = 0.f;
  for (int i = tid; i < BT; i += 256) s += rowloss[i];
  red[tid] = s;
  __syncthreads();
  for (int m = 128; m >= 1; m >>= 1) {
    if (tid < m) red[tid] += red[tid + m];
    __syncthreads();
  }
  if (tid == 0) out[0] = red[0] * (1.0f / BT);
}

// ---------------- host orchestration ----------------
extern "C" void kernel_launch(void* const* d_in, const int* in_sizes, int n_in,
                              void* d_out, int out_size, void* d_ws,
                              size_t ws_size, hipStream_t stream) {
  (void)in_sizes; (void)n_in; (void)out_size; (void)ws_size;
  const int* index = (const int*)d_in[0];
  const int* targets = (const int*)d_in[1];
  const float* tok_emb = (const float*)d_in[2];
  const float* pos_emb = (const float*)d_in[3];
  const float* wq = (const float*)d_in[4];
  const float* wk = (const float*)d_in[5];
  const float* wv = (const float*)d_in[6];
  const float* wo = (const float*)d_in[7];
  const float* bo = (const float*)d_in[8];
  const float* w1 = (const float*)d_in[9];
  const float* b1 = (const float*)d_in[10];
  const float* w2 = (const float*)d_in[11];
  const float* b2 = (const float*)d_in[12];
  const float* ln1_g = (const float*)d_in[13];
  const float* ln1_b = (const float*)d_in[14];
  const float* ln2_g = (const float*)d_in[15];
  const float* ln2_b = (const float*)d_in[16];
  const float* lnf_g = (const float*)d_in[17];
  const float* lnf_b = (const float*)d_in[18];
  const float* lm_w = (const float*)d_in[19];
  const float* lm_b = (const float*)d_in[20];

  float* logits = (float*)d_out;
  float* loss = logits + (size_t)BT * V;

  size_t off = 0;
  auto alloc = [&](size_t bytes) -> void* {
    off = (off + 255) & ~(size_t)255;
    void* p = (void*)((char*)d_ws + off);
    off += bytes;
    return p;
  };
  u16* wqkv_t = (u16*)alloc((size_t)L * C3 * C * 2);  // [L][3C][C]
  u16* wo_t = (u16*)alloc((size_t)L * C * C * 2);
  u16* w1_t = (u16*)alloc((size_t)L * C * C4 * 2);
  u16* w2_t = (u16*)alloc((size_t)L * C4 * C * 2);
  u16* lmw_t = (u16*)alloc((size_t)V * C * 2);
  float* x = (float*)alloc((size_t)BT * C * 4);
  float* tmp = (float*)alloc((size_t)BT * C * 4);
  u16* xb = (u16*)alloc((size_t)BT * C * 2);
  u16* qkvb = (u16*)alloc((size_t)BT * C3 * 2);
  u16* vtb = (u16*)alloc((size_t)BT * C * 2);   // V transposed per (b,h)
  u16* attb = (u16*)alloc((size_t)BT * C * 2);
  u16* hb = (u16*)alloc((size_t)BT * C4 * 2);
  float* rowloss = (float*)alloc((size_t)BT * 4);
  float* sums = (float*)alloc((size_t)BT * 128 * 4);

  dim3 blk(256);
  dim3 blk5(512);
  k_transpose<<<dim3(C / 64, C / 64, L), blk, 0, stream>>>(
      wq, wqkv_t, C, C, (size_t)C * C, (size_t)C3 * C);
  k_transpose<<<dim3(C / 64, C / 64, L), blk, 0, stream>>>(
      wk, wqkv_t + (size_t)C * C, C, C, (size_t)C * C, (size_t)C3 * C);
  k_transpose<<<dim3(C / 64, C / 64, L), blk, 0, stream>>>(
      wv, wqkv_t + (size_t)2 * C * C, C, C, (size_t)C * C, (size_t)C3 * C);
  k_transpose<<<dim3(C / 64, C / 64, L), blk, 0, stream>>>(
      wo, wo_t, C, C, (size_t)C * C, (size_t)C * C);
  k_transpose<<<dim3(C4 / 64, C / 64, L), blk, 0, stream>>>(
      w1, w1_t, C, C4, (size_t)C * C4, (size_t)C * C4);
  k_transpose<<<dim3(C / 64, C4 / 64, L), blk, 0, stream>>>(
      w2, w2_t, C4, C, (size_t)C4 * C, (size_t)C4 * C);
  k_transpose<<<dim3(V / 64, C / 64, 1), blk, 0, stream>>>(
      lm_w, lmw_t, C, V, 0, 0);

  k_embed<<<BT, blk, 0, stream>>>(index, tok_emb, pos_emb, x, xb);

  dim3 gQKV(C3 / 256, BT / 256);   // 12 x 16 = 192 wg (256^2)
  dim3 gCC(C / 128, BT / 128);     // 256 wg (128^2)
  dim3 gC4(C4 / 256, BT / 256);    // 256 wg (256^2)
  for (int l = 0; l < L; ++l) {
    const u16* wqkvt = wqkv_t + (size_t)l * C3 * C;
    const u16* wot = wo_t + (size_t)l * C * C;
    const u16* w1t = w1_t + (size_t)l * C * C4;
    const u16* w2t = w2_t + (size_t)l * C4 * C;

    k_gemm256<1, 0, 0, 0, 1, 0, 0><<<gQKV, blk5, 0, stream>>>(
        xb, wqkvt, nullptr, nullptr, nullptr, qkvb, vtb, nullptr, BT, C3, C);
    k_attn<<<B * H * 8, blk, 0, stream>>>(qkvb, vtb, attb);
    k_gemm<0, 0, 1, 1><<<gCC, blk, 0, stream>>>(
        attb, wot, bo + (size_t)l * C, x, tmp, nullptr, BT, C, C);
    k_ln<<<BT, blk, 0, stream>>>(tmp, ln1_g + (size_t)l * C,
                                 ln1_b + (size_t)l * C, x, xb);
    k_gemm256<1, 1, 1, 0, 0, 0, 0><<<gC4, blk5, 0, stream>>>(
        xb, w1t, b1 + (size_t)l * C4, nullptr, nullptr, hb, nullptr, nullptr,
        BT, C4, C);
    k_gemm<0, 0, 1, 1><<<gCC, blk, 0, stream>>>(
        hb, w2t, b2 + (size_t)l * C, x, tmp, nullptr, BT, C, C4);
    k_ln<<<BT, blk, 0, stream>>>(tmp, ln2_g + (size_t)l * C,
                                 ln2_b + (size_t)l * C, x, xb);
  }
  k_ln<<<BT, blk, 0, stream>>>(x, lnf_g, lnf_b, x, xb);
  k_gemm256<0, 0, 1, 0, 0, 1, 1><<<dim3(V / 256, BT / 256), blk5, 0, stream>>>(
      xb, lmw_t, lm_b, nullptr, logits, nullptr, nullptr, sums, BT, V, C);
  k_rowloss2<<<BT, dim3(128), 0, stream>>>(sums, logits, targets, rowloss);
  k_lossreduce<<<1, blk, 0, stream>>>(rowloss, loss);
}